// Round 12
// baseline (790.385 us; speedup 1.0000x reference)
//
#include <hip/hip_runtime.h>
#include <hip/hip_bf16.h>

#define C_    768
#define NH_   8
#define DH_   96
#define S_    729
#define B_    8
#define MTOK  5832
#define C3    2304
#define GUN   12288
#define DK    6144
#define SPAD  736
#define NPB   559872   // C_*S_

typedef __attribute__((ext_vector_type(8))) short short8;
typedef __attribute__((ext_vector_type(4))) float f32x4;
typedef __attribute__((ext_vector_type(4))) unsigned int uint4v;
typedef __hip_bfloat16 bf16;

__device__ __forceinline__ void gld_lds16(const bf16* g, bf16* l) {
  __builtin_amdgcn_global_load_lds((const __attribute__((address_space(1))) void*)g,
                                   (__attribute__((address_space(3))) void*)l, 16, 0, 0);
}
__device__ __forceinline__ void gld_lds16c(const char* g, char* l) {
  __builtin_amdgcn_global_load_lds((const __attribute__((address_space(1))) void*)g,
                                   (__attribute__((address_space(3))) void*)l, 16, 0, 0);
}

// ================= 256x256 8-wave 2-phase deep-pipelined GEMM =================
// Per tile: P0 {read A0-3+B0-3 from db; stage t+1-h1 -> nb; MFMA m0-3 x n0-3} bar
//           P1 {read A4-7 from db; stage B-h0(t+2) -> db; MFMA m4-7 x n0-3} bar
//           {stage A-h0(t+2) -> db; vmcnt; bar}
// No forced lgkmcnt: compiler emits dependency-counted waits -> ds_read/MFMA overlap.
template<int DB>
__device__ __forceinline__ void tile_step(
    char* ldsc, char* ldsw,
    const int rA0, const int rA1, const int rB0, const int rB1,
    const char* pA0, const char* pA1, const char* pA2, const char* pA3,
    const char* pB0, const char* pB1, const char* pB2, const char* pB3,
    const int s1, const int s2, const bool gH1, const bool gH0, const int wmode,
    f32x4 (&acc)[8][4], short8 (&a4)[4][2], short8 (&b4)[4][2])
{
  const int DBO = DB * 65536;
  const int NBO = 65536 - DBO;
  // ---- P0: read A0-3 + B0-3; stage full h1(t+1) -> nb; MFMA upper half ----
  #pragma unroll
  for (int mf = 0; mf < 4; ++mf) {
    a4[mf][0] = *(const short8*)(ldsc + DBO + rA0 + mf*2048);
    a4[mf][1] = *(const short8*)(ldsc + DBO + rA1 + mf*2048);
  }
  #pragma unroll
  for (int nf = 0; nf < 4; ++nf) {
    b4[nf][0] = *(const short8*)(ldsc + DBO + rB0 + nf*2048);
    b4[nf][1] = *(const short8*)(ldsc + DBO + rB1 + nf*2048);
  }
  if (gH1) {
    gld_lds16c(pA2 + s1, ldsw + NBO + 16384);
    gld_lds16c(pA3 + s1, ldsw + NBO + 16384 + 8192);
    gld_lds16c(pB2 + s1, ldsw + NBO + 32768 + 16384);
    gld_lds16c(pB3 + s1, ldsw + NBO + 32768 + 16384 + 8192);
  }
  __builtin_amdgcn_s_setprio(1);
  #pragma unroll
  for (int mf = 0; mf < 4; ++mf)
    #pragma unroll
    for (int nf = 0; nf < 4; ++nf)
      #pragma unroll
      for (int j = 0; j < 2; ++j)
        acc[mf][nf] = __builtin_amdgcn_mfma_f32_16x16x32_bf16(a4[mf][j], b4[nf][j], acc[mf][nf], 0, 0, 0);
  __builtin_amdgcn_s_setprio(0);
  __builtin_amdgcn_s_barrier();                    // bar1: all B + A-upper reads done
  // ---- P1: read A4-7; stage B-h0(t+2) -> db; MFMA lower half ----
  #pragma unroll
  for (int mi = 0; mi < 4; ++mi) {
    a4[mi][0] = *(const short8*)(ldsc + DBO + rA0 + (4+mi)*2048);
    a4[mi][1] = *(const short8*)(ldsc + DBO + rA1 + (4+mi)*2048);
  }
  if (gH0) {
    gld_lds16c(pB0 + s2, ldsw + DBO + 32768);
    gld_lds16c(pB1 + s2, ldsw + DBO + 32768 + 8192);
  }
  __builtin_amdgcn_s_setprio(1);
  #pragma unroll
  for (int mi = 0; mi < 4; ++mi)
    #pragma unroll
    for (int nf = 0; nf < 4; ++nf)
      #pragma unroll
      for (int j = 0; j < 2; ++j)
        acc[4+mi][nf] = __builtin_amdgcn_mfma_f32_16x16x32_bf16(a4[mi][j], b4[nf][j], acc[4+mi][nf], 0, 0, 0);
  __builtin_amdgcn_s_setprio(0);
  __builtin_amdgcn_s_barrier();                    // bar2: all tile-t reads complete
  if (gH0) {
    gld_lds16c(pA0 + s2, ldsw + DBO);
    gld_lds16c(pA1 + s2, ldsw + DBO + 8192);
  }
  if (wmode == 0)      asm volatile("s_waitcnt vmcnt(4)" ::: "memory");
  else if (wmode == 1) asm volatile("s_waitcnt vmcnt(0)" ::: "memory");
  __builtin_amdgcn_s_barrier();                    // bar3: tile boundary
}

// modes: 0 = bf16 out (Cb, +z*c_zoff). 1 = fp32 out (Cf, +z*c_zoff).
// 3 = fused MoE: gate/up interleaved at 16-col granularity; writes
// silu(g)*u*wfull[row*3+e] bf16 to Cb[row*c_rs + h], h = ((col32)>>5)*16+fr.
__global__ void __launch_bounds__(512, 2)
gemm8(const bf16* __restrict__ A, long a_rs,
      const bf16* __restrict__ Bt, long b_rs,
      float* __restrict__ Cf, bf16* __restrict__ Cb,
      long c_rs, long c_zoff, int M, int N, int Ksub,
      const float* __restrict__ wfull, int mode)
{
  __shared__ __attribute__((aligned(128))) char ldsc[131072];
  const int tid = threadIdx.x;
  const int wid = tid >> 6, lid = tid & 63;
  const int wm = wid >> 2, wn = wid & 3;           // 2 x 4 wave grid
  const int fr = lid & 15, g8 = (lid >> 4) * 8;
  const int brow = blockIdx.y * 256, bcol = blockIdx.x * 256;
  const long k0b = (long)blockIdx.z * Ksub * 2;
  const long a_rsb = a_rs * 2, b_rsb = b_rs * 2;
  const int srow = tid >> 3;
  const int scol = ((tid & 7) ^ (srow & 7)) << 4;
  const int NT = Ksub >> 6;
  char* ldsw = ldsc + wid * 1024;

  int ra0_ = brow + srow;        if (ra0_ > M-1) ra0_ = M-1;
  int ra1_ = brow + 64 + srow;   if (ra1_ > M-1) ra1_ = M-1;
  int ra2_ = brow + 128 + srow;  if (ra2_ > M-1) ra2_ = M-1;
  int ra3_ = brow + 192 + srow;  if (ra3_ > M-1) ra3_ = M-1;
  int rb0_ = bcol + srow;        if (rb0_ > N-1) rb0_ = N-1;
  int rb1_ = bcol + 64 + srow;   if (rb1_ > N-1) rb1_ = N-1;
  int rb2_ = bcol + 128 + srow;  if (rb2_ > N-1) rb2_ = N-1;
  int rb3_ = bcol + 192 + srow;  if (rb3_ > N-1) rb3_ = N-1;
  const char* pA0 = (const char*)A + (long)ra0_*a_rsb + k0b + scol;
  const char* pA1 = (const char*)A + (long)ra1_*a_rsb + k0b + scol;
  const char* pA2 = (const char*)A + (long)ra2_*a_rsb + k0b + scol;
  const char* pA3 = (const char*)A + (long)ra3_*a_rsb + k0b + scol;
  const char* pB0 = (const char*)Bt + (long)rb0_*b_rsb + k0b + scol;
  const char* pB1 = (const char*)Bt + (long)rb1_*b_rsb + k0b + scol;
  const char* pB2 = (const char*)Bt + (long)rb2_*b_rsb + k0b + scol;
  const char* pB3 = (const char*)Bt + (long)rb3_*b_rsb + k0b + scol;

  const int swz = (fr & 7) << 4;
  const int cx0 = (g8 * 2) ^ swz;
  const int cx1 = (64 + g8 * 2) ^ swz;
  const int rA0 = (wm*128 + fr)*128 + cx0;
  const int rA1 = (wm*128 + fr)*128 + cx1;
  const int rB0 = 32768 + (wn*64 + fr)*128 + cx0;
  const int rB1 = 32768 + (wn*64 + fr)*128 + cx1;

  f32x4 acc[8][4] = {};
  short8 a4[4][2], b4[4][2];

  gld_lds16c(pA0, ldsw);
  gld_lds16c(pA1, ldsw + 8192);
  gld_lds16c(pA2, ldsw + 16384);
  gld_lds16c(pA3, ldsw + 16384 + 8192);
  gld_lds16c(pB0, ldsw + 32768);
  gld_lds16c(pB1, ldsw + 32768 + 8192);
  gld_lds16c(pB2, ldsw + 32768 + 16384);
  gld_lds16c(pB3, ldsw + 32768 + 16384 + 8192);
  gld_lds16c(pA0 + 128, ldsw + 65536);
  gld_lds16c(pA1 + 128, ldsw + 65536 + 8192);
  gld_lds16c(pB0 + 128, ldsw + 65536 + 32768);
  gld_lds16c(pB1 + 128, ldsw + 65536 + 32768 + 8192);
  asm volatile("s_waitcnt vmcnt(4)" ::: "memory");
  __builtin_amdgcn_s_barrier();

  for (int tp = 0; tp < NT; tp += 2) {
    const bool g2 = (tp + 2) < NT;
    tile_step<0>(ldsc, ldsw, rA0, rA1, rB0, rB1,
                 pA0, pA1, pA2, pA3, pB0, pB1, pB2, pB3,
                 128, 256, true, g2, g2 ? 0 : 1, acc, a4, b4);
    tile_step<1>(ldsc, ldsw, rA0, rA1, rB0, rB1,
                 pA0, pA1, pA2, pA3, pB0, pB1, pB2, pB3,
                 256, 384, g2, g2, g2 ? 0 : 2, acc, a4, b4);
    if (g2) {
      pA0 += 256; pA1 += 256; pA2 += 256; pA3 += 256;
      pB0 += 256; pB1 += 256; pB2 += 256; pB3 += 256;
    }
  }

  const int rg = (lid >> 4) * 4;
  if (mode == 3) {
    // fused silu(gate)*up*w epilogue; gate=acc[*][even nf], up=acc[*][odd nf]
    #pragma unroll
    for (int mf = 0; mf < 8; ++mf) {
      #pragma unroll
      for (int np = 0; np < 2; ++np) {
        const int hb = (bcol + wn*64 + np*32) >> 5;   // 32-row block index
        const int h = hb*16 + fr;
        const int e = h >> 11;                         // expert = h / 2048
        #pragma unroll
        for (int j = 0; j < 4; ++j) {
          const int row = brow + wm*128 + mf*16 + rg + j;
          if (row < M) {
            float g = acc[mf][2*np][j];
            float u = acc[mf][2*np+1][j];
            float w = wfull[row*3 + e];
            float sg = g / (1.f + __expf(-g));
            Cb[(long)row*c_rs + h] = __float2bfloat16(sg * u * w);
          }
        }
      }
    }
  } else {
    #pragma unroll
    for (int mf = 0; mf < 8; ++mf) {
      #pragma unroll
      for (int nf = 0; nf < 4; ++nf) {
        const int col = bcol + wn*64 + nf*16 + fr;
        if (col < N) {
          #pragma unroll
          for (int j = 0; j < 4; ++j) {
            const int row = brow + wm*128 + mf*16 + rg + j;
            if (row < M) {
              long off = (long)blockIdx.z*c_zoff + (long)row*c_rs + col;
              if (mode == 0) Cb[off] = __float2bfloat16(acc[mf][nf][j]);
              else           Cf[off] = acc[mf][nf][j];
            }
          }
        }
      }
    }
  }
}

// ---------------- bf16x3 split GEMM: A=(Ah+Al), B=(Bh+Bl), 3 products ----------------
__global__ void __launch_bounds__(256)
gemm3_bt(const bf16* __restrict__ Ah, const bf16* __restrict__ Al,
         long a_rs, long a_oo, long a_oi,
         const bf16* __restrict__ Bth, const bf16* __restrict__ Btl,
         long b_rs, long b_oo, long b_oi,
         float* __restrict__ Cf, bf16* __restrict__ Ch, bf16* __restrict__ Cl,
         long c_rs, long c_oo, long c_oi,
         int M, int N, int K, int nlim, int zdiv)
{
  __shared__ bf16 lAh[4096];
  __shared__ bf16 lAl[4096];
  __shared__ bf16 lBh[4096];
  __shared__ bf16 lBl[4096];
  const int tid = threadIdx.x;
  const int wid = tid >> 6;
  const int lid = tid & 63;
  const int z = blockIdx.z;
  const int zo = z / zdiv, zi = z - zo*zdiv;
  const long aoff = (long)zo*a_oo + (long)zi*a_oi;
  const long boff = (long)zo*b_oo + (long)zi*b_oi;
  const long cbase = (long)zo*c_oo + (long)zi*c_oi;
  const int brow = blockIdx.y * 128;
  const int bcol = blockIdx.x * 128;

  const int ch0 = tid, ch1 = tid + 256;
  int ra0 = brow + (ch0 >> 2); if (ra0 > M-1) ra0 = M-1;
  int ra1 = brow + (ch1 >> 2); if (ra1 > M-1) ra1 = M-1;
  int rb0 = bcol + (ch0 >> 2); if (rb0 > N-1) rb0 = N-1;
  int rb1 = bcol + (ch1 >> 2); if (rb1 > N-1) rb1 = N-1;
  const int sw = ((ch0 ^ (ch0 >> 2)) & 3) * 8;
  const long ia0 = aoff + (long)ra0*a_rs + sw;
  const long ia1 = aoff + (long)ra1*a_rs + sw;
  const long ib0 = boff + (long)rb0*b_rs + sw;
  const long ib1 = boff + (long)rb1*b_rs + sw;
  bf16* dAh0 = (bf16*)((char*)lAh + wid*1024);
  bf16* dAh1 = (bf16*)((char*)lAh + 4096 + wid*1024);
  bf16* dAl0 = (bf16*)((char*)lAl + wid*1024);
  bf16* dAl1 = (bf16*)((char*)lAl + 4096 + wid*1024);
  bf16* dBh0 = (bf16*)((char*)lBh + wid*1024);
  bf16* dBh1 = (bf16*)((char*)lBh + 4096 + wid*1024);
  bf16* dBl0 = (bf16*)((char*)lBl + wid*1024);
  bf16* dBl1 = (bf16*)((char*)lBl + 4096 + wid*1024);

  f32x4 acc[4][4] = {};
  const int wm = wid >> 1, wn = wid & 1;
  const int fr = lid & 15, g8 = (lid >> 4) * 8;
  const int gx = g8 ^ ((lid & 3) << 3);

  for (int kt = 0; kt < K; kt += 32) {
    __syncthreads();
    gld_lds16(Ah + ia0 + kt, dAh0);
    gld_lds16(Ah + ia1 + kt, dAh1);
    gld_lds16(Al + ia0 + kt, dAl0);
    gld_lds16(Al + ia1 + kt, dAl1);
    gld_lds16(Bth + ib0 + kt, dBh0);
    gld_lds16(Bth + ib1 + kt, dBh1);
    gld_lds16(Btl + ib0 + kt, dBl0);
    gld_lds16(Btl + ib1 + kt, dBl1);
    __syncthreads();
    short8 fah[4], fal[4], fbh[4], fbl[4];
    #pragma unroll
    for (int m = 0; m < 4; ++m) {
      int ro = (wm*64 + m*16 + fr)*32 + gx;
      fah[m] = *(const short8*)&lAh[ro];
      fal[m] = *(const short8*)&lAl[ro];
    }
    #pragma unroll
    for (int n = 0; n < 4; ++n) {
      int ro = (wn*64 + n*16 + fr)*32 + gx;
      fbh[n] = *(const short8*)&lBh[ro];
      fbl[n] = *(const short8*)&lBl[ro];
    }
    #pragma unroll
    for (int m = 0; m < 4; ++m)
      #pragma unroll
      for (int n = 0; n < 4; ++n) {
        acc[m][n] = __builtin_amdgcn_mfma_f32_16x16x32_bf16(fal[m], fbh[n], acc[m][n], 0, 0, 0);
        acc[m][n] = __builtin_amdgcn_mfma_f32_16x16x32_bf16(fah[m], fbl[n], acc[m][n], 0, 0, 0);
        acc[m][n] = __builtin_amdgcn_mfma_f32_16x16x32_bf16(fah[m], fbh[n], acc[m][n], 0, 0, 0);
      }
  }

  const int rg = (lid >> 4) * 4;
  #pragma unroll
  for (int m = 0; m < 4; ++m) {
    #pragma unroll
    for (int n = 0; n < 4; ++n) {
      const int col = bcol + wn*64 + n*16 + fr;
      if (col < nlim) {
        #pragma unroll
        for (int j = 0; j < 4; ++j) {
          const int row = brow + wm*64 + m*16 + rg + j;
          if (row < M) {
            long off = cbase + (long)row*c_rs + col;
            float v = acc[m][n][j];
            if (Cl) {
              bf16 h = __float2bfloat16(v);
              Ch[off] = h;
              Cl[off] = __float2bfloat16(v - __bfloat162float(h));
            } else if (Ch) {
              Ch[off] = __float2bfloat16(v);
            } else {
              Cf[off] = v;
            }
          }
        }
      }
    }
  }
}

// ---------------- weight transpose fp32 -> bf16 (opt. 16-row interleave) ----------------
__global__ void wtrans(const float* __restrict__ in, bf16* __restrict__ out,
                       int R, int Cc, long in_rs, long out_rs, long in_bs, long out_bs,
                       int ilv, int radd)
{
  __shared__ float tile[32][33];
  in  += (long)blockIdx.z * in_bs;
  out += (long)blockIdx.z * out_bs;
  int r0 = blockIdx.y*32, c0 = blockIdx.x*32;
  int tx = threadIdx.x, ty = threadIdx.y;
  #pragma unroll
  for (int i = 0; i < 32; i += 8) {
    int r = r0 + ty + i, c = c0 + tx;
    if (r < R && c < Cc) tile[ty+i][tx] = in[(long)r*in_rs + c];
  }
  __syncthreads();
  #pragma unroll
  for (int i = 0; i < 32; i += 8) {
    int ro = c0 + ty + i, co = r0 + tx;
    if (ro < Cc && co < R) {
      int rr = ilv ? (((ro >> 4) << 5) + (ro & 15) + radd) : ro;
      out[(long)rr*out_rs + co] = __float2bfloat16(tile[tx][ty+i]);
    }
  }
}

// ---------------- weight transpose fp32 -> bf16 hi/lo pair ----------------
__global__ void wtrans3(const float* __restrict__ in, bf16* __restrict__ oh, bf16* __restrict__ ol,
                        int R, int Cc, long in_rs, long out_rs)
{
  __shared__ float tile[32][33];
  int r0 = blockIdx.y*32, c0 = blockIdx.x*32;
  int tx = threadIdx.x, ty = threadIdx.y;
  #pragma unroll
  for (int i = 0; i < 32; i += 8) {
    int r = r0 + ty + i, c = c0 + tx;
    if (r < R && c < Cc) tile[ty+i][tx] = in[(long)r*in_rs + c];
  }
  __syncthreads();
  #pragma unroll
  for (int i = 0; i < 32; i += 8) {
    int ro = c0 + ty + i, co = r0 + tx;
    if (ro < Cc && co < R) {
      float v = tile[tx][ty+i];
      bf16 h = __float2bfloat16(v);
      long o = (long)ro*out_rs + co;
      oh[o] = h;
      ol[o] = __float2bfloat16(v - __bfloat162float(h));
    }
  }
}

// ---------------- LayerNorm ----------------
__global__ void ln_partial(const float* __restrict__ x, float* __restrict__ part) {
  int b = blockIdx.y, blk = blockIdx.x;
  const float* xb = x + (long)b*NPB;
  int start = blk * 4374;
  float s = 0.f, ss = 0.f;
  for (int i = start + threadIdx.x; i < start + 4374; i += 256) {
    float v = xb[i]; s += v; ss += v*v;
  }
  #pragma unroll
  for (int o = 32; o; o >>= 1) { s += __shfl_down(s, o); ss += __shfl_down(ss, o); }
  __shared__ float red[2][4];
  int wid = threadIdx.x >> 6, lid = threadIdx.x & 63;
  if (lid == 0) { red[0][wid] = s; red[1][wid] = ss; }
  __syncthreads();
  if (threadIdx.x == 0) {
    float S = 0.f, SS = 0.f;
    for (int w = 0; w < 4; ++w) { S += red[0][w]; SS += red[1][w]; }
    part[(b*128 + blk)*2] = S; part[(b*128 + blk)*2 + 1] = SS;
  }
}

__global__ void ln_final(const float* __restrict__ part, float* __restrict__ stats) {
  int b = blockIdx.x, lid = threadIdx.x;
  float s = 0.f, ss = 0.f;
  for (int i = lid; i < 128; i += 64) { s += part[(b*128+i)*2]; ss += part[(b*128+i)*2+1]; }
  #pragma unroll
  for (int o = 32; o; o >>= 1) { s += __shfl_down(s, o); ss += __shfl_down(ss, o); }
  if (lid == 0) {
    float mean = s / (float)NPB;
    float var = ss / (float)NPB - mean*mean;
    stats[b*2] = mean; stats[b*2+1] = rsqrtf(var + 1e-5f);
  }
}

__global__ void ln_apply3(const float* __restrict__ x, const float* __restrict__ lnw,
                          const float* __restrict__ lnb, const float* __restrict__ stats,
                          bf16* __restrict__ th, bf16* __restrict__ tl, long ts)
{
  __shared__ float tile[32][33];
  int b = blockIdx.z;
  int s0 = blockIdx.x*32, c0 = blockIdx.y*32;
  float mean = stats[b*2], rstd = stats[b*2+1];
  int tx = threadIdx.x, ty = threadIdx.y;
  #pragma unroll
  for (int i = 0; i < 32; i += 8) {
    int c = c0 + ty + i, s = s0 + tx;
    if (s < S_) {
      long o = (long)c*S_ + s;
      tile[ty+i][tx] = (x[(long)b*NPB + o] - mean)*rstd*lnw[o] + lnb[o];
    }
  }
  __syncthreads();
  #pragma unroll
  for (int i = 0; i < 32; i += 8) {
    int s = s0 + ty + i, c = c0 + tx;
    if (s < S_) {
      float v = tile[tx][ty+i];
      bf16 h = __float2bfloat16(v);
      long o = ((long)b*S_ + s)*ts + c;
      th[o] = h;
      tl[o] = __float2bfloat16(v - __bfloat162float(h));
    }
  }
}

// ---------------- V transpose (bf16), zero pad t in [S_, SPAD) ----------------
__global__ void vtrans(const bf16* __restrict__ qkv, bf16* __restrict__ VT) {
  __shared__ float tile[32][33];
  int z = blockIdx.z; int bb = z >> 3, h = z & 7;
  const bf16* v = qkv + (long)bb*S_*C3 + 1536 + h*DH_;
  bf16* o = VT + (long)z*DH_*SPAD;
  int t0 = blockIdx.y*32, d0 = blockIdx.x*32;
  int tx = threadIdx.x, ty = threadIdx.y;
  #pragma unroll
  for (int i = 0; i < 32; i += 8) {
    int t = t0 + ty + i, d = d0 + tx;
    float val = 0.f;
    if (t < S_ && d < DH_) val = __bfloat162float(v[(long)t*C3 + d]);
    tile[ty+i][tx] = val;
  }
  __syncthreads();
  #pragma unroll
  for (int i = 0; i < 32; i += 8) {
    int d = d0 + ty + i, t = t0 + tx;
    if (d < DH_ && t < SPAD) o[(long)d*SPAD + t] = __float2bfloat16(tile[tx][ty+i]);
  }
}

// -------- softmax over bf16 hi/lo score rows, IN PLACE (row stride 2*SPAD) --------
__global__ void softmax3p(bf16* __restrict__ scores, int nrows) {
  int row = blockIdx.x*4 + (threadIdx.x >> 6);
  if (row >= nrows) return;
  int lid = threadIdx.x & 63;
  bf16* ph = scores + (long)row*2*SPAD;
  bf16* pl = ph + SPAD;
  float vals[12];
  float mx = -1e30f;
  #pragma unroll
  for (int i = 0; i < 12; ++i) {
    int t = i*64 + lid;
    float v = -1e30f;
    if (t < S_) v = __bfloat162float(ph[t]) + __bfloat162float(pl[t]);
    vals[i] = v; mx = fmaxf(mx, v);
  }
  #pragma unroll
  for (int o = 32; o; o >>= 1) mx = fmaxf(mx, __shfl_xor(mx, o));
  float sum = 0.f;
  #pragma unroll
  for (int i = 0; i < 12; ++i) { float e = __expf(vals[i] - mx); vals[i] = e; sum += e; }
  #pragma unroll
  for (int o = 32; o; o >>= 1) sum += __shfl_xor(sum, o);
  float inv = 1.f / sum;
  #pragma unroll
  for (int i = 0; i < 12; ++i) {
    int t = i*64 + lid;
    if (t < SPAD) {
      float p = (t < S_) ? vals[i]*inv : 0.f;
      bf16 h = __float2bfloat16(p);
      ph[t] = h;
      pl[t] = __float2bfloat16(p - __bfloat162float(h));
    }
  }
}

// ---------------- residual transpose-add 1 ----------------
__global__ void tadd1(const float* __restrict__ x, const float* __restrict__ oproj,
                      float* __restrict__ xattn, bf16* __restrict__ tok2,
                      float* __restrict__ tok2f)
{
  __shared__ float t_o[32][33];
  __shared__ float t_x[32][33];
  int b = blockIdx.z;
  int s0 = blockIdx.x*32, c0 = blockIdx.y*32;
  int tx = threadIdx.x, ty = threadIdx.y;
  #pragma unroll
  for (int i = 0; i < 32; i += 8) {
    int s = s0 + ty + i;
    if (s < S_) t_o[ty+i][tx] = oproj[((long)b*S_ + s)*C_ + c0 + tx];
    int s2 = s0 + tx;
    if (s2 < S_) t_x[ty+i][tx] = x[(long)b*NPB + (long)(c0+ty+i)*S_ + s2];
  }
  __syncthreads();
  #pragma unroll
  for (int i = 0; i < 32; i += 8) {
    int s = s0 + tx, c = c0 + ty + i;
    if (s < S_) xattn[(long)b*NPB + (long)c*S_ + s] = t_x[ty+i][tx] + t_o[tx][ty+i];
    int s2 = s0 + ty + i, c2 = c0 + tx;
    if (s2 < S_) {
      float v = t_x[tx][ty+i] + t_o[ty+i][tx];
      long o = ((long)b*S_ + s2)*C_ + c2;
      tok2[o] = __float2bfloat16(v);
      tok2f[o] = v;
    }
  }
}

// ---- residual transpose-add 2 (final output), sums 8 bf16 down-partials ----
__global__ void tadd2(const float* __restrict__ xattn, const bf16* __restrict__ prt,
                      float* __restrict__ out)
{
  __shared__ float t_m[32][33];
  __shared__ float t_x[32][33];
  int b = blockIdx.z;
  int s0 = blockIdx.x*32, c0 = blockIdx.y*32;
  int tx = threadIdx.x, ty = threadIdx.y;
  #pragma unroll
  for (int i = 0; i < 32; i += 8) {
    int s = s0 + ty + i;
    if (s < S_) {
      const bf16* p = prt + ((long)b*S_ + s)*768 + c0 + tx;
      float acc = 0.f;
      #pragma unroll
      for (int z = 0; z < 8; ++z) acc += __bfloat162float(p[(long)z*MTOK*768]);
      t_m[ty+i][tx] = acc;
    }
    int s2 = s0 + tx;
    if (s2 < S_) t_x[ty+i][tx] = xattn[(long)b*NPB + (long)(c0+ty+i)*S_ + s2];
  }
  __syncthreads();
  #pragma unroll
  for (int i = 0; i < 32; i += 8) {
    int s = s0 + tx, c = c0 + ty + i;
    if (s < S_) out[(long)b*NPB + (long)c*S_ + s] = t_x[ty+i][tx] + t_m[tx][ty+i];
  }
}

// ---------------- router: top-2 of 3 from fp32 tok2, normalized weights ----------------
__global__ void router_k(const float* __restrict__ tok2f, const float* __restrict__ rw,
                         float* __restrict__ wfull)
{
  int t = blockIdx.x*4 + (threadIdx.x >> 6);
  if (t >= MTOK) return;
  int lid = threadIdx.x & 63;
  const float* tk = tok2f + (long)t*C_;
  float a0 = 0.f, a1 = 0.f, a2 = 0.f;
  for (int i = lid; i < C_; i += 64) {
    float v = tk[i];
    a0 += v*rw[i*3+0]; a1 += v*rw[i*3+1]; a2 += v*rw[i*3+2];
  }
  #pragma unroll
  for (int o = 32; o; o >>= 1) {
    a0 += __shfl_xor(a0, o); a1 += __shfl_xor(a1, o); a2 += __shfl_xor(a2, o);
  }
  if (lid == 0) {
    float m = fmaxf(a0, fmaxf(a1, a2));
    float e0 = __expf(a0-m), e1 = __expf(a1-m), e2 = __expf(a2-m);
    int emin = 0; float pm = e0;
    if (e1 <= pm) { pm = e1; emin = 1; }
    if (e2 <= pm) { pm = e2; emin = 2; }
    float rest = e0 + e1 + e2 - pm;
    wfull[t*3+0] = (emin == 0) ? 0.f : e0/rest;
    wfull[t*3+1] = (emin == 1) ? 0.f : e1/rest;
    wfull[t*3+2] = (emin == 2) ? 0.f : e2/rest;
  }
}

// =============================== host ===============================
static inline void launch_gemm3(hipStream_t st,
    const bf16* Ah, const bf16* Al, long a_rs, long a_oo, long a_oi,
    const bf16* Bh, const bf16* Bl, long b_rs, long b_oo, long b_oi,
    float* Cf, bf16* Ch, bf16* Cl, long c_rs, long c_oo, long c_oi,
    int M, int N, int K, int nlim, int zdiv, int nz)
{
  dim3 g((N + 127)/128, (M + 127)/128, nz);
  gemm3_bt<<<g, 256, 0, st>>>(Ah, Al, a_rs, a_oo, a_oi, Bh, Bl, b_rs, b_oo, b_oi,
                              Cf, Ch, Cl, c_rs, c_oo, c_oi, M, N, K, nlim, zdiv);
}

extern "C" void kernel_launch(void* const* d_in, const int* in_sizes, int n_in,
                              void* d_out, int out_size, void* d_ws, size_t ws_size,
                              hipStream_t stream)
{
  const float* x      = (const float*)d_in[0];
  const float* ln_w   = (const float*)d_in[1];
  const float* ln_b   = (const float*)d_in[2];
  const float* qkv_w  = (const float*)d_in[3];
  const float* proj_w = (const float*)d_in[4];
  const float* rout_w = (const float*)d_in[5];
  const float* gate_w = (const float*)d_in[6];
  const float* up_w   = (const float*)d_in[7];
  const float* down_w = (const float*)d_in[8];
  float* out = (float*)d_out;

  char* ws = (char*)d_ws;
  size_t off = 0;
  auto alloc = [&](size_t bytes) { size_t r = off; off += (bytes + 255) & ~(size_t)255; return r; };

  // persistent (~82.6 MB)
  size_t o_stats = alloc(8*2*4);
  size_t o_part  = alloc(8*128*2*4);
  size_t o_wfull = alloc((size_t)MTOK*3*4);
  size_t o_qkvTh = alloc((size_t)C3*C_*2);
  size_t o_qkvTl = alloc((size_t)C3*C_*2);
  size_t o_prjTh = alloc((size_t)C_*C_*2);
  size_t o_prjTl = alloc((size_t)C_*C_*2);
  size_t o_guT   = alloc((size_t)GUN*C_*2);      // gate/up 16-row interleaved
  size_t o_downT = alloc((size_t)C_*DK*2);
  size_t o_xattn = alloc((size_t)B_*NPB*4);
  size_t o_tok2  = alloc((size_t)MTOK*C_*2);
  size_t o_tok2f = alloc((size_t)MTOK*C_*4);
  size_t big0 = off;
  // phase A (attention): fixed buffers + union region (tok | scores | oproj)
  size_t o_qkvh  = alloc((size_t)MTOK*C3*2);
  size_t o_qkvl  = alloc((size_t)MTOK*C3*2);
  size_t o_VTh   = alloc((size_t)64*DH_*SPAD*2);
  size_t o_VTl   = alloc((size_t)64*DH_*SPAD*2);
  size_t o_aoh   = alloc((size_t)MTOK*C_*2);
  size_t o_aol   = alloc((size_t)MTOK*C_*2);
  size_t o_union = alloc((size_t)32*S_*SPAD*4);  // 68.7 MB
  size_t endA = off;
  // phase B (MoE): hidden + 8 bf16 partials
  off = big0;
  size_t o_hid = alloc((size_t)MTOK*DK*2);
  size_t o_prt = alloc((size_t)8*MTOK*768*2);
  size_t endB = off;
  size_t needed = endA > endB ? endA : endB;
  if (ws_size < needed) return;  // insufficient workspace: visible failure

  float* stats  = (float*)(ws + o_stats);
  float* part   = (float*)(ws + o_part);
  float* wfull  = (float*)(ws + o_wfull);
  bf16*  qkvTh  = (bf16*)(ws + o_qkvTh);
  bf16*  qkvTl  = (bf16*)(ws + o_qkvTl);
  bf16*  prjTh  = (bf16*)(ws + o_prjTh);
  bf16*  prjTl  = (bf16*)(ws + o_prjTl);
  bf16*  guT    = (bf16*)(ws + o_guT);
  bf16*  downT  = (bf16*)(ws + o_downT);
  float* xattn  = (float*)(ws + o_xattn);
  bf16*  tok2   = (bf16*)(ws + o_tok2);
  float* tok2f  = (float*)(ws + o_tok2f);
  bf16*  qkvh   = (bf16*)(ws + o_qkvh);
  bf16*  qkvl   = (bf16*)(ws + o_qkvl);
  bf16*  VTh    = (bf16*)(ws + o_VTh);
  bf16*  VTl    = (bf16*)(ws + o_VTl);
  bf16*  aoh    = (bf16*)(ws + o_aoh);
  bf16*  aol    = (bf16*)(ws + o_aol);
  // union region occupants (live ranges disjoint in stream order):
  bf16*  tokh   = (bf16*)(ws + o_union);
  bf16*  tokl   = (bf16*)(ws + o_union + (size_t)MTOK*C_*2);
  bf16*  Pbase  = (bf16*)(ws + o_union);
  float* oproj  = (float*)(ws + o_union);
  bf16*  hidden = (bf16*)(ws + o_hid);
  bf16*  prt    = (bf16*)(ws + o_prt);

  dim3 b32(32, 8);

  // weight conversions (gate/up 16-row interleaved per 32-row block of guT)
  wtrans3<<<dim3(72,24,1), b32, 0, stream>>>(qkv_w,  qkvTh, qkvTl, 768, 2304, 2304, 768);
  wtrans3<<<dim3(24,24,1), b32, 0, stream>>>(proj_w, prjTh, prjTl, 768, 768,  768,  768);
  wtrans<<<dim3(64,24,3), b32, 0, stream>>>(gate_w, guT, 768, 2048, 2048, 768,
                                            (long)768*2048, (long)4096*768, 1, 0);
  wtrans<<<dim3(64,24,3), b32, 0, stream>>>(up_w, guT, 768, 2048, 2048, 768,
                                            (long)768*2048, (long)4096*768, 1, 16);
  wtrans<<<dim3(24,64,3), b32, 0, stream>>>(down_w, downT, 2048, 768, 768, 6144,
                                            (long)2048*768, 2048, 0, 0);

  // LayerNorm -> tok hi/lo (b,s,c)
  ln_partial<<<dim3(128,8), 256, 0, stream>>>(x, part);
  ln_final<<<8, 64, 0, stream>>>(part, stats);
  ln_apply3<<<dim3(23,24,8), b32, 0, stream>>>(x, ln_w, ln_b, stats, tokh, tokl, C_);

  // qkv = tok @ qkv_w (bf16x3, hi/lo out); tok region dead afterwards
  launch_gemm3(stream, tokh, tokl, C_, 0, 0, qkvTh, qkvTl, C_, 0, 0,
               nullptr, qkvh, qkvl, C3, 0, 0, MTOK, C3, C_, C3, 1, 1);

  // V^T per (b,h), zero-padded to SPAD (hi and lo)
  vtrans<<<dim3(3,23,64), b32, 0, stream>>>(qkvh, VTh);
  vtrans<<<dim3(3,23,64), b32, 0, stream>>>(qkvl, VTl);

  // attention in 2 chunks of 32 (b,h)-pairs (4 batches each)
  for (int c = 0; c < 2; ++c) {
    const long qoff = (long)(4*c)*S_*C3;
    launch_gemm3(stream,
        qkvh + qoff, qkvl + qoff, C3, (long)S_*C3, DH_,
        qkvh + qoff + 768, qkvl + qoff + 768, C3, (long)S_*C3, DH_,
        nullptr, Pbase, Pbase + SPAD, 2*SPAD, (long)8*S_*2*SPAD, (long)S_*2*SPAD,
        S_, S_, DH_, SPAD, 8, 32);
    softmax3p<<<5832, 256, 0, stream>>>(Pbase, 32*S_);
    launch_gemm3(stream,
        Pbase, Pbase + SPAD, 2*SPAD, (long)8*S_*2*SPAD, (long)S_*2*SPAD,
        VTh + (size_t)c*32*DH_*SPAD, VTl + (size_t)c*32*DH_*SPAD, SPAD,
        (long)8*DH_*SPAD, (long)DH_*SPAD,
        nullptr, aoh + (size_t)(4*c)*S_*C_, aol + (size_t)(4*c)*S_*C_,
        C_, (long)S_*C_, DH_,
        S_, DH_, SPAD, DH_, 8, 32);
  }

  // oproj = attnout @ proj_w (fp32 out, into union region — P dead now)
  launch_gemm3(stream, aoh, aol, C_, 0, 0, prjTh, prjTl, C_, 0, 0,
               oproj, nullptr, nullptr, C_, 0, 0, MTOK, C_, C_, C_, 1, 1);

  // residual + layouts
  tadd1<<<dim3(23,24,8), b32, 0, stream>>>(x, oproj, xattn, tok2, tok2f);

  // router weights (fp32 path) — must precede fused GU epilogue
  router_k<<<1458, 256, 0, stream>>>(tok2f, rout_w, wfull);

  // GU gemm with fused silu*up*w epilogue -> hidden [MTOK][6144]
  gemm8<<<dim3(GUN/256, 23, 1), 512, 0, stream>>>(
      tok2, C_, guT, C_, nullptr, hidden, DK, 0, MTOK, GUN, C_, wfull, 3);

  // down GEMM (K=6144) nz=8 K-split, bf16 partials
  gemm8<<<dim3(C_/256, 23, 8), 512, 0, stream>>>(
      hidden, DK, downT, DK, nullptr, prt, 768, (long)MTOK*768, MTOK, C_, DK/8,
      nullptr, 0);

  // final residual transpose-add (sums 8 partials) into output
  tadd2<<<dim3(23,24,8), b32, 0, stream>>>(xattn, prt, out);
}

// Round 13
// 782.512 us; speedup vs baseline: 1.0101x; 1.0101x over previous
//
#include <hip/hip_runtime.h>
#include <hip/hip_bf16.h>

#define C_    768
#define NH_   8
#define DH_   96
#define S_    729
#define B_    8
#define MTOK  5832
#define C3    2304
#define GUN   12288
#define DK    6144
#define SPAD  736
#define NPB   559872   // C_*S_

typedef __attribute__((ext_vector_type(8))) short short8;
typedef __attribute__((ext_vector_type(4))) float f32x4;
typedef __attribute__((ext_vector_type(4))) unsigned int uint4v;
typedef __hip_bfloat16 bf16;

__device__ __forceinline__ void gld_lds16(const bf16* g, bf16* l) {
  __builtin_amdgcn_global_load_lds((const __attribute__((address_space(1))) void*)g,
                                   (__attribute__((address_space(3))) void*)l, 16, 0, 0);
}
__device__ __forceinline__ void gld_lds16c(const char* g, char* l) {
  __builtin_amdgcn_global_load_lds((const __attribute__((address_space(1))) void*)g,
                                   (__attribute__((address_space(3))) void*)l, 16, 0, 0);
}

// ================= 256x256 8-wave 2-phase deep-pipelined GEMM =================
// Per tile: P0 {read A0-3+B0-3 from db; stage h1(t+1) -> nb; MFMA upper} bar1
//           P1 {read A4-7 from db; bar2; stage h0(t+2) -> db (overlaps MFMA);
//               MFMA lower; vmcnt; bar3}
template<int DB>
__device__ __forceinline__ void tile_step(
    char* ldsc, char* ldsw,
    const int rA0, const int rA1, const int rB0, const int rB1,
    const char* pA0, const char* pA1, const char* pA2, const char* pA3,
    const char* pB0, const char* pB1, const char* pB2, const char* pB3,
    const int s1, const int s2, const bool gH1, const bool gH0, const int wmode,
    f32x4 (&acc)[8][4], short8 (&a4)[4][2], short8 (&b4)[4][2])
{
  const int DBO = DB * 65536;
  const int NBO = 65536 - DBO;
  // ---- P0: read A0-3 + B0-3; stage full h1(t+1) -> nb; MFMA upper half ----
  #pragma unroll
  for (int mf = 0; mf < 4; ++mf) {
    a4[mf][0] = *(const short8*)(ldsc + DBO + rA0 + mf*2048);
    a4[mf][1] = *(const short8*)(ldsc + DBO + rA1 + mf*2048);
  }
  #pragma unroll
  for (int nf = 0; nf < 4; ++nf) {
    b4[nf][0] = *(const short8*)(ldsc + DBO + rB0 + nf*2048);
    b4[nf][1] = *(const short8*)(ldsc + DBO + rB1 + nf*2048);
  }
  if (gH1) {
    gld_lds16c(pA2 + s1, ldsw + NBO + 16384);
    gld_lds16c(pA3 + s1, ldsw + NBO + 16384 + 8192);
    gld_lds16c(pB2 + s1, ldsw + NBO + 32768 + 16384);
    gld_lds16c(pB3 + s1, ldsw + NBO + 32768 + 16384 + 8192);
  }
  __builtin_amdgcn_s_setprio(1);
  #pragma unroll
  for (int mf = 0; mf < 4; ++mf)
    #pragma unroll
    for (int nf = 0; nf < 4; ++nf)
      #pragma unroll
      for (int j = 0; j < 2; ++j)
        acc[mf][nf] = __builtin_amdgcn_mfma_f32_16x16x32_bf16(a4[mf][j], b4[nf][j], acc[mf][nf], 0, 0, 0);
  __builtin_amdgcn_s_setprio(0);
  __builtin_amdgcn_s_barrier();                    // bar1: all db-B + db-A-upper reads issued/done
  // ---- P1: read A4-7; bar2; stage h0(t+2) -> db; MFMA lower half ----
  #pragma unroll
  for (int mi = 0; mi < 4; ++mi) {
    a4[mi][0] = *(const short8*)(ldsc + DBO + rA0 + (4+mi)*2048);
    a4[mi][1] = *(const short8*)(ldsc + DBO + rA1 + (4+mi)*2048);
  }
  __builtin_amdgcn_s_barrier();                    // bar2: all db-A reads issued by all waves
  if (gH0) {
    gld_lds16c(pB0 + s2, ldsw + DBO + 32768);
    gld_lds16c(pB1 + s2, ldsw + DBO + 32768 + 8192);
    gld_lds16c(pA0 + s2, ldsw + DBO);
    gld_lds16c(pA1 + s2, ldsw + DBO + 8192);
  }
  __builtin_amdgcn_s_setprio(1);
  #pragma unroll
  for (int mi = 0; mi < 4; ++mi)
    #pragma unroll
    for (int nf = 0; nf < 4; ++nf)
      #pragma unroll
      for (int j = 0; j < 2; ++j)
        acc[4+mi][nf] = __builtin_amdgcn_mfma_f32_16x16x32_bf16(a4[mi][j], b4[nf][j], acc[4+mi][nf], 0, 0, 0);
  __builtin_amdgcn_s_setprio(0);
  if (wmode == 0)      asm volatile("s_waitcnt vmcnt(4)" ::: "memory");
  else if (wmode == 1) asm volatile("s_waitcnt vmcnt(0)" ::: "memory");
  __builtin_amdgcn_s_barrier();                    // bar3: tile boundary
}

// modes: 0 = bf16 out (Cb, +z*c_zoff). 1 = fp32 out (Cf, +z*c_zoff).
// 3 = fused MoE: gate/up interleaved at 16-col granularity; writes
// silu(g)*u*wfull[row*3+e] bf16 to Cb[row*c_rs + h], h = ((col32)>>5)*16+fr.
__global__ void __launch_bounds__(512, 2)
gemm8(const bf16* __restrict__ A, long a_rs,
      const bf16* __restrict__ Bt, long b_rs,
      float* __restrict__ Cf, bf16* __restrict__ Cb,
      long c_rs, long c_zoff, int M, int N, int Ksub,
      const float* __restrict__ wfull, int mode)
{
  __shared__ __attribute__((aligned(128))) char ldsc[131072];
  const int tid = threadIdx.x;
  const int wid = tid >> 6, lid = tid & 63;
  const int wm = wid >> 2, wn = wid & 3;           // 2 x 4 wave grid
  const int fr = lid & 15, g8 = (lid >> 4) * 8;
  const int brow = blockIdx.y * 256, bcol = blockIdx.x * 256;
  const long k0b = (long)blockIdx.z * Ksub * 2;
  const long a_rsb = a_rs * 2, b_rsb = b_rs * 2;
  const int srow = tid >> 3;
  const int scol = ((tid & 7) ^ (srow & 7)) << 4;
  const int NT = Ksub >> 6;
  char* ldsw = ldsc + wid * 1024;

  int ra0_ = brow + srow;        if (ra0_ > M-1) ra0_ = M-1;
  int ra1_ = brow + 64 + srow;   if (ra1_ > M-1) ra1_ = M-1;
  int ra2_ = brow + 128 + srow;  if (ra2_ > M-1) ra2_ = M-1;
  int ra3_ = brow + 192 + srow;  if (ra3_ > M-1) ra3_ = M-1;
  int rb0_ = bcol + srow;        if (rb0_ > N-1) rb0_ = N-1;
  int rb1_ = bcol + 64 + srow;   if (rb1_ > N-1) rb1_ = N-1;
  int rb2_ = bcol + 128 + srow;  if (rb2_ > N-1) rb2_ = N-1;
  int rb3_ = bcol + 192 + srow;  if (rb3_ > N-1) rb3_ = N-1;
  const char* pA0 = (const char*)A + (long)ra0_*a_rsb + k0b + scol;
  const char* pA1 = (const char*)A + (long)ra1_*a_rsb + k0b + scol;
  const char* pA2 = (const char*)A + (long)ra2_*a_rsb + k0b + scol;
  const char* pA3 = (const char*)A + (long)ra3_*a_rsb + k0b + scol;
  const char* pB0 = (const char*)Bt + (long)rb0_*b_rsb + k0b + scol;
  const char* pB1 = (const char*)Bt + (long)rb1_*b_rsb + k0b + scol;
  const char* pB2 = (const char*)Bt + (long)rb2_*b_rsb + k0b + scol;
  const char* pB3 = (const char*)Bt + (long)rb3_*b_rsb + k0b + scol;

  const int swz = (fr & 7) << 4;
  const int cx0 = (g8 * 2) ^ swz;
  const int cx1 = (64 + g8 * 2) ^ swz;
  const int rA0 = (wm*128 + fr)*128 + cx0;
  const int rA1 = (wm*128 + fr)*128 + cx1;
  const int rB0 = 32768 + (wn*64 + fr)*128 + cx0;
  const int rB1 = 32768 + (wn*64 + fr)*128 + cx1;

  f32x4 acc[8][4] = {};
  short8 a4[4][2], b4[4][2];

  gld_lds16c(pA0, ldsw);
  gld_lds16c(pA1, ldsw + 8192);
  gld_lds16c(pA2, ldsw + 16384);
  gld_lds16c(pA3, ldsw + 16384 + 8192);
  gld_lds16c(pB0, ldsw + 32768);
  gld_lds16c(pB1, ldsw + 32768 + 8192);
  gld_lds16c(pB2, ldsw + 32768 + 16384);
  gld_lds16c(pB3, ldsw + 32768 + 16384 + 8192);
  gld_lds16c(pA0 + 128, ldsw + 65536);
  gld_lds16c(pA1 + 128, ldsw + 65536 + 8192);
  gld_lds16c(pB0 + 128, ldsw + 65536 + 32768);
  gld_lds16c(pB1 + 128, ldsw + 65536 + 32768 + 8192);
  asm volatile("s_waitcnt vmcnt(4)" ::: "memory");
  __builtin_amdgcn_s_barrier();

  for (int tp = 0; tp < NT; tp += 2) {
    const bool g2 = (tp + 2) < NT;
    tile_step<0>(ldsc, ldsw, rA0, rA1, rB0, rB1,
                 pA0, pA1, pA2, pA3, pB0, pB1, pB2, pB3,
                 128, 256, true, g2, g2 ? 0 : 1, acc, a4, b4);
    tile_step<1>(ldsc, ldsw, rA0, rA1, rB0, rB1,
                 pA0, pA1, pA2, pA3, pB0, pB1, pB2, pB3,
                 256, 384, g2, g2, g2 ? 0 : 2, acc, a4, b4);
    if (g2) {
      pA0 += 256; pA1 += 256; pA2 += 256; pA3 += 256;
      pB0 += 256; pB1 += 256; pB2 += 256; pB3 += 256;
    }
  }

  const int rg = (lid >> 4) * 4;
  if (mode == 3) {
    // fused silu(gate)*up*w epilogue; gate=acc[*][even nf], up=acc[*][odd nf]
    #pragma unroll
    for (int mf = 0; mf < 8; ++mf) {
      #pragma unroll
      for (int np = 0; np < 2; ++np) {
        const int hb = (bcol + wn*64 + np*32) >> 5;   // 32-row block index
        const int h = hb*16 + fr;
        const int e = h >> 11;                         // expert = h / 2048
        #pragma unroll
        for (int j = 0; j < 4; ++j) {
          const int row = brow + wm*128 + mf*16 + rg + j;
          if (row < M) {
            float g = acc[mf][2*np][j];
            float u = acc[mf][2*np+1][j];
            float w = wfull[row*3 + e];
            float sg = g / (1.f + __expf(-g));
            Cb[(long)row*c_rs + h] = __float2bfloat16(sg * u * w);
          }
        }
      }
    }
  } else {
    #pragma unroll
    for (int mf = 0; mf < 8; ++mf) {
      #pragma unroll
      for (int nf = 0; nf < 4; ++nf) {
        const int col = bcol + wn*64 + nf*16 + fr;
        if (col < N) {
          #pragma unroll
          for (int j = 0; j < 4; ++j) {
            const int row = brow + wm*128 + mf*16 + rg + j;
            if (row < M) {
              long off = (long)blockIdx.z*c_zoff + (long)row*c_rs + col;
              if (mode == 0) Cb[off] = __float2bfloat16(acc[mf][nf][j]);
              else           Cf[off] = acc[mf][nf][j];
            }
          }
        }
      }
    }
  }
}

// ---------------- bf16x3 split GEMM: A=(Ah+Al), B=(Bh+Bl), 3 products ----------------
__global__ void __launch_bounds__(256)
gemm3_bt(const bf16* __restrict__ Ah, const bf16* __restrict__ Al,
         long a_rs, long a_oo, long a_oi,
         const bf16* __restrict__ Bth, const bf16* __restrict__ Btl,
         long b_rs, long b_oo, long b_oi,
         float* __restrict__ Cf, bf16* __restrict__ Ch, bf16* __restrict__ Cl,
         long c_rs, long c_oo, long c_oi,
         int M, int N, int K, int nlim, int zdiv)
{
  __shared__ bf16 lAh[4096];
  __shared__ bf16 lAl[4096];
  __shared__ bf16 lBh[4096];
  __shared__ bf16 lBl[4096];
  const int tid = threadIdx.x;
  const int wid = tid >> 6;
  const int lid = tid & 63;
  const int z = blockIdx.z;
  const int zo = z / zdiv, zi = z - zo*zdiv;
  const long aoff = (long)zo*a_oo + (long)zi*a_oi;
  const long boff = (long)zo*b_oo + (long)zi*b_oi;
  const long cbase = (long)zo*c_oo + (long)zi*c_oi;
  const int brow = blockIdx.y * 128;
  const int bcol = blockIdx.x * 128;

  const int ch0 = tid, ch1 = tid + 256;
  int ra0 = brow + (ch0 >> 2); if (ra0 > M-1) ra0 = M-1;
  int ra1 = brow + (ch1 >> 2); if (ra1 > M-1) ra1 = M-1;
  int rb0 = bcol + (ch0 >> 2); if (rb0 > N-1) rb0 = N-1;
  int rb1 = bcol + (ch1 >> 2); if (rb1 > N-1) rb1 = N-1;
  const int sw = ((ch0 ^ (ch0 >> 2)) & 3) * 8;
  const long ia0 = aoff + (long)ra0*a_rs + sw;
  const long ia1 = aoff + (long)ra1*a_rs + sw;
  const long ib0 = boff + (long)rb0*b_rs + sw;
  const long ib1 = boff + (long)rb1*b_rs + sw;
  bf16* dAh0 = (bf16*)((char*)lAh + wid*1024);
  bf16* dAh1 = (bf16*)((char*)lAh + 4096 + wid*1024);
  bf16* dAl0 = (bf16*)((char*)lAl + wid*1024);
  bf16* dAl1 = (bf16*)((char*)lAl + 4096 + wid*1024);
  bf16* dBh0 = (bf16*)((char*)lBh + wid*1024);
  bf16* dBh1 = (bf16*)((char*)lBh + 4096 + wid*1024);
  bf16* dBl0 = (bf16*)((char*)lBl + wid*1024);
  bf16* dBl1 = (bf16*)((char*)lBl + 4096 + wid*1024);

  f32x4 acc[4][4] = {};
  const int wm = wid >> 1, wn = wid & 1;
  const int fr = lid & 15, g8 = (lid >> 4) * 8;
  const int gx = g8 ^ ((lid & 3) << 3);

  for (int kt = 0; kt < K; kt += 32) {
    __syncthreads();
    gld_lds16(Ah + ia0 + kt, dAh0);
    gld_lds16(Ah + ia1 + kt, dAh1);
    gld_lds16(Al + ia0 + kt, dAl0);
    gld_lds16(Al + ia1 + kt, dAl1);
    gld_lds16(Bth + ib0 + kt, dBh0);
    gld_lds16(Bth + ib1 + kt, dBh1);
    gld_lds16(Btl + ib0 + kt, dBl0);
    gld_lds16(Btl + ib1 + kt, dBl1);
    __syncthreads();
    short8 fah[4], fal[4], fbh[4], fbl[4];
    #pragma unroll
    for (int m = 0; m < 4; ++m) {
      int ro = (wm*64 + m*16 + fr)*32 + gx;
      fah[m] = *(const short8*)&lAh[ro];
      fal[m] = *(const short8*)&lAl[ro];
    }
    #pragma unroll
    for (int n = 0; n < 4; ++n) {
      int ro = (wn*64 + n*16 + fr)*32 + gx;
      fbh[n] = *(const short8*)&lBh[ro];
      fbl[n] = *(const short8*)&lBl[ro];
    }
    #pragma unroll
    for (int m = 0; m < 4; ++m)
      #pragma unroll
      for (int n = 0; n < 4; ++n) {
        acc[m][n] = __builtin_amdgcn_mfma_f32_16x16x32_bf16(fal[m], fbh[n], acc[m][n], 0, 0, 0);
        acc[m][n] = __builtin_amdgcn_mfma_f32_16x16x32_bf16(fah[m], fbl[n], acc[m][n], 0, 0, 0);
        acc[m][n] = __builtin_amdgcn_mfma_f32_16x16x32_bf16(fah[m], fbh[n], acc[m][n], 0, 0, 0);
      }
  }

  const int rg = (lid >> 4) * 4;
  #pragma unroll
  for (int m = 0; m < 4; ++m) {
    #pragma unroll
    for (int n = 0; n < 4; ++n) {
      const int col = bcol + wn*64 + n*16 + fr;
      if (col < nlim) {
        #pragma unroll
        for (int j = 0; j < 4; ++j) {
          const int row = brow + wm*64 + m*16 + rg + j;
          if (row < M) {
            long off = cbase + (long)row*c_rs + col;
            float v = acc[m][n][j];
            if (Cl) {
              bf16 h = __float2bfloat16(v);
              Ch[off] = h;
              Cl[off] = __float2bfloat16(v - __bfloat162float(h));
            } else if (Ch) {
              Ch[off] = __float2bfloat16(v);
            } else {
              Cf[off] = v;
            }
          }
        }
      }
    }
  }
}

// ---------------- weight transpose fp32 -> bf16 (opt. 16-row interleave) ----------------
__global__ void wtrans(const float* __restrict__ in, bf16* __restrict__ out,
                       int R, int Cc, long in_rs, long out_rs, long in_bs, long out_bs,
                       int ilv, int radd)
{
  __shared__ float tile[32][33];
  in  += (long)blockIdx.z * in_bs;
  out += (long)blockIdx.z * out_bs;
  int r0 = blockIdx.y*32, c0 = blockIdx.x*32;
  int tx = threadIdx.x, ty = threadIdx.y;
  #pragma unroll
  for (int i = 0; i < 32; i += 8) {
    int r = r0 + ty + i, c = c0 + tx;
    if (r < R && c < Cc) tile[ty+i][tx] = in[(long)r*in_rs + c];
  }
  __syncthreads();
  #pragma unroll
  for (int i = 0; i < 32; i += 8) {
    int ro = c0 + ty + i, co = r0 + tx;
    if (ro < Cc && co < R) {
      int rr = ilv ? (((ro >> 4) << 5) + (ro & 15) + radd) : ro;
      out[(long)rr*out_rs + co] = __float2bfloat16(tile[tx][ty+i]);
    }
  }
}

// ---------------- weight transpose fp32 -> bf16 hi/lo pair ----------------
__global__ void wtrans3(const float* __restrict__ in, bf16* __restrict__ oh, bf16* __restrict__ ol,
                        int R, int Cc, long in_rs, long out_rs)
{
  __shared__ float tile[32][33];
  int r0 = blockIdx.y*32, c0 = blockIdx.x*32;
  int tx = threadIdx.x, ty = threadIdx.y;
  #pragma unroll
  for (int i = 0; i < 32; i += 8) {
    int r = r0 + ty + i, c = c0 + tx;
    if (r < R && c < Cc) tile[ty+i][tx] = in[(long)r*in_rs + c];
  }
  __syncthreads();
  #pragma unroll
  for (int i = 0; i < 32; i += 8) {
    int ro = c0 + ty + i, co = r0 + tx;
    if (ro < Cc && co < R) {
      float v = tile[tx][ty+i];
      bf16 h = __float2bfloat16(v);
      long o = (long)ro*out_rs + co;
      oh[o] = h;
      ol[o] = __float2bfloat16(v - __bfloat162float(h));
    }
  }
}

// ---------------- LayerNorm ----------------
__global__ void ln_partial(const float* __restrict__ x, float* __restrict__ part) {
  int b = blockIdx.y, blk = blockIdx.x;
  const float* xb = x + (long)b*NPB;
  int start = blk * 4374;
  float s = 0.f, ss = 0.f;
  for (int i = start + threadIdx.x; i < start + 4374; i += 256) {
    float v = xb[i]; s += v; ss += v*v;
  }
  #pragma unroll
  for (int o = 32; o; o >>= 1) { s += __shfl_down(s, o); ss += __shfl_down(ss, o); }
  __shared__ float red[2][4];
  int wid = threadIdx.x >> 6, lid = threadIdx.x & 63;
  if (lid == 0) { red[0][wid] = s; red[1][wid] = ss; }
  __syncthreads();
  if (threadIdx.x == 0) {
    float S = 0.f, SS = 0.f;
    for (int w = 0; w < 4; ++w) { S += red[0][w]; SS += red[1][w]; }
    part[(b*128 + blk)*2] = S; part[(b*128 + blk)*2 + 1] = SS;
  }
}

__global__ void ln_final(const float* __restrict__ part, float* __restrict__ stats) {
  int b = blockIdx.x, lid = threadIdx.x;
  float s = 0.f, ss = 0.f;
  for (int i = lid; i < 128; i += 64) { s += part[(b*128+i)*2]; ss += part[(b*128+i)*2+1]; }
  #pragma unroll
  for (int o = 32; o; o >>= 1) { s += __shfl_down(s, o); ss += __shfl_down(ss, o); }
  if (lid == 0) {
    float mean = s / (float)NPB;
    float var = ss / (float)NPB - mean*mean;
    stats[b*2] = mean; stats[b*2+1] = rsqrtf(var + 1e-5f);
  }
}

__global__ void ln_apply3(const float* __restrict__ x, const float* __restrict__ lnw,
                          const float* __restrict__ lnb, const float* __restrict__ stats,
                          bf16* __restrict__ th, bf16* __restrict__ tl, long ts)
{
  __shared__ float tile[32][33];
  int b = blockIdx.z;
  int s0 = blockIdx.x*32, c0 = blockIdx.y*32;
  float mean = stats[b*2], rstd = stats[b*2+1];
  int tx = threadIdx.x, ty = threadIdx.y;
  #pragma unroll
  for (int i = 0; i < 32; i += 8) {
    int c = c0 + ty + i, s = s0 + tx;
    if (s < S_) {
      long o = (long)c*S_ + s;
      tile[ty+i][tx] = (x[(long)b*NPB + o] - mean)*rstd*lnw[o] + lnb[o];
    }
  }
  __syncthreads();
  #pragma unroll
  for (int i = 0; i < 32; i += 8) {
    int s = s0 + ty + i, c = c0 + tx;
    if (s < S_) {
      float v = tile[tx][ty+i];
      bf16 h = __float2bfloat16(v);
      long o = ((long)b*S_ + s)*ts + c;
      th[o] = h;
      tl[o] = __float2bfloat16(v - __bfloat162float(h));
    }
  }
}

// ------- V transpose (bf16), hi (z<64) and lo (z>=64), zero pad t in [S_, SPAD) -------
__global__ void vtrans2(const bf16* __restrict__ qkvh, const bf16* __restrict__ qkvl,
                        bf16* __restrict__ VTh, bf16* __restrict__ VTl)
{
  __shared__ float tile[32][33];
  int z = blockIdx.z;
  const bf16* qkv = (z < 64) ? qkvh : qkvl;
  bf16* VT = (z < 64) ? VTh : VTl;
  int zz = z & 63;
  int bb = zz >> 3, h = zz & 7;
  const bf16* v = qkv + (long)bb*S_*C3 + 1536 + h*DH_;
  bf16* o = VT + (long)zz*DH_*SPAD;
  int t0 = blockIdx.y*32, d0 = blockIdx.x*32;
  int tx = threadIdx.x, ty = threadIdx.y;
  #pragma unroll
  for (int i = 0; i < 32; i += 8) {
    int t = t0 + ty + i, d = d0 + tx;
    float val = 0.f;
    if (t < S_ && d < DH_) val = __bfloat162float(v[(long)t*C3 + d]);
    tile[ty+i][tx] = val;
  }
  __syncthreads();
  #pragma unroll
  for (int i = 0; i < 32; i += 8) {
    int d = d0 + ty + i, t = t0 + tx;
    if (d < DH_ && t < SPAD) o[(long)d*SPAD + t] = __float2bfloat16(tile[tx][ty+i]);
  }
}

// -------- softmax over bf16 hi/lo score rows, IN PLACE (row stride 2*SPAD) --------
__global__ void softmax3p(bf16* __restrict__ scores, int nrows) {
  int row = blockIdx.x*4 + (threadIdx.x >> 6);
  if (row >= nrows) return;
  int lid = threadIdx.x & 63;
  bf16* ph = scores + (long)row*2*SPAD;
  bf16* pl = ph + SPAD;
  float vals[12];
  float mx = -1e30f;
  #pragma unroll
  for (int i = 0; i < 12; ++i) {
    int t = i*64 + lid;
    float v = -1e30f;
    if (t < S_) v = __bfloat162float(ph[t]) + __bfloat162float(pl[t]);
    vals[i] = v; mx = fmaxf(mx, v);
  }
  #pragma unroll
  for (int o = 32; o; o >>= 1) mx = fmaxf(mx, __shfl_xor(mx, o));
  float sum = 0.f;
  #pragma unroll
  for (int i = 0; i < 12; ++i) { float e = __expf(vals[i] - mx); vals[i] = e; sum += e; }
  #pragma unroll
  for (int o = 32; o; o >>= 1) sum += __shfl_xor(sum, o);
  float inv = 1.f / sum;
  #pragma unroll
  for (int i = 0; i < 12; ++i) {
    int t = i*64 + lid;
    if (t < SPAD) {
      float p = (t < S_) ? vals[i]*inv : 0.f;
      bf16 h = __float2bfloat16(p);
      ph[t] = h;
      pl[t] = __float2bfloat16(p - __bfloat162float(h));
    }
  }
}

// ---------------- residual transpose-add 1 ----------------
__global__ void tadd1(const float* __restrict__ x, const float* __restrict__ oproj,
                      float* __restrict__ xattn, bf16* __restrict__ tok2,
                      float* __restrict__ tok2f)
{
  __shared__ float t_o[32][33];
  __shared__ float t_x[32][33];
  int b = blockIdx.z;
  int s0 = blockIdx.x*32, c0 = blockIdx.y*32;
  int tx = threadIdx.x, ty = threadIdx.y;
  #pragma unroll
  for (int i = 0; i < 32; i += 8) {
    int s = s0 + ty + i;
    if (s < S_) t_o[ty+i][tx] = oproj[((long)b*S_ + s)*C_ + c0 + tx];
    int s2 = s0 + tx;
    if (s2 < S_) t_x[ty+i][tx] = x[(long)b*NPB + (long)(c0+ty+i)*S_ + s2];
  }
  __syncthreads();
  #pragma unroll
  for (int i = 0; i < 32; i += 8) {
    int s = s0 + tx, c = c0 + ty + i;
    if (s < S_) xattn[(long)b*NPB + (long)c*S_ + s] = t_x[ty+i][tx] + t_o[tx][ty+i];
    int s2 = s0 + ty + i, c2 = c0 + tx;
    if (s2 < S_) {
      float v = t_x[tx][ty+i] + t_o[ty+i][tx];
      long o = ((long)b*S_ + s2)*C_ + c2;
      tok2[o] = __float2bfloat16(v);
      tok2f[o] = v;
    }
  }
}

// ---- residual transpose-add 2 (final output), sums 8 bf16 down-partials ----
__global__ void tadd2(const float* __restrict__ xattn, const bf16* __restrict__ prt,
                      float* __restrict__ out)
{
  __shared__ float t_m[32][33];
  __shared__ float t_x[32][33];
  int b = blockIdx.z;
  int s0 = blockIdx.x*32, c0 = blockIdx.y*32;
  int tx = threadIdx.x, ty = threadIdx.y;
  #pragma unroll
  for (int i = 0; i < 32; i += 8) {
    int s = s0 + ty + i;
    if (s < S_) {
      const bf16* p = prt + ((long)b*S_ + s)*768 + c0 + tx;
      float acc = 0.f;
      #pragma unroll
      for (int z = 0; z < 8; ++z) acc += __bfloat162float(p[(long)z*MTOK*768]);
      t_m[ty+i][tx] = acc;
    }
    int s2 = s0 + tx;
    if (s2 < S_) t_x[ty+i][tx] = xattn[(long)b*NPB + (long)(c0+ty+i)*S_ + s2];
  }
  __syncthreads();
  #pragma unroll
  for (int i = 0; i < 32; i += 8) {
    int s = s0 + tx, c = c0 + ty + i;
    if (s < S_) out[(long)b*NPB + (long)c*S_ + s] = t_x[ty+i][tx] + t_m[tx][ty+i];
  }
}

// ---------------- router: top-2 of 3 from fp32 tok2, normalized weights ----------------
__global__ void router_k(const float* __restrict__ tok2f, const float* __restrict__ rw,
                         float* __restrict__ wfull)
{
  int t = blockIdx.x*4 + (threadIdx.x >> 6);
  if (t >= MTOK) return;
  int lid = threadIdx.x & 63;
  const float* tk = tok2f + (long)t*C_;
  float a0 = 0.f, a1 = 0.f, a2 = 0.f;
  for (int i = lid; i < C_; i += 64) {
    float v = tk[i];
    a0 += v*rw[i*3+0]; a1 += v*rw[i*3+1]; a2 += v*rw[i*3+2];
  }
  #pragma unroll
  for (int o = 32; o; o >>= 1) {
    a0 += __shfl_xor(a0, o); a1 += __shfl_xor(a1, o); a2 += __shfl_xor(a2, o);
  }
  if (lid == 0) {
    float m = fmaxf(a0, fmaxf(a1, a2));
    float e0 = __expf(a0-m), e1 = __expf(a1-m), e2 = __expf(a2-m);
    int emin = 0; float pm = e0;
    if (e1 <= pm) { pm = e1; emin = 1; }
    if (e2 <= pm) { pm = e2; emin = 2; }
    float rest = e0 + e1 + e2 - pm;
    wfull[t*3+0] = (emin == 0) ? 0.f : e0/rest;
    wfull[t*3+1] = (emin == 1) ? 0.f : e1/rest;
    wfull[t*3+2] = (emin == 2) ? 0.f : e2/rest;
  }
}

// =============================== host ===============================
static inline void launch_gemm3(hipStream_t st,
    const bf16* Ah, const bf16* Al, long a_rs, long a_oo, long a_oi,
    const bf16* Bh, const bf16* Bl, long b_rs, long b_oo, long b_oi,
    float* Cf, bf16* Ch, bf16* Cl, long c_rs, long c_oo, long c_oi,
    int M, int N, int K, int nlim, int zdiv, int nz)
{
  dim3 g((N + 127)/128, (M + 127)/128, nz);
  gemm3_bt<<<g, 256, 0, st>>>(Ah, Al, a_rs, a_oo, a_oi, Bh, Bl, b_rs, b_oo, b_oi,
                              Cf, Ch, Cl, c_rs, c_oo, c_oi, M, N, K, nlim, zdiv);
}

extern "C" void kernel_launch(void* const* d_in, const int* in_sizes, int n_in,
                              void* d_out, int out_size, void* d_ws, size_t ws_size,
                              hipStream_t stream)
{
  const float* x      = (const float*)d_in[0];
  const float* ln_w   = (const float*)d_in[1];
  const float* ln_b   = (const float*)d_in[2];
  const float* qkv_w  = (const float*)d_in[3];
  const float* proj_w = (const float*)d_in[4];
  const float* rout_w = (const float*)d_in[5];
  const float* gate_w = (const float*)d_in[6];
  const float* up_w   = (const float*)d_in[7];
  const float* down_w = (const float*)d_in[8];
  float* out = (float*)d_out;

  char* ws = (char*)d_ws;
  size_t off = 0;
  auto alloc = [&](size_t bytes) { size_t r = off; off += (bytes + 255) & ~(size_t)255; return r; };

  // persistent (~82.6 MB)
  size_t o_stats = alloc(8*2*4);
  size_t o_part  = alloc(8*128*2*4);
  size_t o_wfull = alloc((size_t)MTOK*3*4);
  size_t o_qkvTh = alloc((size_t)C3*C_*2);
  size_t o_qkvTl = alloc((size_t)C3*C_*2);
  size_t o_prjTh = alloc((size_t)C_*C_*2);
  size_t o_prjTl = alloc((size_t)C_*C_*2);
  size_t o_guT   = alloc((size_t)GUN*C_*2);      // gate/up 16-row interleaved
  size_t o_downT = alloc((size_t)C_*DK*2);
  size_t o_xattn = alloc((size_t)B_*NPB*4);
  size_t o_tok2  = alloc((size_t)MTOK*C_*2);
  size_t o_tok2f = alloc((size_t)MTOK*C_*4);
  size_t big0 = off;
  // phase A (attention): fixed buffers + union region (tok | scores | oproj)
  size_t o_qkvh  = alloc((size_t)MTOK*C3*2);
  size_t o_qkvl  = alloc((size_t)MTOK*C3*2);
  size_t o_VTh   = alloc((size_t)64*DH_*SPAD*2);
  size_t o_VTl   = alloc((size_t)64*DH_*SPAD*2);
  size_t o_aoh   = alloc((size_t)MTOK*C_*2);
  size_t o_aol   = alloc((size_t)MTOK*C_*2);
  size_t o_union = alloc((size_t)32*S_*SPAD*4);  // 68.7 MB
  size_t endA = off;
  // phase B (MoE): hidden + 8 bf16 partials
  off = big0;
  size_t o_hid = alloc((size_t)MTOK*DK*2);
  size_t o_prt = alloc((size_t)8*MTOK*768*2);
  size_t endB = off;
  size_t needed = endA > endB ? endA : endB;
  if (ws_size < needed) return;  // insufficient workspace: visible failure

  float* stats  = (float*)(ws + o_stats);
  float* part   = (float*)(ws + o_part);
  float* wfull  = (float*)(ws + o_wfull);
  bf16*  qkvTh  = (bf16*)(ws + o_qkvTh);
  bf16*  qkvTl  = (bf16*)(ws + o_qkvTl);
  bf16*  prjTh  = (bf16*)(ws + o_prjTh);
  bf16*  prjTl  = (bf16*)(ws + o_prjTl);
  bf16*  guT    = (bf16*)(ws + o_guT);
  bf16*  downT  = (bf16*)(ws + o_downT);
  float* xattn  = (float*)(ws + o_xattn);
  bf16*  tok2   = (bf16*)(ws + o_tok2);
  float* tok2f  = (float*)(ws + o_tok2f);
  bf16*  qkvh   = (bf16*)(ws + o_qkvh);
  bf16*  qkvl   = (bf16*)(ws + o_qkvl);
  bf16*  VTh    = (bf16*)(ws + o_VTh);
  bf16*  VTl    = (bf16*)(ws + o_VTl);
  bf16*  aoh    = (bf16*)(ws + o_aoh);
  bf16*  aol    = (bf16*)(ws + o_aol);
  // union region occupants (live ranges disjoint in stream order):
  bf16*  tokh   = (bf16*)(ws + o_union);
  bf16*  tokl   = (bf16*)(ws + o_union + (size_t)MTOK*C_*2);
  bf16*  Pbase  = (bf16*)(ws + o_union);
  float* oproj  = (float*)(ws + o_union);
  bf16*  hidden = (bf16*)(ws + o_hid);
  bf16*  prt    = (bf16*)(ws + o_prt);

  dim3 b32(32, 8);

  // weight conversions (gate/up 16-row interleaved per 32-row block of guT)
  wtrans3<<<dim3(72,24,1), b32, 0, stream>>>(qkv_w,  qkvTh, qkvTl, 768, 2304, 2304, 768);
  wtrans3<<<dim3(24,24,1), b32, 0, stream>>>(proj_w, prjTh, prjTl, 768, 768,  768,  768);
  wtrans<<<dim3(64,24,3), b32, 0, stream>>>(gate_w, guT, 768, 2048, 2048, 768,
                                            (long)768*2048, (long)4096*768, 1, 0);
  wtrans<<<dim3(64,24,3), b32, 0, stream>>>(up_w, guT, 768, 2048, 2048, 768,
                                            (long)768*2048, (long)4096*768, 1, 16);
  wtrans<<<dim3(24,64,3), b32, 0, stream>>>(down_w, downT, 2048, 768, 768, 6144,
                                            (long)2048*768, 2048, 0, 0);

  // LayerNorm -> tok hi/lo (b,s,c)
  ln_partial<<<dim3(128,8), 256, 0, stream>>>(x, part);
  ln_final<<<8, 64, 0, stream>>>(part, stats);
  ln_apply3<<<dim3(23,24,8), b32, 0, stream>>>(x, ln_w, ln_b, stats, tokh, tokl, C_);

  // qkv = tok @ qkv_w (bf16x3, hi/lo out); tok region dead afterwards
  launch_gemm3(stream, tokh, tokl, C_, 0, 0, qkvTh, qkvTl, C_, 0, 0,
               nullptr, qkvh, qkvl, C3, 0, 0, MTOK, C3, C_, C3, 1, 1);

  // V^T per (b,h), hi+lo in one dispatch, zero-padded to SPAD
  vtrans2<<<dim3(3,23,128), b32, 0, stream>>>(qkvh, qkvl, VTh, VTl);

  // attention in 2 chunks of 32 (b,h)-pairs (4 batches each)
  for (int c = 0; c < 2; ++c) {
    const long qoff = (long)(4*c)*S_*C3;
    launch_gemm3(stream,
        qkvh + qoff, qkvl + qoff, C3, (long)S_*C3, DH_,
        qkvh + qoff + 768, qkvl + qoff + 768, C3, (long)S_*C3, DH_,
        nullptr, Pbase, Pbase + SPAD, 2*SPAD, (long)8*S_*2*SPAD, (long)S_*2*SPAD,
        S_, S_, DH_, SPAD, 8, 32);
    softmax3p<<<5832, 256, 0, stream>>>(Pbase, 32*S_);
    launch_gemm3(stream,
        Pbase, Pbase + SPAD, 2*SPAD, (long)8*S_*2*SPAD, (long)S_*2*SPAD,
        VTh + (size_t)c*32*DH_*SPAD, VTl + (size_t)c*32*DH_*SPAD, SPAD,
        (long)8*DH_*SPAD, (long)DH_*SPAD,
        nullptr, aoh + (size_t)(4*c)*S_*C_, aol + (size_t)(4*c)*S_*C_,
        C_, (long)S_*C_, DH_,
        S_, DH_, SPAD, DH_, 8, 32);
  }

  // oproj = attnout @ proj_w (fp32 out, into union region — P dead now)
  launch_gemm3(stream, aoh, aol, C_, 0, 0, prjTh, prjTl, C_, 0, 0,
               oproj, nullptr, nullptr, C_, 0, 0, MTOK, C_, C_, C_, 1, 1);

  // residual + layouts
  tadd1<<<dim3(23,24,8), b32, 0, stream>>>(x, oproj, xattn, tok2, tok2f);

  // router weights (fp32 path) — must precede fused GU epilogue
  router_k<<<1458, 256, 0, stream>>>(tok2f, rout_w, wfull);

  // GU gemm with fused silu*up*w epilogue -> hidden [MTOK][6144]
  gemm8<<<dim3(GUN/256, 23, 1), 512, 0, stream>>>(
      tok2, C_, guT, C_, nullptr, hidden, DK, 0, MTOK, GUN, C_, wfull, 3);

  // down GEMM (K=6144) nz=8 K-split, bf16 partials
  gemm8<<<dim3(C_/256, 23, 8), 512, 0, stream>>>(
      hidden, DK, downT, DK, nullptr, prt, 768, (long)MTOK*768, MTOK, C_, DK/8,
      nullptr, 0);

  // final residual transpose-add (sums 8 partials) into output
  tadd2<<<dim3(23,24,8), b32, 0, stream>>>(xattn, prt, out);
}

// Round 14
// 745.867 us; speedup vs baseline: 1.0597x; 1.0491x over previous
//
#include <hip/hip_runtime.h>
#include <hip/hip_bf16.h>

#define C_    768
#define NH_   8
#define DH_   96
#define S_    729
#define B_    8
#define MTOK  5832
#define C3    2304
#define GUN   12288
#define DK    6144
#define SPAD  736
#define NPB   559872   // C_*S_

typedef __attribute__((ext_vector_type(8))) short short8;
typedef __attribute__((ext_vector_type(4))) float f32x4;
typedef __attribute__((ext_vector_type(4))) unsigned int uint4v;
typedef __hip_bfloat16 bf16;

__device__ __forceinline__ void gld_lds16(const bf16* g, bf16* l) {
  __builtin_amdgcn_global_load_lds((const __attribute__((address_space(1))) void*)g,
                                   (__attribute__((address_space(3))) void*)l, 16, 0, 0);
}
__device__ __forceinline__ void gld_lds16c(const char* g, char* l) {
  __builtin_amdgcn_global_load_lds((const __attribute__((address_space(1))) void*)g,
                                   (__attribute__((address_space(3))) void*)l, 16, 0, 0);
}

// ========== 128x128 4-wave BK=32 double-buffered GEMM (m97-style, high occupancy) ==========
// LDS 32KB = 2 x {A[128x32] | B[128x32]} bf16. Chunk-XOR swizzle: 16B chunk c of row r
// holds global chunk c^(r&3) (pre-swizzled source, linear gld_lds dest); reads XOR back.
// Loop: {stage T(t+1) -> nb; ds_read frags from db; 16 MFMA; vmcnt(0); bar} — stalls
// hidden by ~3 co-resident blocks/CU (TLP).
template<int DBO>
__device__ __forceinline__ void g97_step(
    char* ldsc, char* ldsw, const int rA, const int rB, const int cx,
    const char*& pA0, const char*& pA1, const char*& pB0, const char*& pB1,
    const bool stage, f32x4 (&acc)[4][4])
{
  const int NBO = 16384 - DBO;
  if (stage) {
    gld_lds16c(pA0, ldsw + NBO);
    gld_lds16c(pA1, ldsw + NBO + 4096);
    gld_lds16c(pB0, ldsw + NBO + 8192);
    gld_lds16c(pB1, ldsw + NBO + 12288);
    pA0 += 64; pA1 += 64; pB0 += 64; pB1 += 64;
  }
  short8 a4[4], b4[4];
  #pragma unroll
  for (int mf = 0; mf < 4; ++mf)
    a4[mf] = *(const short8*)(ldsc + DBO + rA + mf*1024 + cx);
  #pragma unroll
  for (int nf = 0; nf < 4; ++nf)
    b4[nf] = *(const short8*)(ldsc + DBO + rB + nf*1024 + cx);
  __builtin_amdgcn_s_setprio(1);
  #pragma unroll
  for (int mf = 0; mf < 4; ++mf)
    #pragma unroll
    for (int nf = 0; nf < 4; ++nf)
      acc[mf][nf] = __builtin_amdgcn_mfma_f32_16x16x32_bf16(a4[mf], b4[nf], acc[mf][nf], 0, 0, 0);
  __builtin_amdgcn_s_setprio(0);
  asm volatile("s_waitcnt vmcnt(0)" ::: "memory");
  __builtin_amdgcn_s_barrier();
}

// modes: 0 = bf16 out (Cb, +z*c_zoff). 1 = fp32 out (Cf, +z*c_zoff).
// 3 = fused MoE: gate/up interleaved at 16-col granularity; writes
// silu(g)*u*wfull[row*3+e] bf16 to Cb[row*c_rs + h], h = ((col32)>>5)*16+fr.
__global__ void __launch_bounds__(256, 3)
gemm97(const bf16* __restrict__ A, long a_rs,
       const bf16* __restrict__ Bt, long b_rs,
       float* __restrict__ Cf, bf16* __restrict__ Cb,
       long c_rs, long c_zoff, int M, int N, int Ksub,
       const float* __restrict__ wfull, int mode)
{
  __shared__ __attribute__((aligned(128))) char ldsc[32768];
  const int tid = threadIdx.x;
  const int wid = tid >> 6, lid = tid & 63;
  const int wm = wid >> 1, wn = wid & 1;           // 2 x 2 wave grid (64x64 each)
  const int fr = lid & 15, g8 = (lid >> 4) * 8;
  const int brow = blockIdx.y * 128, bcol = blockIdx.x * 128;
  const long k0b = (long)blockIdx.z * Ksub * 2;
  const long a_rsb = a_rs * 2, b_rsb = b_rs * 2;
  const int srow = tid >> 2;                        // 0..63
  const int scol = ((tid & 3) ^ (srow & 3)) << 4;   // pre-swizzled source chunk
  const int NT = Ksub >> 5;
  char* ldsw = ldsc + wid * 1024;                   // wave staging base (+lid*16)

  int ra0_ = brow + srow;       if (ra0_ > M-1) ra0_ = M-1;
  int ra1_ = brow + 64 + srow;  if (ra1_ > M-1) ra1_ = M-1;
  int rb0_ = bcol + srow;       if (rb0_ > N-1) rb0_ = N-1;
  int rb1_ = bcol + 64 + srow;  if (rb1_ > N-1) rb1_ = N-1;
  const char* pA0 = (const char*)A + (long)ra0_*a_rsb + k0b + scol;
  const char* pA1 = (const char*)A + (long)ra1_*a_rsb + k0b + scol;
  const char* pB0 = (const char*)Bt + (long)rb0_*b_rsb + k0b + scol;
  const char* pB1 = (const char*)Bt + (long)rb1_*b_rsb + k0b + scol;

  const int cx = (g8*2) ^ ((fr & 3) << 4);          // read-side chunk XOR (row&3 == fr&3)
  const int rA = (wm*64 + fr)*64;
  const int rB = 8192 + (wn*64 + fr)*64;

  f32x4 acc[4][4] = {};

  // prologue: stage T0 -> buf0
  gld_lds16c(pA0, ldsw);
  gld_lds16c(pA1, ldsw + 4096);
  gld_lds16c(pB0, ldsw + 8192);
  gld_lds16c(pB1, ldsw + 12288);
  pA0 += 64; pA1 += 64; pB0 += 64; pB1 += 64;
  asm volatile("s_waitcnt vmcnt(0)" ::: "memory");
  __builtin_amdgcn_s_barrier();

  for (int tp = 0; tp < NT; tp += 2) {
    g97_step<0>(ldsc, ldsw, rA, rB, cx, pA0, pA1, pB0, pB1, true, acc);
    g97_step<16384>(ldsc, ldsw, rA, rB, cx, pA0, pA1, pB0, pB1, (tp + 2) < NT, acc);
  }

  const int rg = (lid >> 4) * 4;
  if (mode == 3) {
    // fused silu(gate)*up*w; gate = acc[*][even nf], up = acc[*][odd nf]
    #pragma unroll
    for (int mf = 0; mf < 4; ++mf) {
      #pragma unroll
      for (int np = 0; np < 2; ++np) {
        const int hb = (bcol + wn*64 + np*32) >> 5;
        const int h = hb*16 + fr;
        const int e = h >> 11;
        #pragma unroll
        for (int j = 0; j < 4; ++j) {
          const int row = brow + wm*64 + mf*16 + rg + j;
          if (row < M) {
            float g = acc[mf][2*np][j];
            float u = acc[mf][2*np+1][j];
            float w = wfull[row*3 + e];
            float sg = g / (1.f + __expf(-g));
            Cb[(long)row*c_rs + h] = __float2bfloat16(sg * u * w);
          }
        }
      }
    }
  } else {
    #pragma unroll
    for (int mf = 0; mf < 4; ++mf) {
      #pragma unroll
      for (int nf = 0; nf < 4; ++nf) {
        const int col = bcol + wn*64 + nf*16 + fr;
        if (col < N) {
          #pragma unroll
          for (int j = 0; j < 4; ++j) {
            const int row = brow + wm*64 + mf*16 + rg + j;
            if (row < M) {
              long off = (long)blockIdx.z*c_zoff + (long)row*c_rs + col;
              if (mode == 0) Cb[off] = __float2bfloat16(acc[mf][nf][j]);
              else           Cf[off] = acc[mf][nf][j];
            }
          }
        }
      }
    }
  }
}

// ---------------- bf16x3 split GEMM: A=(Ah+Al), B=(Bh+Bl), 3 products ----------------
__global__ void __launch_bounds__(256)
gemm3_bt(const bf16* __restrict__ Ah, const bf16* __restrict__ Al,
         long a_rs, long a_oo, long a_oi,
         const bf16* __restrict__ Bth, const bf16* __restrict__ Btl,
         long b_rs, long b_oo, long b_oi,
         float* __restrict__ Cf, bf16* __restrict__ Ch, bf16* __restrict__ Cl,
         long c_rs, long c_oo, long c_oi,
         int M, int N, int K, int nlim, int zdiv)
{
  __shared__ bf16 lAh[4096];
  __shared__ bf16 lAl[4096];
  __shared__ bf16 lBh[4096];
  __shared__ bf16 lBl[4096];
  const int tid = threadIdx.x;
  const int wid = tid >> 6;
  const int lid = tid & 63;
  const int z = blockIdx.z;
  const int zo = z / zdiv, zi = z - zo*zdiv;
  const long aoff = (long)zo*a_oo + (long)zi*a_oi;
  const long boff = (long)zo*b_oo + (long)zi*b_oi;
  const long cbase = (long)zo*c_oo + (long)zi*c_oi;
  const int brow = blockIdx.y * 128;
  const int bcol = blockIdx.x * 128;

  const int ch0 = tid, ch1 = tid + 256;
  int ra0 = brow + (ch0 >> 2); if (ra0 > M-1) ra0 = M-1;
  int ra1 = brow + (ch1 >> 2); if (ra1 > M-1) ra1 = M-1;
  int rb0 = bcol + (ch0 >> 2); if (rb0 > N-1) rb0 = N-1;
  int rb1 = bcol + (ch1 >> 2); if (rb1 > N-1) rb1 = N-1;
  const int sw = ((ch0 ^ (ch0 >> 2)) & 3) * 8;
  const long ia0 = aoff + (long)ra0*a_rs + sw;
  const long ia1 = aoff + (long)ra1*a_rs + sw;
  const long ib0 = boff + (long)rb0*b_rs + sw;
  const long ib1 = boff + (long)rb1*b_rs + sw;
  bf16* dAh0 = (bf16*)((char*)lAh + wid*1024);
  bf16* dAh1 = (bf16*)((char*)lAh + 4096 + wid*1024);
  bf16* dAl0 = (bf16*)((char*)lAl + wid*1024);
  bf16* dAl1 = (bf16*)((char*)lAl + 4096 + wid*1024);
  bf16* dBh0 = (bf16*)((char*)lBh + wid*1024);
  bf16* dBh1 = (bf16*)((char*)lBh + 4096 + wid*1024);
  bf16* dBl0 = (bf16*)((char*)lBl + wid*1024);
  bf16* dBl1 = (bf16*)((char*)lBl + 4096 + wid*1024);

  f32x4 acc[4][4] = {};
  const int wm = wid >> 1, wn = wid & 1;
  const int fr = lid & 15, g8 = (lid >> 4) * 8;
  const int gx = g8 ^ ((lid & 3) << 3);

  for (int kt = 0; kt < K; kt += 32) {
    __syncthreads();
    gld_lds16(Ah + ia0 + kt, dAh0);
    gld_lds16(Ah + ia1 + kt, dAh1);
    gld_lds16(Al + ia0 + kt, dAl0);
    gld_lds16(Al + ia1 + kt, dAl1);
    gld_lds16(Bth + ib0 + kt, dBh0);
    gld_lds16(Bth + ib1 + kt, dBh1);
    gld_lds16(Btl + ib0 + kt, dBl0);
    gld_lds16(Btl + ib1 + kt, dBl1);
    __syncthreads();
    short8 fah[4], fal[4], fbh[4], fbl[4];
    #pragma unroll
    for (int m = 0; m < 4; ++m) {
      int ro = (wm*64 + m*16 + fr)*32 + gx;
      fah[m] = *(const short8*)&lAh[ro];
      fal[m] = *(const short8*)&lAl[ro];
    }
    #pragma unroll
    for (int n = 0; n < 4; ++n) {
      int ro = (wn*64 + n*16 + fr)*32 + gx;
      fbh[n] = *(const short8*)&lBh[ro];
      fbl[n] = *(const short8*)&lBl[ro];
    }
    #pragma unroll
    for (int m = 0; m < 4; ++m)
      #pragma unroll
      for (int n = 0; n < 4; ++n) {
        acc[m][n] = __builtin_amdgcn_mfma_f32_16x16x32_bf16(fal[m], fbh[n], acc[m][n], 0, 0, 0);
        acc[m][n] = __builtin_amdgcn_mfma_f32_16x16x32_bf16(fah[m], fbl[n], acc[m][n], 0, 0, 0);
        acc[m][n] = __builtin_amdgcn_mfma_f32_16x16x32_bf16(fah[m], fbh[n], acc[m][n], 0, 0, 0);
      }
  }

  const int rg = (lid >> 4) * 4;
  #pragma unroll
  for (int m = 0; m < 4; ++m) {
    #pragma unroll
    for (int n = 0; n < 4; ++n) {
      const int col = bcol + wn*64 + n*16 + fr;
      if (col < nlim) {
        #pragma unroll
        for (int j = 0; j < 4; ++j) {
          const int row = brow + wm*64 + m*16 + rg + j;
          if (row < M) {
            long off = cbase + (long)row*c_rs + col;
            float v = acc[m][n][j];
            if (Cl) {
              bf16 h = __float2bfloat16(v);
              Ch[off] = h;
              Cl[off] = __float2bfloat16(v - __bfloat162float(h));
            } else if (Ch) {
              Ch[off] = __float2bfloat16(v);
            } else {
              Cf[off] = v;
            }
          }
        }
      }
    }
  }
}

// ---------------- weight transpose fp32 -> bf16 (opt. 16-row interleave) ----------------
__global__ void wtrans(const float* __restrict__ in, bf16* __restrict__ out,
                       int R, int Cc, long in_rs, long out_rs, long in_bs, long out_bs,
                       int ilv, int radd)
{
  __shared__ float tile[32][33];
  in  += (long)blockIdx.z * in_bs;
  out += (long)blockIdx.z * out_bs;
  int r0 = blockIdx.y*32, c0 = blockIdx.x*32;
  int tx = threadIdx.x, ty = threadIdx.y;
  #pragma unroll
  for (int i = 0; i < 32; i += 8) {
    int r = r0 + ty + i, c = c0 + tx;
    if (r < R && c < Cc) tile[ty+i][tx] = in[(long)r*in_rs + c];
  }
  __syncthreads();
  #pragma unroll
  for (int i = 0; i < 32; i += 8) {
    int ro = c0 + ty + i, co = r0 + tx;
    if (ro < Cc && co < R) {
      int rr = ilv ? (((ro >> 4) << 5) + (ro & 15) + radd) : ro;
      out[(long)rr*out_rs + co] = __float2bfloat16(tile[tx][ty+i]);
    }
  }
}

// ---------------- weight transpose fp32 -> bf16 hi/lo pair ----------------
__global__ void wtrans3(const float* __restrict__ in, bf16* __restrict__ oh, bf16* __restrict__ ol,
                        int R, int Cc, long in_rs, long out_rs)
{
  __shared__ float tile[32][33];
  int r0 = blockIdx.y*32, c0 = blockIdx.x*32;
  int tx = threadIdx.x, ty = threadIdx.y;
  #pragma unroll
  for (int i = 0; i < 32; i += 8) {
    int r = r0 + ty + i, c = c0 + tx;
    if (r < R && c < Cc) tile[ty+i][tx] = in[(long)r*in_rs + c];
  }
  __syncthreads();
  #pragma unroll
  for (int i = 0; i < 32; i += 8) {
    int ro = c0 + ty + i, co = r0 + tx;
    if (ro < Cc && co < R) {
      float v = tile[tx][ty+i];
      bf16 h = __float2bfloat16(v);
      long o = (long)ro*out_rs + co;
      oh[o] = h;
      ol[o] = __float2bfloat16(v - __bfloat162float(h));
    }
  }
}

// ---------------- LayerNorm ----------------
__global__ void ln_partial(const float* __restrict__ x, float* __restrict__ part) {
  int b = blockIdx.y, blk = blockIdx.x;
  const float* xb = x + (long)b*NPB;
  int start = blk * 4374;
  float s = 0.f, ss = 0.f;
  for (int i = start + threadIdx.x; i < start + 4374; i += 256) {
    float v = xb[i]; s += v; ss += v*v;
  }
  #pragma unroll
  for (int o = 32; o; o >>= 1) { s += __shfl_down(s, o); ss += __shfl_down(ss, o); }
  __shared__ float red[2][4];
  int wid = threadIdx.x >> 6, lid = threadIdx.x & 63;
  if (lid == 0) { red[0][wid] = s; red[1][wid] = ss; }
  __syncthreads();
  if (threadIdx.x == 0) {
    float S = 0.f, SS = 0.f;
    for (int w = 0; w < 4; ++w) { S += red[0][w]; SS += red[1][w]; }
    part[(b*128 + blk)*2] = S; part[(b*128 + blk)*2 + 1] = SS;
  }
}

__global__ void ln_final(const float* __restrict__ part, float* __restrict__ stats) {
  int b = blockIdx.x, lid = threadIdx.x;
  float s = 0.f, ss = 0.f;
  for (int i = lid; i < 128; i += 64) { s += part[(b*128+i)*2]; ss += part[(b*128+i)*2+1]; }
  #pragma unroll
  for (int o = 32; o; o >>= 1) { s += __shfl_down(s, o); ss += __shfl_down(ss, o); }
  if (lid == 0) {
    float mean = s / (float)NPB;
    float var = ss / (float)NPB - mean*mean;
    stats[b*2] = mean; stats[b*2+1] = rsqrtf(var + 1e-5f);
  }
}

__global__ void ln_apply3(const float* __restrict__ x, const float* __restrict__ lnw,
                          const float* __restrict__ lnb, const float* __restrict__ stats,
                          bf16* __restrict__ th, bf16* __restrict__ tl, long ts)
{
  __shared__ float tile[32][33];
  int b = blockIdx.z;
  int s0 = blockIdx.x*32, c0 = blockIdx.y*32;
  float mean = stats[b*2], rstd = stats[b*2+1];
  int tx = threadIdx.x, ty = threadIdx.y;
  #pragma unroll
  for (int i = 0; i < 32; i += 8) {
    int c = c0 + ty + i, s = s0 + tx;
    if (s < S_) {
      long o = (long)c*S_ + s;
      tile[ty+i][tx] = (x[(long)b*NPB + o] - mean)*rstd*lnw[o] + lnb[o];
    }
  }
  __syncthreads();
  #pragma unroll
  for (int i = 0; i < 32; i += 8) {
    int s = s0 + ty + i, c = c0 + tx;
    if (s < S_) {
      float v = tile[tx][ty+i];
      bf16 h = __float2bfloat16(v);
      long o = ((long)b*S_ + s)*ts + c;
      th[o] = h;
      tl[o] = __float2bfloat16(v - __bfloat162float(h));
    }
  }
}

// ------- V transpose (bf16), hi (z<64) and lo (z>=64), zero pad t in [S_, SPAD) -------
__global__ void vtrans2(const bf16* __restrict__ qkvh, const bf16* __restrict__ qkvl,
                        bf16* __restrict__ VTh, bf16* __restrict__ VTl)
{
  __shared__ float tile[32][33];
  int z = blockIdx.z;
  const bf16* qkv = (z < 64) ? qkvh : qkvl;
  bf16* VT = (z < 64) ? VTh : VTl;
  int zz = z & 63;
  int bb = zz >> 3, h = zz & 7;
  const bf16* v = qkv + (long)bb*S_*C3 + 1536 + h*DH_;
  bf16* o = VT + (long)zz*DH_*SPAD;
  int t0 = blockIdx.y*32, d0 = blockIdx.x*32;
  int tx = threadIdx.x, ty = threadIdx.y;
  #pragma unroll
  for (int i = 0; i < 32; i += 8) {
    int t = t0 + ty + i, d = d0 + tx;
    float val = 0.f;
    if (t < S_ && d < DH_) val = __bfloat162float(v[(long)t*C3 + d]);
    tile[ty+i][tx] = val;
  }
  __syncthreads();
  #pragma unroll
  for (int i = 0; i < 32; i += 8) {
    int d = d0 + ty + i, t = t0 + tx;
    if (d < DH_ && t < SPAD) o[(long)d*SPAD + t] = __float2bfloat16(tile[tx][ty+i]);
  }
}

// -------- softmax over bf16 hi/lo score rows, IN PLACE (row stride 2*SPAD) --------
__global__ void softmax3p(bf16* __restrict__ scores, int nrows) {
  int row = blockIdx.x*4 + (threadIdx.x >> 6);
  if (row >= nrows) return;
  int lid = threadIdx.x & 63;
  bf16* ph = scores + (long)row*2*SPAD;
  bf16* pl = ph + SPAD;
  float vals[12];
  float mx = -1e30f;
  #pragma unroll
  for (int i = 0; i < 12; ++i) {
    int t = i*64 + lid;
    float v = -1e30f;
    if (t < S_) v = __bfloat162float(ph[t]) + __bfloat162float(pl[t]);
    vals[i] = v; mx = fmaxf(mx, v);
  }
  #pragma unroll
  for (int o = 32; o; o >>= 1) mx = fmaxf(mx, __shfl_xor(mx, o));
  float sum = 0.f;
  #pragma unroll
  for (int i = 0; i < 12; ++i) { float e = __expf(vals[i] - mx); vals[i] = e; sum += e; }
  #pragma unroll
  for (int o = 32; o; o >>= 1) sum += __shfl_xor(sum, o);
  float inv = 1.f / sum;
  #pragma unroll
  for (int i = 0; i < 12; ++i) {
    int t = i*64 + lid;
    if (t < SPAD) {
      float p = (t < S_) ? vals[i]*inv : 0.f;
      bf16 h = __float2bfloat16(p);
      ph[t] = h;
      pl[t] = __float2bfloat16(p - __bfloat162float(h));
    }
  }
}

// ---------------- residual transpose-add 1 ----------------
__global__ void tadd1(const float* __restrict__ x, const float* __restrict__ oproj,
                      float* __restrict__ xattn, bf16* __restrict__ tok2,
                      float* __restrict__ tok2f)
{
  __shared__ float t_o[32][33];
  __shared__ float t_x[32][33];
  int b = blockIdx.z;
  int s0 = blockIdx.x*32, c0 = blockIdx.y*32;
  int tx = threadIdx.x, ty = threadIdx.y;
  #pragma unroll
  for (int i = 0; i < 32; i += 8) {
    int s = s0 + ty + i;
    if (s < S_) t_o[ty+i][tx] = oproj[((long)b*S_ + s)*C_ + c0 + tx];
    int s2 = s0 + tx;
    if (s2 < S_) t_x[ty+i][tx] = x[(long)b*NPB + (long)(c0+ty+i)*S_ + s2];
  }
  __syncthreads();
  #pragma unroll
  for (int i = 0; i < 32; i += 8) {
    int s = s0 + tx, c = c0 + ty + i;
    if (s < S_) xattn[(long)b*NPB + (long)c*S_ + s] = t_x[ty+i][tx] + t_o[tx][ty+i];
    int s2 = s0 + ty + i, c2 = c0 + tx;
    if (s2 < S_) {
      float v = t_x[tx][ty+i] + t_o[ty+i][tx];
      long o = ((long)b*S_ + s2)*C_ + c2;
      tok2[o] = __float2bfloat16(v);
      tok2f[o] = v;
    }
  }
}

// ---- residual transpose-add 2 (final output), sums 8 bf16 down-partials ----
__global__ void tadd2(const float* __restrict__ xattn, const bf16* __restrict__ prt,
                      float* __restrict__ out)
{
  __shared__ float t_m[32][33];
  __shared__ float t_x[32][33];
  int b = blockIdx.z;
  int s0 = blockIdx.x*32, c0 = blockIdx.y*32;
  int tx = threadIdx.x, ty = threadIdx.y;
  #pragma unroll
  for (int i = 0; i < 32; i += 8) {
    int s = s0 + ty + i;
    if (s < S_) {
      const bf16* p = prt + ((long)b*S_ + s)*768 + c0 + tx;
      float acc = 0.f;
      #pragma unroll
      for (int z = 0; z < 8; ++z) acc += __bfloat162float(p[(long)z*MTOK*768]);
      t_m[ty+i][tx] = acc;
    }
    int s2 = s0 + tx;
    if (s2 < S_) t_x[ty+i][tx] = xattn[(long)b*NPB + (long)(c0+ty+i)*S_ + s2];
  }
  __syncthreads();
  #pragma unroll
  for (int i = 0; i < 32; i += 8) {
    int s = s0 + tx, c = c0 + ty + i;
    if (s < S_) out[(long)b*NPB + (long)c*S_ + s] = t_x[ty+i][tx] + t_m[tx][ty+i];
  }
}

// ---------------- router: top-2 of 3 from fp32 tok2, normalized weights ----------------
__global__ void router_k(const float* __restrict__ tok2f, const float* __restrict__ rw,
                         float* __restrict__ wfull)
{
  int t = blockIdx.x*4 + (threadIdx.x >> 6);
  if (t >= MTOK) return;
  int lid = threadIdx.x & 63;
  const float* tk = tok2f + (long)t*C_;
  float a0 = 0.f, a1 = 0.f, a2 = 0.f;
  for (int i = lid; i < C_; i += 64) {
    float v = tk[i];
    a0 += v*rw[i*3+0]; a1 += v*rw[i*3+1]; a2 += v*rw[i*3+2];
  }
  #pragma unroll
  for (int o = 32; o; o >>= 1) {
    a0 += __shfl_xor(a0, o); a1 += __shfl_xor(a1, o); a2 += __shfl_xor(a2, o);
  }
  if (lid == 0) {
    float m = fmaxf(a0, fmaxf(a1, a2));
    float e0 = __expf(a0-m), e1 = __expf(a1-m), e2 = __expf(a2-m);
    int emin = 0; float pm = e0;
    if (e1 <= pm) { pm = e1; emin = 1; }
    if (e2 <= pm) { pm = e2; emin = 2; }
    float rest = e0 + e1 + e2 - pm;
    wfull[t*3+0] = (emin == 0) ? 0.f : e0/rest;
    wfull[t*3+1] = (emin == 1) ? 0.f : e1/rest;
    wfull[t*3+2] = (emin == 2) ? 0.f : e2/rest;
  }
}

// =============================== host ===============================
static inline void launch_gemm3(hipStream_t st,
    const bf16* Ah, const bf16* Al, long a_rs, long a_oo, long a_oi,
    const bf16* Bh, const bf16* Bl, long b_rs, long b_oo, long b_oi,
    float* Cf, bf16* Ch, bf16* Cl, long c_rs, long c_oo, long c_oi,
    int M, int N, int K, int nlim, int zdiv, int nz)
{
  dim3 g((N + 127)/128, (M + 127)/128, nz);
  gemm3_bt<<<g, 256, 0, st>>>(Ah, Al, a_rs, a_oo, a_oi, Bh, Bl, b_rs, b_oo, b_oi,
                              Cf, Ch, Cl, c_rs, c_oo, c_oi, M, N, K, nlim, zdiv);
}

extern "C" void kernel_launch(void* const* d_in, const int* in_sizes, int n_in,
                              void* d_out, int out_size, void* d_ws, size_t ws_size,
                              hipStream_t stream)
{
  const float* x      = (const float*)d_in[0];
  const float* ln_w   = (const float*)d_in[1];
  const float* ln_b   = (const float*)d_in[2];
  const float* qkv_w  = (const float*)d_in[3];
  const float* proj_w = (const float*)d_in[4];
  const float* rout_w = (const float*)d_in[5];
  const float* gate_w = (const float*)d_in[6];
  const float* up_w   = (const float*)d_in[7];
  const float* down_w = (const float*)d_in[8];
  float* out = (float*)d_out;

  char* ws = (char*)d_ws;
  size_t off = 0;
  auto alloc = [&](size_t bytes) { size_t r = off; off += (bytes + 255) & ~(size_t)255; return r; };

  // persistent (~82.6 MB)
  size_t o_stats = alloc(8*2*4);
  size_t o_part  = alloc(8*128*2*4);
  size_t o_wfull = alloc((size_t)MTOK*3*4);
  size_t o_qkvTh = alloc((size_t)C3*C_*2);
  size_t o_qkvTl = alloc((size_t)C3*C_*2);
  size_t o_prjTh = alloc((size_t)C_*C_*2);
  size_t o_prjTl = alloc((size_t)C_*C_*2);
  size_t o_guT   = alloc((size_t)GUN*C_*2);      // gate/up 16-row interleaved
  size_t o_downT = alloc((size_t)C_*DK*2);
  size_t o_xattn = alloc((size_t)B_*NPB*4);
  size_t o_tok2  = alloc((size_t)MTOK*C_*2);
  size_t o_tok2f = alloc((size_t)MTOK*C_*4);
  size_t big0 = off;
  // phase A (attention): fixed buffers + union region (tok | scores | oproj)
  size_t o_qkvh  = alloc((size_t)MTOK*C3*2);
  size_t o_qkvl  = alloc((size_t)MTOK*C3*2);
  size_t o_VTh   = alloc((size_t)64*DH_*SPAD*2);
  size_t o_VTl   = alloc((size_t)64*DH_*SPAD*2);
  size_t o_aoh   = alloc((size_t)MTOK*C_*2);
  size_t o_aol   = alloc((size_t)MTOK*C_*2);
  size_t o_union = alloc((size_t)32*S_*SPAD*4);  // 68.7 MB
  size_t endA = off;
  // phase B (MoE): hidden + 8 bf16 partials
  off = big0;
  size_t o_hid = alloc((size_t)MTOK*DK*2);
  size_t o_prt = alloc((size_t)8*MTOK*768*2);
  size_t endB = off;
  size_t needed = endA > endB ? endA : endB;
  if (ws_size < needed) return;  // insufficient workspace: visible failure

  float* stats  = (float*)(ws + o_stats);
  float* part   = (float*)(ws + o_part);
  float* wfull  = (float*)(ws + o_wfull);
  bf16*  qkvTh  = (bf16*)(ws + o_qkvTh);
  bf16*  qkvTl  = (bf16*)(ws + o_qkvTl);
  bf16*  prjTh  = (bf16*)(ws + o_prjTh);
  bf16*  prjTl  = (bf16*)(ws + o_prjTl);
  bf16*  guT    = (bf16*)(ws + o_guT);
  bf16*  downT  = (bf16*)(ws + o_downT);
  float* xattn  = (float*)(ws + o_xattn);
  bf16*  tok2   = (bf16*)(ws + o_tok2);
  float* tok2f  = (float*)(ws + o_tok2f);
  bf16*  qkvh   = (bf16*)(ws + o_qkvh);
  bf16*  qkvl   = (bf16*)(ws + o_qkvl);
  bf16*  VTh    = (bf16*)(ws + o_VTh);
  bf16*  VTl    = (bf16*)(ws + o_VTl);
  bf16*  aoh    = (bf16*)(ws + o_aoh);
  bf16*  aol    = (bf16*)(ws + o_aol);
  // union region occupants (live ranges disjoint in stream order):
  bf16*  tokh   = (bf16*)(ws + o_union);
  bf16*  tokl   = (bf16*)(ws + o_union + (size_t)MTOK*C_*2);
  bf16*  Pbase  = (bf16*)(ws + o_union);
  float* oproj  = (float*)(ws + o_union);
  bf16*  hidden = (bf16*)(ws + o_hid);
  bf16*  prt    = (bf16*)(ws + o_prt);

  dim3 b32(32, 8);

  // weight conversions (gate/up 16-row interleaved per 32-row block of guT)
  wtrans3<<<dim3(72,24,1), b32, 0, stream>>>(qkv_w,  qkvTh, qkvTl, 768, 2304, 2304, 768);
  wtrans3<<<dim3(24,24,1), b32, 0, stream>>>(proj_w, prjTh, prjTl, 768, 768,  768,  768);
  wtrans<<<dim3(64,24,3), b32, 0, stream>>>(gate_w, guT, 768, 2048, 2048, 768,
                                            (long)768*2048, (long)4096*768, 1, 0);
  wtrans<<<dim3(64,24,3), b32, 0, stream>>>(up_w, guT, 768, 2048, 2048, 768,
                                            (long)768*2048, (long)4096*768, 1, 16);
  wtrans<<<dim3(24,64,3), b32, 0, stream>>>(down_w, downT, 2048, 768, 768, 6144,
                                            (long)2048*768, 2048, 0, 0);

  // LayerNorm -> tok hi/lo (b,s,c)
  ln_partial<<<dim3(128,8), 256, 0, stream>>>(x, part);
  ln_final<<<8, 64, 0, stream>>>(part, stats);
  ln_apply3<<<dim3(23,24,8), b32, 0, stream>>>(x, ln_w, ln_b, stats, tokh, tokl, C_);

  // qkv = tok @ qkv_w (bf16x3, hi/lo out); tok region dead afterwards
  launch_gemm3(stream, tokh, tokl, C_, 0, 0, qkvTh, qkvTl, C_, 0, 0,
               nullptr, qkvh, qkvl, C3, 0, 0, MTOK, C3, C_, C3, 1, 1);

  // V^T per (b,h), hi+lo in one dispatch, zero-padded to SPAD
  vtrans2<<<dim3(3,23,128), b32, 0, stream>>>(qkvh, qkvl, VTh, VTl);

  // attention in 2 chunks of 32 (b,h)-pairs (4 batches each)
  for (int c = 0; c < 2; ++c) {
    const long qoff = (long)(4*c)*S_*C3;
    launch_gemm3(stream,
        qkvh + qoff, qkvl + qoff, C3, (long)S_*C3, DH_,
        qkvh + qoff + 768, qkvl + qoff + 768, C3, (long)S_*C3, DH_,
        nullptr, Pbase, Pbase + SPAD, 2*SPAD, (long)8*S_*2*SPAD, (long)S_*2*SPAD,
        S_, S_, DH_, SPAD, 8, 32);
    softmax3p<<<5832, 256, 0, stream>>>(Pbase, 32*S_);
    launch_gemm3(stream,
        Pbase, Pbase + SPAD, 2*SPAD, (long)8*S_*2*SPAD, (long)S_*2*SPAD,
        VTh + (size_t)c*32*DH_*SPAD, VTl + (size_t)c*32*DH_*SPAD, SPAD,
        (long)8*DH_*SPAD, (long)DH_*SPAD,
        nullptr, aoh + (size_t)(4*c)*S_*C_, aol + (size_t)(4*c)*S_*C_,
        C_, (long)S_*C_, DH_,
        S_, DH_, SPAD, DH_, 8, 32);
  }

  // oproj = attnout @ proj_w (fp32 out, into union region — P dead now)
  launch_gemm3(stream, aoh, aol, C_, 0, 0, prjTh, prjTl, C_, 0, 0,
               oproj, nullptr, nullptr, C_, 0, 0, MTOK, C_, C_, C_, 1, 1);

  // residual + layouts
  tadd1<<<dim3(23,24,8), b32, 0, stream>>>(x, oproj, xattn, tok2, tok2f);

  // router weights (fp32 path) — must precede fused GU epilogue
  router_k<<<1458, 256, 0, stream>>>(tok2f, rout_w, wfull);

  // GU gemm with fused silu*up*w epilogue -> hidden [MTOK][6144]  (128^2 high-occ kernel)
  gemm97<<<dim3(GUN/128, 46, 1), 256, 0, stream>>>(
      tok2, C_, guT, C_, nullptr, hidden, DK, 0, MTOK, GUN, C_, wfull, 3);

  // down GEMM (K=6144) nz=8 K-split, bf16 partials
  gemm97<<<dim3(C_/128, 46, 8), 256, 0, stream>>>(
      hidden, DK, downT, DK, nullptr, prt, 768, (long)MTOK*768, MTOK, C_, DK/8,
      nullptr, 0);

  // final residual transpose-add (sums 8 partials) into output
  tadd2<<<dim3(23,24,8), b32, 0, stream>>>(xattn, prt, out);
}

// Round 15
// 731.568 us; speedup vs baseline: 1.0804x; 1.0195x over previous
//
#include <hip/hip_runtime.h>
#include <hip/hip_bf16.h>

#define C_    768
#define NH_   8
#define DH_   96
#define S_    729
#define B_    8
#define MTOK  5832
#define C3    2304
#define GUN   12288
#define DK    6144
#define SPAD  736
#define NPB   559872   // C_*S_

typedef __attribute__((ext_vector_type(8))) short short8;
typedef __attribute__((ext_vector_type(4))) float f32x4;
typedef __attribute__((ext_vector_type(4))) unsigned int uint4v;
typedef __hip_bfloat16 bf16;

__device__ __forceinline__ void gld_lds16(const bf16* g, bf16* l) {
  __builtin_amdgcn_global_load_lds((const __attribute__((address_space(1))) void*)g,
                                   (__attribute__((address_space(3))) void*)l, 16, 0, 0);
}
__device__ __forceinline__ void gld_lds16c(const char* g, char* l) {
  __builtin_amdgcn_global_load_lds((const __attribute__((address_space(1))) void*)g,
                                   (__attribute__((address_space(3))) void*)l, 16, 0, 0);
}

// ========== 128x128 4-wave BK=32 double-buffered GEMM (m97-style, high occupancy) ==========
template<int DBO>
__device__ __forceinline__ void g97_step(
    char* ldsc, char* ldsw, const int rA, const int rB, const int cx,
    const char*& pA0, const char*& pA1, const char*& pB0, const char*& pB1,
    const bool stage, f32x4 (&acc)[4][4])
{
  const int NBO = 16384 - DBO;
  if (stage) {
    gld_lds16c(pA0, ldsw + NBO);
    gld_lds16c(pA1, ldsw + NBO + 4096);
    gld_lds16c(pB0, ldsw + NBO + 8192);
    gld_lds16c(pB1, ldsw + NBO + 12288);
    pA0 += 64; pA1 += 64; pB0 += 64; pB1 += 64;
  }
  short8 a4[4], b4[4];
  #pragma unroll
  for (int mf = 0; mf < 4; ++mf)
    a4[mf] = *(const short8*)(ldsc + DBO + rA + mf*1024 + cx);
  #pragma unroll
  for (int nf = 0; nf < 4; ++nf)
    b4[nf] = *(const short8*)(ldsc + DBO + rB + nf*1024 + cx);
  __builtin_amdgcn_s_setprio(1);
  #pragma unroll
  for (int mf = 0; mf < 4; ++mf)
    #pragma unroll
    for (int nf = 0; nf < 4; ++nf)
      acc[mf][nf] = __builtin_amdgcn_mfma_f32_16x16x32_bf16(a4[mf], b4[nf], acc[mf][nf], 0, 0, 0);
  __builtin_amdgcn_s_setprio(0);
  asm volatile("s_waitcnt vmcnt(0)" ::: "memory");
  __builtin_amdgcn_s_barrier();
}

// modes: 0 = bf16 out (Cb, +z*c_zoff). 1 = fp32 out (Cf, +z*c_zoff).
// 3 = fused MoE: gate/up interleaved at 16-col granularity; writes
// silu(g)*u*wfull[row*3+e] bf16 to Cb[row*c_rs + h].
__global__ void __launch_bounds__(256, 4)
gemm97(const bf16* __restrict__ A, long a_rs,
       const bf16* __restrict__ Bt, long b_rs,
       float* __restrict__ Cf, bf16* __restrict__ Cb,
       long c_rs, long c_zoff, int M, int N, int Ksub,
       const float* __restrict__ wfull, int mode)
{
  __shared__ __attribute__((aligned(128))) char ldsc[32768];
  const int tid = threadIdx.x;
  const int wid = tid >> 6, lid = tid & 63;
  const int wm = wid >> 1, wn = wid & 1;           // 2 x 2 wave grid (64x64 each)
  const int fr = lid & 15, g8 = (lid >> 4) * 8;
  const int brow = blockIdx.y * 128, bcol = blockIdx.x * 128;
  const long k0b = (long)blockIdx.z * Ksub * 2;
  const long a_rsb = a_rs * 2, b_rsb = b_rs * 2;
  const int srow = tid >> 2;                        // 0..63
  const int scol = ((tid & 3) ^ (srow & 3)) << 4;   // pre-swizzled source chunk
  const int NT = Ksub >> 5;
  char* ldsw = ldsc + wid * 1024;                   // wave staging base (+lid*16)

  int ra0_ = brow + srow;       if (ra0_ > M-1) ra0_ = M-1;
  int ra1_ = brow + 64 + srow;  if (ra1_ > M-1) ra1_ = M-1;
  int rb0_ = bcol + srow;       if (rb0_ > N-1) rb0_ = N-1;
  int rb1_ = bcol + 64 + srow;  if (rb1_ > N-1) rb1_ = N-1;
  const char* pA0 = (const char*)A + (long)ra0_*a_rsb + k0b + scol;
  const char* pA1 = (const char*)A + (long)ra1_*a_rsb + k0b + scol;
  const char* pB0 = (const char*)Bt + (long)rb0_*b_rsb + k0b + scol;
  const char* pB1 = (const char*)Bt + (long)rb1_*b_rsb + k0b + scol;

  const int cx = (g8*2) ^ ((fr & 3) << 4);          // read-side chunk XOR (row&3 == fr&3)
  const int rA = (wm*64 + fr)*64;
  const int rB = 8192 + (wn*64 + fr)*64;

  f32x4 acc[4][4] = {};

  // prologue: stage T0 -> buf0
  gld_lds16c(pA0, ldsw);
  gld_lds16c(pA1, ldsw + 4096);
  gld_lds16c(pB0, ldsw + 8192);
  gld_lds16c(pB1, ldsw + 12288);
  pA0 += 64; pA1 += 64; pB0 += 64; pB1 += 64;
  asm volatile("s_waitcnt vmcnt(0)" ::: "memory");
  __builtin_amdgcn_s_barrier();

  for (int tp = 0; tp < NT; tp += 2) {
    g97_step<0>(ldsc, ldsw, rA, rB, cx, pA0, pA1, pB0, pB1, true, acc);
    g97_step<16384>(ldsc, ldsw, rA, rB, cx, pA0, pA1, pB0, pB1, (tp + 2) < NT, acc);
  }

  const int rg = (lid >> 4) * 4;
  if (mode == 3) {
    // fused silu(gate)*up*w; gate = acc[*][even nf], up = acc[*][odd nf]
    #pragma unroll
    for (int mf = 0; mf < 4; ++mf) {
      #pragma unroll
      for (int np = 0; np < 2; ++np) {
        const int hb = (bcol + wn*64 + np*32) >> 5;
        const int h = hb*16 + fr;
        const int e = h >> 11;
        #pragma unroll
        for (int j = 0; j < 4; ++j) {
          const int row = brow + wm*64 + mf*16 + rg + j;
          if (row < M) {
            float g = acc[mf][2*np][j];
            float u = acc[mf][2*np+1][j];
            float w = wfull[row*3 + e];
            float sg = g / (1.f + __expf(-g));
            Cb[(long)row*c_rs + h] = __float2bfloat16(sg * u * w);
          }
        }
      }
    }
  } else {
    #pragma unroll
    for (int mf = 0; mf < 4; ++mf) {
      #pragma unroll
      for (int nf = 0; nf < 4; ++nf) {
        const int col = bcol + wn*64 + nf*16 + fr;
        if (col < N) {
          #pragma unroll
          for (int j = 0; j < 4; ++j) {
            const int row = brow + wm*64 + mf*16 + rg + j;
            if (row < M) {
              long off = (long)blockIdx.z*c_zoff + (long)row*c_rs + col;
              if (mode == 0) Cb[off] = __float2bfloat16(acc[mf][nf][j]);
              else           Cf[off] = acc[mf][nf][j];
            }
          }
        }
      }
    }
  }
}

// ---------------- bf16x3 split GEMM: A=(Ah+Al), B=(Bh+Bl), 3 products ----------------
__global__ void __launch_bounds__(256, 3)
gemm3_bt(const bf16* __restrict__ Ah, const bf16* __restrict__ Al,
         long a_rs, long a_oo, long a_oi,
         const bf16* __restrict__ Bth, const bf16* __restrict__ Btl,
         long b_rs, long b_oo, long b_oi,
         float* __restrict__ Cf, bf16* __restrict__ Ch, bf16* __restrict__ Cl,
         long c_rs, long c_oo, long c_oi,
         int M, int N, int K, int nlim, int zdiv)
{
  __shared__ bf16 lAh[4096];
  __shared__ bf16 lAl[4096];
  __shared__ bf16 lBh[4096];
  __shared__ bf16 lBl[4096];
  const int tid = threadIdx.x;
  const int wid = tid >> 6;
  const int lid = tid & 63;
  const int z = blockIdx.z;
  const int zo = z / zdiv, zi = z - zo*zdiv;
  const long aoff = (long)zo*a_oo + (long)zi*a_oi;
  const long boff = (long)zo*b_oo + (long)zi*b_oi;
  const long cbase = (long)zo*c_oo + (long)zi*c_oi;
  const int brow = blockIdx.y * 128;
  const int bcol = blockIdx.x * 128;

  const int ch0 = tid, ch1 = tid + 256;
  int ra0 = brow + (ch0 >> 2); if (ra0 > M-1) ra0 = M-1;
  int ra1 = brow + (ch1 >> 2); if (ra1 > M-1) ra1 = M-1;
  int rb0 = bcol + (ch0 >> 2); if (rb0 > N-1) rb0 = N-1;
  int rb1 = bcol + (ch1 >> 2); if (rb1 > N-1) rb1 = N-1;
  const int sw = ((ch0 ^ (ch0 >> 2)) & 3) * 8;
  // advancing staging pointers (+64B per K-tile)
  const char* qh0 = (const char*)(Ah + aoff + (long)ra0*a_rs + sw);
  const char* qh1 = (const char*)(Ah + aoff + (long)ra1*a_rs + sw);
  const char* ql0 = (const char*)(Al + aoff + (long)ra0*a_rs + sw);
  const char* ql1 = (const char*)(Al + aoff + (long)ra1*a_rs + sw);
  const char* rh0 = (const char*)(Bth + boff + (long)rb0*b_rs + sw);
  const char* rh1 = (const char*)(Bth + boff + (long)rb1*b_rs + sw);
  const char* rl0 = (const char*)(Btl + boff + (long)rb0*b_rs + sw);
  const char* rl1 = (const char*)(Btl + boff + (long)rb1*b_rs + sw);
  char* dAh0 = (char*)lAh + wid*1024;
  char* dAh1 = (char*)lAh + 4096 + wid*1024;
  char* dAl0 = (char*)lAl + wid*1024;
  char* dAl1 = (char*)lAl + 4096 + wid*1024;
  char* dBh0 = (char*)lBh + wid*1024;
  char* dBh1 = (char*)lBh + 4096 + wid*1024;
  char* dBl0 = (char*)lBl + wid*1024;
  char* dBl1 = (char*)lBl + 4096 + wid*1024;

  f32x4 acc[4][4] = {};
  const int wm = wid >> 1, wn = wid & 1;
  const int fr = lid & 15, g8 = (lid >> 4) * 8;
  const int gx = g8 ^ ((lid & 3) << 3);

  const int NTk = K >> 5;
  for (int kt = 0; kt < NTk; ++kt) {
    __syncthreads();
    gld_lds16c(qh0, dAh0);
    gld_lds16c(qh1, dAh1);
    gld_lds16c(ql0, dAl0);
    gld_lds16c(ql1, dAl1);
    gld_lds16c(rh0, dBh0);
    gld_lds16c(rh1, dBh1);
    gld_lds16c(rl0, dBl0);
    gld_lds16c(rl1, dBl1);
    qh0 += 64; qh1 += 64; ql0 += 64; ql1 += 64;
    rh0 += 64; rh1 += 64; rl0 += 64; rl1 += 64;
    __syncthreads();
    short8 fah[4], fal[4], fbh[4], fbl[4];
    #pragma unroll
    for (int m = 0; m < 4; ++m) {
      int ro = (wm*64 + m*16 + fr)*32 + gx;
      fah[m] = *(const short8*)&lAh[ro];
      fal[m] = *(const short8*)&lAl[ro];
    }
    #pragma unroll
    for (int n = 0; n < 4; ++n) {
      int ro = (wn*64 + n*16 + fr)*32 + gx;
      fbh[n] = *(const short8*)&lBh[ro];
      fbl[n] = *(const short8*)&lBl[ro];
    }
    #pragma unroll
    for (int m = 0; m < 4; ++m)
      #pragma unroll
      for (int n = 0; n < 4; ++n) {
        acc[m][n] = __builtin_amdgcn_mfma_f32_16x16x32_bf16(fal[m], fbh[n], acc[m][n], 0, 0, 0);
        acc[m][n] = __builtin_amdgcn_mfma_f32_16x16x32_bf16(fah[m], fbl[n], acc[m][n], 0, 0, 0);
        acc[m][n] = __builtin_amdgcn_mfma_f32_16x16x32_bf16(fah[m], fbh[n], acc[m][n], 0, 0, 0);
      }
  }

  const int rg = (lid >> 4) * 4;
  #pragma unroll
  for (int m = 0; m < 4; ++m) {
    #pragma unroll
    for (int n = 0; n < 4; ++n) {
      const int col = bcol + wn*64 + n*16 + fr;
      if (col < nlim) {
        #pragma unroll
        for (int j = 0; j < 4; ++j) {
          const int row = brow + wm*64 + m*16 + rg + j;
          if (row < M) {
            long off = cbase + (long)row*c_rs + col;
            float v = acc[m][n][j];
            if (Cl) {
              bf16 h = __float2bfloat16(v);
              Ch[off] = h;
              Cl[off] = __float2bfloat16(v - __bfloat162float(h));
            } else if (Ch) {
              Ch[off] = __float2bfloat16(v);
            } else {
              Cf[off] = v;
            }
          }
        }
      }
    }
  }
}

// ---------------- weight transpose fp32 -> bf16 (opt. 16-row interleave) ----------------
__global__ void wtrans(const float* __restrict__ in, bf16* __restrict__ out,
                       int R, int Cc, long in_rs, long out_rs, long in_bs, long out_bs,
                       int ilv, int radd)
{
  __shared__ float tile[32][33];
  in  += (long)blockIdx.z * in_bs;
  out += (long)blockIdx.z * out_bs;
  int r0 = blockIdx.y*32, c0 = blockIdx.x*32;
  int tx = threadIdx.x, ty = threadIdx.y;
  #pragma unroll
  for (int i = 0; i < 32; i += 8) {
    int r = r0 + ty + i, c = c0 + tx;
    if (r < R && c < Cc) tile[ty+i][tx] = in[(long)r*in_rs + c];
  }
  __syncthreads();
  #pragma unroll
  for (int i = 0; i < 32; i += 8) {
    int ro = c0 + ty + i, co = r0 + tx;
    if (ro < Cc && co < R) {
      int rr = ilv ? (((ro >> 4) << 5) + (ro & 15) + radd) : ro;
      out[(long)rr*out_rs + co] = __float2bfloat16(tile[tx][ty+i]);
    }
  }
}

// ---------------- weight transpose fp32 -> bf16 hi/lo pair ----------------
__global__ void wtrans3(const float* __restrict__ in, bf16* __restrict__ oh, bf16* __restrict__ ol,
                        int R, int Cc, long in_rs, long out_rs)
{
  __shared__ float tile[32][33];
  int r0 = blockIdx.y*32, c0 = blockIdx.x*32;
  int tx = threadIdx.x, ty = threadIdx.y;
  #pragma unroll
  for (int i = 0; i < 32; i += 8) {
    int r = r0 + ty + i, c = c0 + tx;
    if (r < R && c < Cc) tile[ty+i][tx] = in[(long)r*in_rs + c];
  }
  __syncthreads();
  #pragma unroll
  for (int i = 0; i < 32; i += 8) {
    int ro = c0 + ty + i, co = r0 + tx;
    if (ro < Cc && co < R) {
      float v = tile[tx][ty+i];
      bf16 h = __float2bfloat16(v);
      long o = (long)ro*out_rs + co;
      oh[o] = h;
      ol[o] = __float2bfloat16(v - __bfloat162float(h));
    }
  }
}

// ---------------- LayerNorm ----------------
__global__ void ln_partial(const float* __restrict__ x, float* __restrict__ part) {
  int b = blockIdx.y, blk = blockIdx.x;
  const float* xb = x + (long)b*NPB;
  int start = blk * 4374;
  float s = 0.f, ss = 0.f;
  for (int i = start + threadIdx.x; i < start + 4374; i += 256) {
    float v = xb[i]; s += v; ss += v*v;
  }
  #pragma unroll
  for (int o = 32; o; o >>= 1) { s += __shfl_down(s, o); ss += __shfl_down(ss, o); }
  __shared__ float red[2][4];
  int wid = threadIdx.x >> 6, lid = threadIdx.x & 63;
  if (lid == 0) { red[0][wid] = s; red[1][wid] = ss; }
  __syncthreads();
  if (threadIdx.x == 0) {
    float S = 0.f, SS = 0.f;
    for (int w = 0; w < 4; ++w) { S += red[0][w]; SS += red[1][w]; }
    part[(b*128 + blk)*2] = S; part[(b*128 + blk)*2 + 1] = SS;
  }
}

__global__ void ln_final(const float* __restrict__ part, float* __restrict__ stats) {
  int b = blockIdx.x, lid = threadIdx.x;
  float s = 0.f, ss = 0.f;
  for (int i = lid; i < 128; i += 64) { s += part[(b*128+i)*2]; ss += part[(b*128+i)*2+1]; }
  #pragma unroll
  for (int o = 32; o; o >>= 1) { s += __shfl_down(s, o); ss += __shfl_down(ss, o); }
  if (lid == 0) {
    float mean = s / (float)NPB;
    float var = ss / (float)NPB - mean*mean;
    stats[b*2] = mean; stats[b*2+1] = rsqrtf(var + 1e-5f);
  }
}

__global__ void ln_apply3(const float* __restrict__ x, const float* __restrict__ lnw,
                          const float* __restrict__ lnb, const float* __restrict__ stats,
                          bf16* __restrict__ th, bf16* __restrict__ tl, long ts)
{
  __shared__ float tile[32][33];
  int b = blockIdx.z;
  int s0 = blockIdx.x*32, c0 = blockIdx.y*32;
  float mean = stats[b*2], rstd = stats[b*2+1];
  int tx = threadIdx.x, ty = threadIdx.y;
  #pragma unroll
  for (int i = 0; i < 32; i += 8) {
    int c = c0 + ty + i, s = s0 + tx;
    if (s < S_) {
      long o = (long)c*S_ + s;
      tile[ty+i][tx] = (x[(long)b*NPB + o] - mean)*rstd*lnw[o] + lnb[o];
    }
  }
  __syncthreads();
  #pragma unroll
  for (int i = 0; i < 32; i += 8) {
    int s = s0 + ty + i, c = c0 + tx;
    if (s < S_) {
      float v = tile[tx][ty+i];
      bf16 h = __float2bfloat16(v);
      long o = ((long)b*S_ + s)*ts + c;
      th[o] = h;
      tl[o] = __float2bfloat16(v - __bfloat162float(h));
    }
  }
}

// ------- V transpose (bf16), hi (z<64) and lo (z>=64), zero pad t in [S_, SPAD) -------
__global__ void vtrans2(const bf16* __restrict__ qkvh, const bf16* __restrict__ qkvl,
                        bf16* __restrict__ VTh, bf16* __restrict__ VTl)
{
  __shared__ float tile[32][33];
  int z = blockIdx.z;
  const bf16* qkv = (z < 64) ? qkvh : qkvl;
  bf16* VT = (z < 64) ? VTh : VTl;
  int zz = z & 63;
  int bb = zz >> 3, h = zz & 7;
  const bf16* v = qkv + (long)bb*S_*C3 + 1536 + h*DH_;
  bf16* o = VT + (long)zz*DH_*SPAD;
  int t0 = blockIdx.y*32, d0 = blockIdx.x*32;
  int tx = threadIdx.x, ty = threadIdx.y;
  #pragma unroll
  for (int i = 0; i < 32; i += 8) {
    int t = t0 + ty + i, d = d0 + tx;
    float val = 0.f;
    if (t < S_ && d < DH_) val = __bfloat162float(v[(long)t*C3 + d]);
    tile[ty+i][tx] = val;
  }
  __syncthreads();
  #pragma unroll
  for (int i = 0; i < 32; i += 8) {
    int d = d0 + ty + i, t = t0 + tx;
    if (d < DH_ && t < SPAD) o[(long)d*SPAD + t] = __float2bfloat16(tile[tx][ty+i]);
  }
}

// -------- softmax over bf16 hi/lo score rows, IN PLACE (row stride 2*SPAD) --------
__global__ void softmax3p(bf16* __restrict__ scores, int nrows) {
  int row = blockIdx.x*4 + (threadIdx.x >> 6);
  if (row >= nrows) return;
  int lid = threadIdx.x & 63;
  bf16* ph = scores + (long)row*2*SPAD;
  bf16* pl = ph + SPAD;
  float vals[12];
  float mx = -1e30f;
  #pragma unroll
  for (int i = 0; i < 12; ++i) {
    int t = i*64 + lid;
    float v = -1e30f;
    if (t < S_) v = __bfloat162float(ph[t]) + __bfloat162float(pl[t]);
    vals[i] = v; mx = fmaxf(mx, v);
  }
  #pragma unroll
  for (int o = 32; o; o >>= 1) mx = fmaxf(mx, __shfl_xor(mx, o));
  float sum = 0.f;
  #pragma unroll
  for (int i = 0; i < 12; ++i) { float e = __expf(vals[i] - mx); vals[i] = e; sum += e; }
  #pragma unroll
  for (int o = 32; o; o >>= 1) sum += __shfl_xor(sum, o);
  float inv = 1.f / sum;
  #pragma unroll
  for (int i = 0; i < 12; ++i) {
    int t = i*64 + lid;
    if (t < SPAD) {
      float p = (t < S_) ? vals[i]*inv : 0.f;
      bf16 h = __float2bfloat16(p);
      ph[t] = h;
      pl[t] = __float2bfloat16(p - __bfloat162float(h));
    }
  }
}

// ---------------- residual transpose-add 1 ----------------
__global__ void tadd1(const float* __restrict__ x, const float* __restrict__ oproj,
                      float* __restrict__ xattn, bf16* __restrict__ tok2,
                      float* __restrict__ tok2f)
{
  __shared__ float t_o[32][33];
  __shared__ float t_x[32][33];
  int b = blockIdx.z;
  int s0 = blockIdx.x*32, c0 = blockIdx.y*32;
  int tx = threadIdx.x, ty = threadIdx.y;
  #pragma unroll
  for (int i = 0; i < 32; i += 8) {
    int s = s0 + ty + i;
    if (s < S_) t_o[ty+i][tx] = oproj[((long)b*S_ + s)*C_ + c0 + tx];
    int s2 = s0 + tx;
    if (s2 < S_) t_x[ty+i][tx] = x[(long)b*NPB + (long)(c0+ty+i)*S_ + s2];
  }
  __syncthreads();
  #pragma unroll
  for (int i = 0; i < 32; i += 8) {
    int s = s0 + tx, c = c0 + ty + i;
    if (s < S_) xattn[(long)b*NPB + (long)c*S_ + s] = t_x[ty+i][tx] + t_o[tx][ty+i];
    int s2 = s0 + ty + i, c2 = c0 + tx;
    if (s2 < S_) {
      float v = t_x[tx][ty+i] + t_o[ty+i][tx];
      long o = ((long)b*S_ + s2)*C_ + c2;
      tok2[o] = __float2bfloat16(v);
      tok2f[o] = v;
    }
  }
}

// ---- residual transpose-add 2 (final output), sums 8 bf16 down-partials ----
__global__ void tadd2(const float* __restrict__ xattn, const bf16* __restrict__ prt,
                      float* __restrict__ out)
{
  __shared__ float t_m[32][33];
  __shared__ float t_x[32][33];
  int b = blockIdx.z;
  int s0 = blockIdx.x*32, c0 = blockIdx.y*32;
  int tx = threadIdx.x, ty = threadIdx.y;
  #pragma unroll
  for (int i = 0; i < 32; i += 8) {
    int s = s0 + ty + i;
    if (s < S_) {
      const bf16* p = prt + ((long)b*S_ + s)*768 + c0 + tx;
      float acc = 0.f;
      #pragma unroll
      for (int z = 0; z < 8; ++z) acc += __bfloat162float(p[(long)z*MTOK*768]);
      t_m[ty+i][tx] = acc;
    }
    int s2 = s0 + tx;
    if (s2 < S_) t_x[ty+i][tx] = xattn[(long)b*NPB + (long)(c0+ty+i)*S_ + s2];
  }
  __syncthreads();
  #pragma unroll
  for (int i = 0; i < 32; i += 8) {
    int s = s0 + tx, c = c0 + ty + i;
    if (s < S_) out[(long)b*NPB + (long)c*S_ + s] = t_x[ty+i][tx] + t_m[tx][ty+i];
  }
}

// ---------------- router: top-2 of 3 from fp32 tok2, normalized weights ----------------
__global__ void router_k(const float* __restrict__ tok2f, const float* __restrict__ rw,
                         float* __restrict__ wfull)
{
  int t = blockIdx.x*4 + (threadIdx.x >> 6);
  if (t >= MTOK) return;
  int lid = threadIdx.x & 63;
  const float* tk = tok2f + (long)t*C_;
  float a0 = 0.f, a1 = 0.f, a2 = 0.f;
  for (int i = lid; i < C_; i += 64) {
    float v = tk[i];
    a0 += v*rw[i*3+0]; a1 += v*rw[i*3+1]; a2 += v*rw[i*3+2];
  }
  #pragma unroll
  for (int o = 32; o; o >>= 1) {
    a0 += __shfl_xor(a0, o); a1 += __shfl_xor(a1, o); a2 += __shfl_xor(a2, o);
  }
  if (lid == 0) {
    float m = fmaxf(a0, fmaxf(a1, a2));
    float e0 = __expf(a0-m), e1 = __expf(a1-m), e2 = __expf(a2-m);
    int emin = 0; float pm = e0;
    if (e1 <= pm) { pm = e1; emin = 1; }
    if (e2 <= pm) { pm = e2; emin = 2; }
    float rest = e0 + e1 + e2 - pm;
    wfull[t*3+0] = (emin == 0) ? 0.f : e0/rest;
    wfull[t*3+1] = (emin == 1) ? 0.f : e1/rest;
    wfull[t*3+2] = (emin == 2) ? 0.f : e2/rest;
  }
}

// =============================== host ===============================
static inline void launch_gemm3(hipStream_t st,
    const bf16* Ah, const bf16* Al, long a_rs, long a_oo, long a_oi,
    const bf16* Bh, const bf16* Bl, long b_rs, long b_oo, long b_oi,
    float* Cf, bf16* Ch, bf16* Cl, long c_rs, long c_oo, long c_oi,
    int M, int N, int K, int nlim, int zdiv, int nz)
{
  dim3 g((N + 127)/128, (M + 127)/128, nz);
  gemm3_bt<<<g, 256, 0, st>>>(Ah, Al, a_rs, a_oo, a_oi, Bh, Bl, b_rs, b_oo, b_oi,
                              Cf, Ch, Cl, c_rs, c_oo, c_oi, M, N, K, nlim, zdiv);
}

extern "C" void kernel_launch(void* const* d_in, const int* in_sizes, int n_in,
                              void* d_out, int out_size, void* d_ws, size_t ws_size,
                              hipStream_t stream)
{
  const float* x      = (const float*)d_in[0];
  const float* ln_w   = (const float*)d_in[1];
  const float* ln_b   = (const float*)d_in[2];
  const float* qkv_w  = (const float*)d_in[3];
  const float* proj_w = (const float*)d_in[4];
  const float* rout_w = (const float*)d_in[5];
  const float* gate_w = (const float*)d_in[6];
  const float* up_w   = (const float*)d_in[7];
  const float* down_w = (const float*)d_in[8];
  float* out = (float*)d_out;

  char* ws = (char*)d_ws;
  size_t off = 0;
  auto alloc = [&](size_t bytes) { size_t r = off; off += (bytes + 255) & ~(size_t)255; return r; };

  // persistent (~82.6 MB)
  size_t o_stats = alloc(8*2*4);
  size_t o_part  = alloc(8*128*2*4);
  size_t o_wfull = alloc((size_t)MTOK*3*4);
  size_t o_qkvTh = alloc((size_t)C3*C_*2);
  size_t o_qkvTl = alloc((size_t)C3*C_*2);
  size_t o_prjTh = alloc((size_t)C_*C_*2);
  size_t o_prjTl = alloc((size_t)C_*C_*2);
  size_t o_guT   = alloc((size_t)GUN*C_*2);      // gate/up 16-row interleaved
  size_t o_downT = alloc((size_t)C_*DK*2);
  size_t o_xattn = alloc((size_t)B_*NPB*4);
  size_t o_tok2  = alloc((size_t)MTOK*C_*2);
  size_t o_tok2f = alloc((size_t)MTOK*C_*4);
  size_t big0 = off;
  // phase A (attention): fixed buffers + union region (tok | scores | oproj)
  size_t o_qkvh  = alloc((size_t)MTOK*C3*2);
  size_t o_qkvl  = alloc((size_t)MTOK*C3*2);
  size_t o_VTh   = alloc((size_t)64*DH_*SPAD*2);
  size_t o_VTl   = alloc((size_t)64*DH_*SPAD*2);
  size_t o_aoh   = alloc((size_t)MTOK*C_*2);
  size_t o_aol   = alloc((size_t)MTOK*C_*2);
  size_t o_union = alloc((size_t)32*S_*SPAD*4);  // 68.7 MB
  size_t endA = off;
  // phase B (MoE): hidden + 8 bf16 partials
  off = big0;
  size_t o_hid = alloc((size_t)MTOK*DK*2);
  size_t o_prt = alloc((size_t)8*MTOK*768*2);
  size_t endB = off;
  size_t needed = endA > endB ? endA : endB;
  if (ws_size < needed) return;  // insufficient workspace: visible failure

  float* stats  = (float*)(ws + o_stats);
  float* part   = (float*)(ws + o_part);
  float* wfull  = (float*)(ws + o_wfull);
  bf16*  qkvTh  = (bf16*)(ws + o_qkvTh);
  bf16*  qkvTl  = (bf16*)(ws + o_qkvTl);
  bf16*  prjTh  = (bf16*)(ws + o_prjTh);
  bf16*  prjTl  = (bf16*)(ws + o_prjTl);
  bf16*  guT    = (bf16*)(ws + o_guT);
  bf16*  downT  = (bf16*)(ws + o_downT);
  float* xattn  = (float*)(ws + o_xattn);
  bf16*  tok2   = (bf16*)(ws + o_tok2);
  float* tok2f  = (float*)(ws + o_tok2f);
  bf16*  qkvh   = (bf16*)(ws + o_qkvh);
  bf16*  qkvl   = (bf16*)(ws + o_qkvl);
  bf16*  VTh    = (bf16*)(ws + o_VTh);
  bf16*  VTl    = (bf16*)(ws + o_VTl);
  bf16*  aoh    = (bf16*)(ws + o_aoh);
  bf16*  aol    = (bf16*)(ws + o_aol);
  // union region occupants (live ranges disjoint in stream order):
  bf16*  tokh   = (bf16*)(ws + o_union);
  bf16*  tokl   = (bf16*)(ws + o_union + (size_t)MTOK*C_*2);
  bf16*  Pbase  = (bf16*)(ws + o_union);
  float* oproj  = (float*)(ws + o_union);
  bf16*  hidden = (bf16*)(ws + o_hid);
  bf16*  prt    = (bf16*)(ws + o_prt);

  dim3 b32(32, 8);

  // weight conversions (gate/up 16-row interleaved per 32-row block of guT)
  wtrans3<<<dim3(72,24,1), b32, 0, stream>>>(qkv_w,  qkvTh, qkvTl, 768, 2304, 2304, 768);
  wtrans3<<<dim3(24,24,1), b32, 0, stream>>>(proj_w, prjTh, prjTl, 768, 768,  768,  768);
  wtrans<<<dim3(64,24,3), b32, 0, stream>>>(gate_w, guT, 768, 2048, 2048, 768,
                                            (long)768*2048, (long)4096*768, 1, 0);
  wtrans<<<dim3(64,24,3), b32, 0, stream>>>(up_w, guT, 768, 2048, 2048, 768,
                                            (long)768*2048, (long)4096*768, 1, 16);
  wtrans<<<dim3(24,64,3), b32, 0, stream>>>(down_w, downT, 2048, 768, 768, 6144,
                                            (long)2048*768, 2048, 0, 0);

  // LayerNorm -> tok hi/lo (b,s,c)
  ln_partial<<<dim3(128,8), 256, 0, stream>>>(x, part);
  ln_final<<<8, 64, 0, stream>>>(part, stats);
  ln_apply3<<<dim3(23,24,8), b32, 0, stream>>>(x, ln_w, ln_b, stats, tokh, tokl, C_);

  // qkv = tok @ qkv_w (bf16x3, hi/lo out); tok region dead afterwards
  launch_gemm3(stream, tokh, tokl, C_, 0, 0, qkvTh, qkvTl, C_, 0, 0,
               nullptr, qkvh, qkvl, C3, 0, 0, MTOK, C3, C_, C3, 1, 1);

  // V^T per (b,h), hi+lo in one dispatch, zero-padded to SPAD
  vtrans2<<<dim3(3,23,128), b32, 0, stream>>>(qkvh, qkvl, VTh, VTl);

  // attention in 2 chunks of 32 (b,h)-pairs (4 batches each)
  for (int c = 0; c < 2; ++c) {
    const long qoff = (long)(4*c)*S_*C3;
    launch_gemm3(stream,
        qkvh + qoff, qkvl + qoff, C3, (long)S_*C3, DH_,
        qkvh + qoff + 768, qkvl + qoff + 768, C3, (long)S_*C3, DH_,
        nullptr, Pbase, Pbase + SPAD, 2*SPAD, (long)8*S_*2*SPAD, (long)S_*2*SPAD,
        S_, S_, DH_, SPAD, 8, 32);
    softmax3p<<<5832, 256, 0, stream>>>(Pbase, 32*S_);
    launch_gemm3(stream,
        Pbase, Pbase + SPAD, 2*SPAD, (long)8*S_*2*SPAD, (long)S_*2*SPAD,
        VTh + (size_t)c*32*DH_*SPAD, VTl + (size_t)c*32*DH_*SPAD, SPAD,
        (long)8*DH_*SPAD, (long)DH_*SPAD,
        nullptr, aoh + (size_t)(4*c)*S_*C_, aol + (size_t)(4*c)*S_*C_,
        C_, (long)S_*C_, DH_,
        S_, DH_, SPAD, DH_, 8, 32);
  }

  // oproj = attnout @ proj_w (fp32 out, into union region — P dead now)
  launch_gemm3(stream, aoh, aol, C_, 0, 0, prjTh, prjTl, C_, 0, 0,
               oproj, nullptr, nullptr, C_, 0, 0, MTOK, C_, C_, C_, 1, 1);

  // residual + layouts
  tadd1<<<dim3(23,24,8), b32, 0, stream>>>(x, oproj, xattn, tok2, tok2f);

  // router weights (fp32 path) — must precede fused GU epilogue
  router_k<<<1458, 256, 0, stream>>>(tok2f, rout_w, wfull);

  // GU gemm with fused silu*up*w epilogue -> hidden [MTOK][6144]  (128^2 high-occ kernel)
  gemm97<<<dim3(GUN/128, 46, 1), 256, 0, stream>>>(
      tok2, C_, guT, C_, nullptr, hidden, DK, 0, MTOK, GUN, C_, wfull, 3);

  // down GEMM (K=6144) nz=8 K-split, bf16 partials
  gemm97<<<dim3(C_/128, 46, 8), 256, 0, stream>>>(
      hidden, DK, downT, DK, nullptr, prt, 768, (long)MTOK*768, MTOK, C_, DK/8,
      nullptr, 0);

  // final residual transpose-add (sums 8 partials) into output
  tadd2<<<dim3(23,24,8), b32, 0, stream>>>(xattn, prt, out);
}

// Round 16
// 727.264 us; speedup vs baseline: 1.0868x; 1.0059x over previous
//
#include <hip/hip_runtime.h>
#include <hip/hip_bf16.h>

#define C_    768
#define NH_   8
#define DH_   96
#define S_    729
#define B_    8
#define MTOK  5832
#define C3    2304
#define GUN   12288
#define DK    6144
#define SPAD  736
#define NPB   559872   // C_*S_

typedef __attribute__((ext_vector_type(8))) short short8;
typedef __attribute__((ext_vector_type(4))) float f32x4;
typedef __attribute__((ext_vector_type(4))) unsigned int uint4v;
typedef __hip_bfloat16 bf16;

__device__ __forceinline__ void gld_lds16(const bf16* g, bf16* l) {
  __builtin_amdgcn_global_load_lds((const __attribute__((address_space(1))) void*)g,
                                   (__attribute__((address_space(3))) void*)l, 16, 0, 0);
}
__device__ __forceinline__ void gld_lds16c(const char* g, char* l) {
  __builtin_amdgcn_global_load_lds((const __attribute__((address_space(1))) void*)g,
                                   (__attribute__((address_space(3))) void*)l, 16, 0, 0);
}

// ========== 128x128 4-wave BK=32 double-buffered GEMM (m97-style, high occupancy) ==========
// Swizzle f(row) = (row>>1)&3: per 16-lane service group, same-parity lanes spread
// over all 4 chunk-XOR values -> 2 lanes per 16B bank-span (free) instead of 4-way.
template<int DBO>
__device__ __forceinline__ void g97_step(
    char* ldsc, char* ldsw, const int rA, const int rB, const int cx,
    const char*& pA0, const char*& pA1, const char*& pB0, const char*& pB1,
    const bool stage, f32x4 (&acc)[4][4])
{
  const int NBO = 16384 - DBO;
  if (stage) {
    gld_lds16c(pA0, ldsw + NBO);
    gld_lds16c(pA1, ldsw + NBO + 4096);
    gld_lds16c(pB0, ldsw + NBO + 8192);
    gld_lds16c(pB1, ldsw + NBO + 12288);
    pA0 += 64; pA1 += 64; pB0 += 64; pB1 += 64;
  }
  short8 a4[4], b4[4];
  #pragma unroll
  for (int mf = 0; mf < 4; ++mf)
    a4[mf] = *(const short8*)(ldsc + DBO + rA + mf*1024 + cx);
  #pragma unroll
  for (int nf = 0; nf < 4; ++nf)
    b4[nf] = *(const short8*)(ldsc + DBO + rB + nf*1024 + cx);
  __builtin_amdgcn_s_setprio(1);
  #pragma unroll
  for (int mf = 0; mf < 4; ++mf)
    #pragma unroll
    for (int nf = 0; nf < 4; ++nf)
      acc[mf][nf] = __builtin_amdgcn_mfma_f32_16x16x32_bf16(a4[mf], b4[nf], acc[mf][nf], 0, 0, 0);
  __builtin_amdgcn_s_setprio(0);
  asm volatile("s_waitcnt vmcnt(0)" ::: "memory");
  __builtin_amdgcn_s_barrier();
}

// modes: 0 = bf16 out (Cb, +z*c_zoff). 1 = fp32 out (Cf, +z*c_zoff).
// 3 = fused MoE: gate/up interleaved at 16-col granularity; writes
// silu(g)*u*wfull[row*3+e] bf16 to Cb[row*c_rs + h].
__global__ void __launch_bounds__(256, 4)
gemm97(const bf16* __restrict__ A, long a_rs,
       const bf16* __restrict__ Bt, long b_rs,
       float* __restrict__ Cf, bf16* __restrict__ Cb,
       long c_rs, long c_zoff, int M, int N, int Ksub,
       const float* __restrict__ wfull, int mode)
{
  __shared__ __attribute__((aligned(128))) char ldsc[32768];
  const int tid = threadIdx.x;
  const int wid = tid >> 6, lid = tid & 63;
  const int wm = wid >> 1, wn = wid & 1;           // 2 x 2 wave grid (64x64 each)
  const int fr = lid & 15, g8 = (lid >> 4) * 8;
  const int brow = blockIdx.y * 128, bcol = blockIdx.x * 128;
  const long k0b = (long)blockIdx.z * Ksub * 2;
  const long a_rsb = a_rs * 2, b_rsb = b_rs * 2;
  const int srow = tid >> 2;                        // 0..63
  const int scol = ((tid & 3) ^ ((tid >> 3) & 3)) << 4;  // f(row)=(row>>1)&3
  const int NT = Ksub >> 5;
  char* ldsw = ldsc + wid * 1024;                   // wave staging base (+lid*16)

  int ra0_ = brow + srow;       if (ra0_ > M-1) ra0_ = M-1;
  int ra1_ = brow + 64 + srow;  if (ra1_ > M-1) ra1_ = M-1;
  int rb0_ = bcol + srow;       if (rb0_ > N-1) rb0_ = N-1;
  int rb1_ = bcol + 64 + srow;  if (rb1_ > N-1) rb1_ = N-1;
  const char* pA0 = (const char*)A + (long)ra0_*a_rsb + k0b + scol;
  const char* pA1 = (const char*)A + (long)ra1_*a_rsb + k0b + scol;
  const char* pB0 = (const char*)Bt + (long)rb0_*b_rsb + k0b + scol;
  const char* pB1 = (const char*)Bt + (long)rb1_*b_rsb + k0b + scol;

  const int cx = (g8*2) ^ (((fr >> 1) & 3) << 4);   // read-side: f((row)&7)=(fr>>1)&3
  const int rA = (wm*64 + fr)*64;
  const int rB = 8192 + (wn*64 + fr)*64;

  f32x4 acc[4][4] = {};

  // prologue: stage T0 -> buf0
  gld_lds16c(pA0, ldsw);
  gld_lds16c(pA1, ldsw + 4096);
  gld_lds16c(pB0, ldsw + 8192);
  gld_lds16c(pB1, ldsw + 12288);
  pA0 += 64; pA1 += 64; pB0 += 64; pB1 += 64;
  asm volatile("s_waitcnt vmcnt(0)" ::: "memory");
  __builtin_amdgcn_s_barrier();

  for (int tp = 0; tp < NT; tp += 2) {
    g97_step<0>(ldsc, ldsw, rA, rB, cx, pA0, pA1, pB0, pB1, true, acc);
    g97_step<16384>(ldsc, ldsw, rA, rB, cx, pA0, pA1, pB0, pB1, (tp + 2) < NT, acc);
  }

  const int rg = (lid >> 4) * 4;
  if (mode == 3) {
    // fused silu(gate)*up*w; gate = acc[*][even nf], up = acc[*][odd nf]
    #pragma unroll
    for (int mf = 0; mf < 4; ++mf) {
      #pragma unroll
      for (int np = 0; np < 2; ++np) {
        const int hb = (bcol + wn*64 + np*32) >> 5;
        const int h = hb*16 + fr;
        const int e = h >> 11;
        #pragma unroll
        for (int j = 0; j < 4; ++j) {
          const int row = brow + wm*64 + mf*16 + rg + j;
          if (row < M) {
            float g = acc[mf][2*np][j];
            float u = acc[mf][2*np+1][j];
            float w = wfull[row*3 + e];
            float sg = g / (1.f + __expf(-g));
            Cb[(long)row*c_rs + h] = __float2bfloat16(sg * u * w);
          }
        }
      }
    }
  } else {
    #pragma unroll
    for (int mf = 0; mf < 4; ++mf) {
      #pragma unroll
      for (int nf = 0; nf < 4; ++nf) {
        const int col = bcol + wn*64 + nf*16 + fr;
        if (col < N) {
          #pragma unroll
          for (int j = 0; j < 4; ++j) {
            const int row = brow + wm*64 + mf*16 + rg + j;
            if (row < M) {
              long off = (long)blockIdx.z*c_zoff + (long)row*c_rs + col;
              if (mode == 0) Cb[off] = __float2bfloat16(acc[mf][nf][j]);
              else           Cf[off] = acc[mf][nf][j];
            }
          }
        }
      }
    }
  }
}

// ---------------- bf16x3 split GEMM: A=(Ah+Al), B=(Bh+Bl), 3 products ----------------
__global__ void __launch_bounds__(256, 3)
gemm3_bt(const bf16* __restrict__ Ah, const bf16* __restrict__ Al,
         long a_rs, long a_oo, long a_oi,
         const bf16* __restrict__ Bth, const bf16* __restrict__ Btl,
         long b_rs, long b_oo, long b_oi,
         float* __restrict__ Cf, bf16* __restrict__ Ch, bf16* __restrict__ Cl,
         long c_rs, long c_oo, long c_oi,
         int M, int N, int K, int nlim, int zdiv)
{
  __shared__ bf16 lAh[4096];
  __shared__ bf16 lAl[4096];
  __shared__ bf16 lBh[4096];
  __shared__ bf16 lBl[4096];
  const int tid = threadIdx.x;
  const int wid = tid >> 6;
  const int lid = tid & 63;
  const int z = blockIdx.z;
  const int zo = z / zdiv, zi = z - zo*zdiv;
  const long aoff = (long)zo*a_oo + (long)zi*a_oi;
  const long boff = (long)zo*b_oo + (long)zi*b_oi;
  const long cbase = (long)zo*c_oo + (long)zi*c_oi;
  const int brow = blockIdx.y * 128;
  const int bcol = blockIdx.x * 128;

  const int ch0 = tid, ch1 = tid + 256;
  int ra0 = brow + (ch0 >> 2); if (ra0 > M-1) ra0 = M-1;
  int ra1 = brow + (ch1 >> 2); if (ra1 > M-1) ra1 = M-1;
  int rb0 = bcol + (ch0 >> 2); if (rb0 > N-1) rb0 = N-1;
  int rb1 = bcol + (ch1 >> 2); if (rb1 > N-1) rb1 = N-1;
  const int sw = ((ch0 ^ (ch0 >> 3)) & 3) * 8;   // f(row)=(row>>1)&3, row=ch>>2
  // advancing staging pointers (+64B per K-tile)
  const char* qh0 = (const char*)(Ah + aoff + (long)ra0*a_rs + sw);
  const char* qh1 = (const char*)(Ah + aoff + (long)ra1*a_rs + sw);
  const char* ql0 = (const char*)(Al + aoff + (long)ra0*a_rs + sw);
  const char* ql1 = (const char*)(Al + aoff + (long)ra1*a_rs + sw);
  const char* rh0 = (const char*)(Bth + boff + (long)rb0*b_rs + sw);
  const char* rh1 = (const char*)(Bth + boff + (long)rb1*b_rs + sw);
  const char* rl0 = (const char*)(Btl + boff + (long)rb0*b_rs + sw);
  const char* rl1 = (const char*)(Btl + boff + (long)rb1*b_rs + sw);
  char* dAh0 = (char*)lAh + wid*1024;
  char* dAh1 = (char*)lAh + 4096 + wid*1024;
  char* dAl0 = (char*)lAl + wid*1024;
  char* dAl1 = (char*)lAl + 4096 + wid*1024;
  char* dBh0 = (char*)lBh + wid*1024;
  char* dBh1 = (char*)lBh + 4096 + wid*1024;
  char* dBl0 = (char*)lBl + wid*1024;
  char* dBl1 = (char*)lBl + 4096 + wid*1024;

  f32x4 acc[4][4] = {};
  const int wm = wid >> 1, wn = wid & 1;
  const int fr = lid & 15, g8 = (lid >> 4) * 8;
  const int gx = g8 ^ (((lid >> 1) & 3) << 3);   // read-side: f = (fr>>1)&3

  const int NTk = K >> 5;
  for (int kt = 0; kt < NTk; ++kt) {
    __syncthreads();
    gld_lds16c(qh0, dAh0);
    gld_lds16c(qh1, dAh1);
    gld_lds16c(ql0, dAl0);
    gld_lds16c(ql1, dAl1);
    gld_lds16c(rh0, dBh0);
    gld_lds16c(rh1, dBh1);
    gld_lds16c(rl0, dBl0);
    gld_lds16c(rl1, dBl1);
    qh0 += 64; qh1 += 64; ql0 += 64; ql1 += 64;
    rh0 += 64; rh1 += 64; rl0 += 64; rl1 += 64;
    __syncthreads();
    short8 fah[4], fal[4], fbh[4], fbl[4];
    #pragma unroll
    for (int m = 0; m < 4; ++m) {
      int ro = (wm*64 + m*16 + fr)*32 + gx;
      fah[m] = *(const short8*)&lAh[ro];
      fal[m] = *(const short8*)&lAl[ro];
    }
    #pragma unroll
    for (int n = 0; n < 4; ++n) {
      int ro = (wn*64 + n*16 + fr)*32 + gx;
      fbh[n] = *(const short8*)&lBh[ro];
      fbl[n] = *(const short8*)&lBl[ro];
    }
    #pragma unroll
    for (int m = 0; m < 4; ++m)
      #pragma unroll
      for (int n = 0; n < 4; ++n) {
        acc[m][n] = __builtin_amdgcn_mfma_f32_16x16x32_bf16(fal[m], fbh[n], acc[m][n], 0, 0, 0);
        acc[m][n] = __builtin_amdgcn_mfma_f32_16x16x32_bf16(fah[m], fbl[n], acc[m][n], 0, 0, 0);
        acc[m][n] = __builtin_amdgcn_mfma_f32_16x16x32_bf16(fah[m], fbh[n], acc[m][n], 0, 0, 0);
      }
  }

  const int rg = (lid >> 4) * 4;
  #pragma unroll
  for (int m = 0; m < 4; ++m) {
    #pragma unroll
    for (int n = 0; n < 4; ++n) {
      const int col = bcol + wn*64 + n*16 + fr;
      if (col < nlim) {
        #pragma unroll
        for (int j = 0; j < 4; ++j) {
          const int row = brow + wm*64 + m*16 + rg + j;
          if (row < M) {
            long off = cbase + (long)row*c_rs + col;
            float v = acc[m][n][j];
            if (Cl) {
              bf16 h = __float2bfloat16(v);
              Ch[off] = h;
              Cl[off] = __float2bfloat16(v - __bfloat162float(h));
            } else if (Ch) {
              Ch[off] = __float2bfloat16(v);
            } else {
              Cf[off] = v;
            }
          }
        }
      }
    }
  }
}

// ---------------- weight transpose fp32 -> bf16 (opt. 16-row interleave) ----------------
__global__ void wtrans(const float* __restrict__ in, bf16* __restrict__ out,
                       int R, int Cc, long in_rs, long out_rs, long in_bs, long out_bs,
                       int ilv, int radd)
{
  __shared__ float tile[32][33];
  in  += (long)blockIdx.z * in_bs;
  out += (long)blockIdx.z * out_bs;
  int r0 = blockIdx.y*32, c0 = blockIdx.x*32;
  int tx = threadIdx.x, ty = threadIdx.y;
  #pragma unroll
  for (int i = 0; i < 32; i += 8) {
    int r = r0 + ty + i, c = c0 + tx;
    if (r < R && c < Cc) tile[ty+i][tx] = in[(long)r*in_rs + c];
  }
  __syncthreads();
  #pragma unroll
  for (int i = 0; i < 32; i += 8) {
    int ro = c0 + ty + i, co = r0 + tx;
    if (ro < Cc && co < R) {
      int rr = ilv ? (((ro >> 4) << 5) + (ro & 15) + radd) : ro;
      out[(long)rr*out_rs + co] = __float2bfloat16(tile[tx][ty+i]);
    }
  }
}

// ---------------- weight transpose fp32 -> bf16 hi/lo pair ----------------
__global__ void wtrans3(const float* __restrict__ in, bf16* __restrict__ oh, bf16* __restrict__ ol,
                        int R, int Cc, long in_rs, long out_rs)
{
  __shared__ float tile[32][33];
  int r0 = blockIdx.y*32, c0 = blockIdx.x*32;
  int tx = threadIdx.x, ty = threadIdx.y;
  #pragma unroll
  for (int i = 0; i < 32; i += 8) {
    int r = r0 + ty + i, c = c0 + tx;
    if (r < R && c < Cc) tile[ty+i][tx] = in[(long)r*in_rs + c];
  }
  __syncthreads();
  #pragma unroll
  for (int i = 0; i < 32; i += 8) {
    int ro = c0 + ty + i, co = r0 + tx;
    if (ro < Cc && co < R) {
      float v = tile[tx][ty+i];
      bf16 h = __float2bfloat16(v);
      long o = (long)ro*out_rs + co;
      oh[o] = h;
      ol[o] = __float2bfloat16(v - __bfloat162float(h));
    }
  }
}

// ---------------- LayerNorm ----------------
__global__ void ln_partial(const float* __restrict__ x, float* __restrict__ part) {
  int b = blockIdx.y, blk = blockIdx.x;
  const float* xb = x + (long)b*NPB;
  int start = blk * 4374;
  float s = 0.f, ss = 0.f;
  for (int i = start + threadIdx.x; i < start + 4374; i += 256) {
    float v = xb[i]; s += v; ss += v*v;
  }
  #pragma unroll
  for (int o = 32; o; o >>= 1) { s += __shfl_down(s, o); ss += __shfl_down(ss, o); }
  __shared__ float red[2][4];
  int wid = threadIdx.x >> 6, lid = threadIdx.x & 63;
  if (lid == 0) { red[0][wid] = s; red[1][wid] = ss; }
  __syncthreads();
  if (threadIdx.x == 0) {
    float S = 0.f, SS = 0.f;
    for (int w = 0; w < 4; ++w) { S += red[0][w]; SS += red[1][w]; }
    part[(b*128 + blk)*2] = S; part[(b*128 + blk)*2 + 1] = SS;
  }
}

__global__ void ln_final(const float* __restrict__ part, float* __restrict__ stats) {
  int b = blockIdx.x, lid = threadIdx.x;
  float s = 0.f, ss = 0.f;
  for (int i = lid; i < 128; i += 64) { s += part[(b*128+i)*2]; ss += part[(b*128+i)*2+1]; }
  #pragma unroll
  for (int o = 32; o; o >>= 1) { s += __shfl_down(s, o); ss += __shfl_down(ss, o); }
  if (lid == 0) {
    float mean = s / (float)NPB;
    float var = ss / (float)NPB - mean*mean;
    stats[b*2] = mean; stats[b*2+1] = rsqrtf(var + 1e-5f);
  }
}

__global__ void ln_apply3(const float* __restrict__ x, const float* __restrict__ lnw,
                          const float* __restrict__ lnb, const float* __restrict__ stats,
                          bf16* __restrict__ th, bf16* __restrict__ tl, long ts)
{
  __shared__ float tile[32][33];
  int b = blockIdx.z;
  int s0 = blockIdx.x*32, c0 = blockIdx.y*32;
  float mean = stats[b*2], rstd = stats[b*2+1];
  int tx = threadIdx.x, ty = threadIdx.y;
  #pragma unroll
  for (int i = 0; i < 32; i += 8) {
    int c = c0 + ty + i, s = s0 + tx;
    if (s < S_) {
      long o = (long)c*S_ + s;
      tile[ty+i][tx] = (x[(long)b*NPB + o] - mean)*rstd*lnw[o] + lnb[o];
    }
  }
  __syncthreads();
  #pragma unroll
  for (int i = 0; i < 32; i += 8) {
    int s = s0 + ty + i, c = c0 + tx;
    if (s < S_) {
      float v = tile[tx][ty+i];
      bf16 h = __float2bfloat16(v);
      long o = ((long)b*S_ + s)*ts + c;
      th[o] = h;
      tl[o] = __float2bfloat16(v - __bfloat162float(h));
    }
  }
}

// ------- V transpose (bf16), hi (z<64) and lo (z>=64), zero pad t in [S_, SPAD) -------
__global__ void vtrans2(const bf16* __restrict__ qkvh, const bf16* __restrict__ qkvl,
                        bf16* __restrict__ VTh, bf16* __restrict__ VTl)
{
  __shared__ float tile[32][33];
  int z = blockIdx.z;
  const bf16* qkv = (z < 64) ? qkvh : qkvl;
  bf16* VT = (z < 64) ? VTh : VTl;
  int zz = z & 63;
  int bb = zz >> 3, h = zz & 7;
  const bf16* v = qkv + (long)bb*S_*C3 + 1536 + h*DH_;
  bf16* o = VT + (long)zz*DH_*SPAD;
  int t0 = blockIdx.y*32, d0 = blockIdx.x*32;
  int tx = threadIdx.x, ty = threadIdx.y;
  #pragma unroll
  for (int i = 0; i < 32; i += 8) {
    int t = t0 + ty + i, d = d0 + tx;
    float val = 0.f;
    if (t < S_ && d < DH_) val = __bfloat162float(v[(long)t*C3 + d]);
    tile[ty+i][tx] = val;
  }
  __syncthreads();
  #pragma unroll
  for (int i = 0; i < 32; i += 8) {
    int d = d0 + ty + i, t = t0 + tx;
    if (d < DH_ && t < SPAD) o[(long)d*SPAD + t] = __float2bfloat16(tile[tx][ty+i]);
  }
}

// -------- softmax over bf16 hi/lo score rows, IN PLACE (row stride 2*SPAD) --------
__global__ void softmax3p(bf16* __restrict__ scores, int nrows) {
  int row = blockIdx.x*4 + (threadIdx.x >> 6);
  if (row >= nrows) return;
  int lid = threadIdx.x & 63;
  bf16* ph = scores + (long)row*2*SPAD;
  bf16* pl = ph + SPAD;
  float vals[12];
  float mx = -1e30f;
  #pragma unroll
  for (int i = 0; i < 12; ++i) {
    int t = i*64 + lid;
    float v = -1e30f;
    if (t < S_) v = __bfloat162float(ph[t]) + __bfloat162float(pl[t]);
    vals[i] = v; mx = fmaxf(mx, v);
  }
  #pragma unroll
  for (int o = 32; o; o >>= 1) mx = fmaxf(mx, __shfl_xor(mx, o));
  float sum = 0.f;
  #pragma unroll
  for (int i = 0; i < 12; ++i) { float e = __expf(vals[i] - mx); vals[i] = e; sum += e; }
  #pragma unroll
  for (int o = 32; o; o >>= 1) sum += __shfl_xor(sum, o);
  float inv = 1.f / sum;
  #pragma unroll
  for (int i = 0; i < 12; ++i) {
    int t = i*64 + lid;
    if (t < SPAD) {
      float p = (t < S_) ? vals[i]*inv : 0.f;
      bf16 h = __float2bfloat16(p);
      ph[t] = h;
      pl[t] = __float2bfloat16(p - __bfloat162float(h));
    }
  }
}

// ---------------- residual transpose-add 1 ----------------
__global__ void tadd1(const float* __restrict__ x, const float* __restrict__ oproj,
                      float* __restrict__ xattn, bf16* __restrict__ tok2,
                      float* __restrict__ tok2f)
{
  __shared__ float t_o[32][33];
  __shared__ float t_x[32][33];
  int b = blockIdx.z;
  int s0 = blockIdx.x*32, c0 = blockIdx.y*32;
  int tx = threadIdx.x, ty = threadIdx.y;
  #pragma unroll
  for (int i = 0; i < 32; i += 8) {
    int s = s0 + ty + i;
    if (s < S_) t_o[ty+i][tx] = oproj[((long)b*S_ + s)*C_ + c0 + tx];
    int s2 = s0 + tx;
    if (s2 < S_) t_x[ty+i][tx] = x[(long)b*NPB + (long)(c0+ty+i)*S_ + s2];
  }
  __syncthreads();
  #pragma unroll
  for (int i = 0; i < 32; i += 8) {
    int s = s0 + tx, c = c0 + ty + i;
    if (s < S_) xattn[(long)b*NPB + (long)c*S_ + s] = t_x[ty+i][tx] + t_o[tx][ty+i];
    int s2 = s0 + ty + i, c2 = c0 + tx;
    if (s2 < S_) {
      float v = t_x[tx][ty+i] + t_o[ty+i][tx];
      long o = ((long)b*S_ + s2)*C_ + c2;
      tok2[o] = __float2bfloat16(v);
      tok2f[o] = v;
    }
  }
}

// ---- residual transpose-add 2 (final output), sums 8 bf16 down-partials ----
__global__ void tadd2(const float* __restrict__ xattn, const bf16* __restrict__ prt,
                      float* __restrict__ out)
{
  __shared__ float t_m[32][33];
  __shared__ float t_x[32][33];
  int b = blockIdx.z;
  int s0 = blockIdx.x*32, c0 = blockIdx.y*32;
  int tx = threadIdx.x, ty = threadIdx.y;
  #pragma unroll
  for (int i = 0; i < 32; i += 8) {
    int s = s0 + ty + i;
    if (s < S_) {
      const bf16* p = prt + ((long)b*S_ + s)*768 + c0 + tx;
      float acc = 0.f;
      #pragma unroll
      for (int z = 0; z < 8; ++z) acc += __bfloat162float(p[(long)z*MTOK*768]);
      t_m[ty+i][tx] = acc;
    }
    int s2 = s0 + tx;
    if (s2 < S_) t_x[ty+i][tx] = xattn[(long)b*NPB + (long)(c0+ty+i)*S_ + s2];
  }
  __syncthreads();
  #pragma unroll
  for (int i = 0; i < 32; i += 8) {
    int s = s0 + tx, c = c0 + ty + i;
    if (s < S_) out[(long)b*NPB + (long)c*S_ + s] = t_x[ty+i][tx] + t_m[tx][ty+i];
  }
}

// ---------------- router: top-2 of 3 from fp32 tok2, normalized weights ----------------
__global__ void router_k(const float* __restrict__ tok2f, const float* __restrict__ rw,
                         float* __restrict__ wfull)
{
  int t = blockIdx.x*4 + (threadIdx.x >> 6);
  if (t >= MTOK) return;
  int lid = threadIdx.x & 63;
  const float* tk = tok2f + (long)t*C_;
  float a0 = 0.f, a1 = 0.f, a2 = 0.f;
  for (int i = lid; i < C_; i += 64) {
    float v = tk[i];
    a0 += v*rw[i*3+0]; a1 += v*rw[i*3+1]; a2 += v*rw[i*3+2];
  }
  #pragma unroll
  for (int o = 32; o; o >>= 1) {
    a0 += __shfl_xor(a0, o); a1 += __shfl_xor(a1, o); a2 += __shfl_xor(a2, o);
  }
  if (lid == 0) {
    float m = fmaxf(a0, fmaxf(a1, a2));
    float e0 = __expf(a0-m), e1 = __expf(a1-m), e2 = __expf(a2-m);
    int emin = 0; float pm = e0;
    if (e1 <= pm) { pm = e1; emin = 1; }
    if (e2 <= pm) { pm = e2; emin = 2; }
    float rest = e0 + e1 + e2 - pm;
    wfull[t*3+0] = (emin == 0) ? 0.f : e0/rest;
    wfull[t*3+1] = (emin == 1) ? 0.f : e1/rest;
    wfull[t*3+2] = (emin == 2) ? 0.f : e2/rest;
  }
}

// =============================== host ===============================
static inline void launch_gemm3(hipStream_t st,
    const bf16* Ah, const bf16* Al, long a_rs, long a_oo, long a_oi,
    const bf16* Bh, const bf16* Bl, long b_rs, long b_oo, long b_oi,
    float* Cf, bf16* Ch, bf16* Cl, long c_rs, long c_oo, long c_oi,
    int M, int N, int K, int nlim, int zdiv, int nz)
{
  dim3 g((N + 127)/128, (M + 127)/128, nz);
  gemm3_bt<<<g, 256, 0, st>>>(Ah, Al, a_rs, a_oo, a_oi, Bh, Bl, b_rs, b_oo, b_oi,
                              Cf, Ch, Cl, c_rs, c_oo, c_oi, M, N, K, nlim, zdiv);
}

extern "C" void kernel_launch(void* const* d_in, const int* in_sizes, int n_in,
                              void* d_out, int out_size, void* d_ws, size_t ws_size,
                              hipStream_t stream)
{
  const float* x      = (const float*)d_in[0];
  const float* ln_w   = (const float*)d_in[1];
  const float* ln_b   = (const float*)d_in[2];
  const float* qkv_w  = (const float*)d_in[3];
  const float* proj_w = (const float*)d_in[4];
  const float* rout_w = (const float*)d_in[5];
  const float* gate_w = (const float*)d_in[6];
  const float* up_w   = (const float*)d_in[7];
  const float* down_w = (const float*)d_in[8];
  float* out = (float*)d_out;

  char* ws = (char*)d_ws;
  size_t off = 0;
  auto alloc = [&](size_t bytes) { size_t r = off; off += (bytes + 255) & ~(size_t)255; return r; };

  // persistent (~82.6 MB)
  size_t o_stats = alloc(8*2*4);
  size_t o_part  = alloc(8*128*2*4);
  size_t o_wfull = alloc((size_t)MTOK*3*4);
  size_t o_qkvTh = alloc((size_t)C3*C_*2);
  size_t o_qkvTl = alloc((size_t)C3*C_*2);
  size_t o_prjTh = alloc((size_t)C_*C_*2);
  size_t o_prjTl = alloc((size_t)C_*C_*2);
  size_t o_guT   = alloc((size_t)GUN*C_*2);      // gate/up 16-row interleaved
  size_t o_downT = alloc((size_t)C_*DK*2);
  size_t o_xattn = alloc((size_t)B_*NPB*4);
  size_t o_tok2  = alloc((size_t)MTOK*C_*2);
  size_t o_tok2f = alloc((size_t)MTOK*C_*4);
  size_t big0 = off;
  // phase A (attention): fixed buffers + union region (tok | scores | oproj)
  size_t o_qkvh  = alloc((size_t)MTOK*C3*2);
  size_t o_qkvl  = alloc((size_t)MTOK*C3*2);
  size_t o_VTh   = alloc((size_t)64*DH_*SPAD*2);
  size_t o_VTl   = alloc((size_t)64*DH_*SPAD*2);
  size_t o_aoh   = alloc((size_t)MTOK*C_*2);
  size_t o_aol   = alloc((size_t)MTOK*C_*2);
  size_t o_union = alloc((size_t)32*S_*SPAD*4);  // 68.7 MB
  size_t endA = off;
  // phase B (MoE): hidden + 8 bf16 partials
  off = big0;
  size_t o_hid = alloc((size_t)MTOK*DK*2);
  size_t o_prt = alloc((size_t)8*MTOK*768*2);
  size_t endB = off;
  size_t needed = endA > endB ? endA : endB;
  if (ws_size < needed) return;  // insufficient workspace: visible failure

  float* stats  = (float*)(ws + o_stats);
  float* part   = (float*)(ws + o_part);
  float* wfull  = (float*)(ws + o_wfull);
  bf16*  qkvTh  = (bf16*)(ws + o_qkvTh);
  bf16*  qkvTl  = (bf16*)(ws + o_qkvTl);
  bf16*  prjTh  = (bf16*)(ws + o_prjTh);
  bf16*  prjTl  = (bf16*)(ws + o_prjTl);
  bf16*  guT    = (bf16*)(ws + o_guT);
  bf16*  downT  = (bf16*)(ws + o_downT);
  float* xattn  = (float*)(ws + o_xattn);
  bf16*  tok2   = (bf16*)(ws + o_tok2);
  float* tok2f  = (float*)(ws + o_tok2f);
  bf16*  qkvh   = (bf16*)(ws + o_qkvh);
  bf16*  qkvl   = (bf16*)(ws + o_qkvl);
  bf16*  VTh    = (bf16*)(ws + o_VTh);
  bf16*  VTl    = (bf16*)(ws + o_VTl);
  bf16*  aoh    = (bf16*)(ws + o_aoh);
  bf16*  aol    = (bf16*)(ws + o_aol);
  // union region occupants (live ranges disjoint in stream order):
  bf16*  tokh   = (bf16*)(ws + o_union);
  bf16*  tokl   = (bf16*)(ws + o_union + (size_t)MTOK*C_*2);
  bf16*  Pbase  = (bf16*)(ws + o_union);
  float* oproj  = (float*)(ws + o_union);
  bf16*  hidden = (bf16*)(ws + o_hid);
  bf16*  prt    = (bf16*)(ws + o_prt);

  dim3 b32(32, 8);

  // weight conversions (gate/up 16-row interleaved per 32-row block of guT)
  wtrans3<<<dim3(72,24,1), b32, 0, stream>>>(qkv_w,  qkvTh, qkvTl, 768, 2304, 2304, 768);
  wtrans3<<<dim3(24,24,1), b32, 0, stream>>>(proj_w, prjTh, prjTl, 768, 768,  768,  768);
  wtrans<<<dim3(64,24,3), b32, 0, stream>>>(gate_w, guT, 768, 2048, 2048, 768,
                                            (long)768*2048, (long)4096*768, 1, 0);
  wtrans<<<dim3(64,24,3), b32, 0, stream>>>(up_w, guT, 768, 2048, 2048, 768,
                                            (long)768*2048, (long)4096*768, 1, 16);
  wtrans<<<dim3(24,64,3), b32, 0, stream>>>(down_w, downT, 2048, 768, 768, 6144,
                                            (long)2048*768, 2048, 0, 0);

  // LayerNorm -> tok hi/lo (b,s,c)
  ln_partial<<<dim3(128,8), 256, 0, stream>>>(x, part);
  ln_final<<<8, 64, 0, stream>>>(part, stats);
  ln_apply3<<<dim3(23,24,8), b32, 0, stream>>>(x, ln_w, ln_b, stats, tokh, tokl, C_);

  // qkv = tok @ qkv_w (bf16x3, hi/lo out); tok region dead afterwards
  launch_gemm3(stream, tokh, tokl, C_, 0, 0, qkvTh, qkvTl, C_, 0, 0,
               nullptr, qkvh, qkvl, C3, 0, 0, MTOK, C3, C_, C3, 1, 1);

  // V^T per (b,h), hi+lo in one dispatch, zero-padded to SPAD
  vtrans2<<<dim3(3,23,128), b32, 0, stream>>>(qkvh, qkvl, VTh, VTl);

  // attention in 2 chunks of 32 (b,h)-pairs (4 batches each)
  for (int c = 0; c < 2; ++c) {
    const long qoff = (long)(4*c)*S_*C3;
    launch_gemm3(stream,
        qkvh + qoff, qkvl + qoff, C3, (long)S_*C3, DH_,
        qkvh + qoff + 768, qkvl + qoff + 768, C3, (long)S_*C3, DH_,
        nullptr, Pbase, Pbase + SPAD, 2*SPAD, (long)8*S_*2*SPAD, (long)S_*2*SPAD,
        S_, S_, DH_, SPAD, 8, 32);
    softmax3p<<<5832, 256, 0, stream>>>(Pbase, 32*S_);
    launch_gemm3(stream,
        Pbase, Pbase + SPAD, 2*SPAD, (long)8*S_*2*SPAD, (long)S_*2*SPAD,
        VTh + (size_t)c*32*DH_*SPAD, VTl + (size_t)c*32*DH_*SPAD, SPAD,
        (long)8*DH_*SPAD, (long)DH_*SPAD,
        nullptr, aoh + (size_t)(4*c)*S_*C_, aol + (size_t)(4*c)*S_*C_,
        C_, (long)S_*C_, DH_,
        S_, DH_, SPAD, DH_, 8, 32);
  }

  // oproj = attnout @ proj_w (fp32 out, into union region — P dead now)
  launch_gemm3(stream, aoh, aol, C_, 0, 0, prjTh, prjTl, C_, 0, 0,
               oproj, nullptr, nullptr, C_, 0, 0, MTOK, C_, C_, C_, 1, 1);

  // residual + layouts
  tadd1<<<dim3(23,24,8), b32, 0, stream>>>(x, oproj, xattn, tok2, tok2f);

  // router weights (fp32 path) — must precede fused GU epilogue
  router_k<<<1458, 256, 0, stream>>>(tok2f, rout_w, wfull);

  // GU gemm with fused silu*up*w epilogue -> hidden [MTOK][6144]  (128^2 high-occ kernel)
  gemm97<<<dim3(GUN/128, 46, 1), 256, 0, stream>>>(
      tok2, C_, guT, C_, nullptr, hidden, DK, 0, MTOK, GUN, C_, wfull, 3);

  // down GEMM (K=6144) nz=8 K-split, bf16 partials
  gemm97<<<dim3(C_/128, 46, 8), 256, 0, stream>>>(
      hidden, DK, downT, DK, nullptr, prt, 768, (long)MTOK*768, MTOK, C_, DK/8,
      nullptr, 0);

  // final residual transpose-add (sums 8 partials) into output
  tadd2<<<dim3(23,24,8), b32, 0, stream>>>(xattn, prt, out);
}

// Round 17
// 701.032 us; speedup vs baseline: 1.1275x; 1.0374x over previous
//
#include <hip/hip_runtime.h>
#include <hip/hip_bf16.h>

#define C_    768
#define NH_   8
#define DH_   96
#define S_    729
#define B_    8
#define MTOK  5832
#define C3    2304
#define GUN   12288
#define DK    6144
#define SPAD  736
#define NPB   559872   // C_*S_

typedef __attribute__((ext_vector_type(8))) short short8;
typedef __attribute__((ext_vector_type(4))) float f32x4;
typedef __attribute__((ext_vector_type(4))) unsigned int uint4v;
typedef __hip_bfloat16 bf16;

__device__ __forceinline__ void gld_lds16c(const char* g, char* l) {
  __builtin_amdgcn_global_load_lds((const __attribute__((address_space(1))) void*)g,
                                   (__attribute__((address_space(3))) void*)l, 16, 0, 0);
}

// ========== 128x128 4-wave BK=32 double-buffered GEMM (m97-style, high occupancy) ==========
// Swizzle f(row) = (row>>1)&3 -> 2-way LDS access (free). Verified r16: conflicts = 0.
template<int DBO>
__device__ __forceinline__ void g97_step(
    char* ldsc, char* ldsw, const int rA, const int rB, const int cx,
    const char*& pA0, const char*& pA1, const char*& pB0, const char*& pB1,
    const bool stage, f32x4 (&acc)[4][4])
{
  const int NBO = 16384 - DBO;
  if (stage) {
    gld_lds16c(pA0, ldsw + NBO);
    gld_lds16c(pA1, ldsw + NBO + 4096);
    gld_lds16c(pB0, ldsw + NBO + 8192);
    gld_lds16c(pB1, ldsw + NBO + 12288);
    pA0 += 64; pA1 += 64; pB0 += 64; pB1 += 64;
  }
  short8 a4[4], b4[4];
  #pragma unroll
  for (int mf = 0; mf < 4; ++mf)
    a4[mf] = *(const short8*)(ldsc + DBO + rA + mf*1024 + cx);
  #pragma unroll
  for (int nf = 0; nf < 4; ++nf)
    b4[nf] = *(const short8*)(ldsc + DBO + rB + nf*1024 + cx);
  __builtin_amdgcn_s_setprio(1);
  #pragma unroll
  for (int mf = 0; mf < 4; ++mf)
    #pragma unroll
    for (int nf = 0; nf < 4; ++nf)
      acc[mf][nf] = __builtin_amdgcn_mfma_f32_16x16x32_bf16(a4[mf], b4[nf], acc[mf][nf], 0, 0, 0);
  __builtin_amdgcn_s_setprio(0);
  asm volatile("s_waitcnt vmcnt(0)" ::: "memory");
  __builtin_amdgcn_s_barrier();
}

// modes: 0 = bf16 out (Cb, +z*c_zoff). 1 = fp32 out (Cf, +z*c_zoff).
// 3 = fused MoE: gate/up interleaved at 16-col granularity; writes
// silu(g)*u*wfull[row*3+e] bf16 to Cb[row*c_rs + h].
__global__ void __launch_bounds__(256, 4)
gemm97(const bf16* __restrict__ A, long a_rs,
       const bf16* __restrict__ Bt, long b_rs,
       float* __restrict__ Cf, bf16* __restrict__ Cb,
       long c_rs, long c_zoff, int M, int N, int Ksub,
       const float* __restrict__ wfull, int mode)
{
  __shared__ __attribute__((aligned(128))) char ldsc[32768];
  const int tid = threadIdx.x;
  const int wid = tid >> 6, lid = tid & 63;
  const int wm = wid >> 1, wn = wid & 1;           // 2 x 2 wave grid (64x64 each)
  const int fr = lid & 15, g8 = (lid >> 4) * 8;
  const int brow = blockIdx.y * 128, bcol = blockIdx.x * 128;
  const long k0b = (long)blockIdx.z * Ksub * 2;
  const long a_rsb = a_rs * 2, b_rsb = b_rs * 2;
  const int srow = tid >> 2;                        // 0..63
  const int scol = ((tid & 3) ^ ((tid >> 3) & 3)) << 4;  // f(row)=(row>>1)&3
  const int NT = Ksub >> 5;
  char* ldsw = ldsc + wid * 1024;                   // wave staging base (+lid*16)

  int ra0_ = brow + srow;       if (ra0_ > M-1) ra0_ = M-1;
  int ra1_ = brow + 64 + srow;  if (ra1_ > M-1) ra1_ = M-1;
  int rb0_ = bcol + srow;       if (rb0_ > N-1) rb0_ = N-1;
  int rb1_ = bcol + 64 + srow;  if (rb1_ > N-1) rb1_ = N-1;
  const char* pA0 = (const char*)A + (long)ra0_*a_rsb + k0b + scol;
  const char* pA1 = (const char*)A + (long)ra1_*a_rsb + k0b + scol;
  const char* pB0 = (const char*)Bt + (long)rb0_*b_rsb + k0b + scol;
  const char* pB1 = (const char*)Bt + (long)rb1_*b_rsb + k0b + scol;

  const int cx = (g8*2) ^ (((fr >> 1) & 3) << 4);   // read-side: f = (fr>>1)&3
  const int rA = (wm*64 + fr)*64;
  const int rB = 8192 + (wn*64 + fr)*64;

  f32x4 acc[4][4] = {};

  // prologue: stage T0 -> buf0
  gld_lds16c(pA0, ldsw);
  gld_lds16c(pA1, ldsw + 4096);
  gld_lds16c(pB0, ldsw + 8192);
  gld_lds16c(pB1, ldsw + 12288);
  pA0 += 64; pA1 += 64; pB0 += 64; pB1 += 64;
  asm volatile("s_waitcnt vmcnt(0)" ::: "memory");
  __builtin_amdgcn_s_barrier();

  for (int tp = 0; tp < NT; tp += 2) {
    g97_step<0>(ldsc, ldsw, rA, rB, cx, pA0, pA1, pB0, pB1, true, acc);
    g97_step<16384>(ldsc, ldsw, rA, rB, cx, pA0, pA1, pB0, pB1, (tp + 2) < NT, acc);
  }

  const int rg = (lid >> 4) * 4;
  if (mode == 3) {
    // fused silu(gate)*up*w; gate = acc[*][even nf], up = acc[*][odd nf]
    #pragma unroll
    for (int mf = 0; mf < 4; ++mf) {
      #pragma unroll
      for (int np = 0; np < 2; ++np) {
        const int hb = (bcol + wn*64 + np*32) >> 5;
        const int h = hb*16 + fr;
        const int e = h >> 11;
        #pragma unroll
        for (int j = 0; j < 4; ++j) {
          const int row = brow + wm*64 + mf*16 + rg + j;
          if (row < M) {
            float g = acc[mf][2*np][j];
            float u = acc[mf][2*np+1][j];
            float w = wfull[row*3 + e];
            float sg = g / (1.f + __expf(-g));
            Cb[(long)row*c_rs + h] = __float2bfloat16(sg * u * w);
          }
        }
      }
    }
  } else {
    #pragma unroll
    for (int mf = 0; mf < 4; ++mf) {
      #pragma unroll
      for (int nf = 0; nf < 4; ++nf) {
        const int col = bcol + wn*64 + nf*16 + fr;
        if (col < N) {
          #pragma unroll
          for (int j = 0; j < 4; ++j) {
            const int row = brow + wm*64 + mf*16 + rg + j;
            if (row < M) {
              long off = (long)blockIdx.z*c_zoff + (long)row*c_rs + col;
              if (mode == 0) Cb[off] = __float2bfloat16(acc[mf][nf][j]);
              else           Cf[off] = acc[mf][nf][j];
            }
          }
        }
      }
    }
  }
}

// ------- bf16x3 split GEMM, DOUBLE-BUFFERED (A=(Ah+Al), B=(Bh+Bl), 3 products) -------
// LDS 64KB = 2 x {Ah|Al|Bh|Bl} 8KB each. Per tile: stage t+1 -> nb; read db; 48 MFMA;
// vmcnt(0); bar. Same chunk-XOR swizzle f(row)=(row>>1)&3 both sides.
template<int DBO>
__device__ __forceinline__ void g3_step(
    char* ldsc, char* ldsw, const int wm, const int wn, const int cx, const int fr,
    const char*& qh0, const char*& qh1, const char*& ql0, const char*& ql1,
    const char*& rh0, const char*& rh1, const char*& rl0, const char*& rl1,
    const bool stage, f32x4 (&acc)[4][4])
{
  const int NBO = 32768 - DBO;
  if (stage) {
    gld_lds16c(qh0, ldsw + NBO);
    gld_lds16c(qh1, ldsw + NBO + 4096);
    gld_lds16c(ql0, ldsw + NBO + 8192);
    gld_lds16c(ql1, ldsw + NBO + 12288);
    gld_lds16c(rh0, ldsw + NBO + 16384);
    gld_lds16c(rh1, ldsw + NBO + 20480);
    gld_lds16c(rl0, ldsw + NBO + 24576);
    gld_lds16c(rl1, ldsw + NBO + 28672);
    qh0 += 64; qh1 += 64; ql0 += 64; ql1 += 64;
    rh0 += 64; rh1 += 64; rl0 += 64; rl1 += 64;
  }
  short8 fah[4], fal[4], fbh[4], fbl[4];
  #pragma unroll
  for (int m = 0; m < 4; ++m) {
    const int ro = DBO + (wm*64 + m*16 + fr)*64 + cx;
    fah[m] = *(const short8*)(ldsc + ro);
    fal[m] = *(const short8*)(ldsc + ro + 8192);
  }
  #pragma unroll
  for (int n = 0; n < 4; ++n) {
    const int ro = DBO + 16384 + (wn*64 + n*16 + fr)*64 + cx;
    fbh[n] = *(const short8*)(ldsc + ro);
    fbl[n] = *(const short8*)(ldsc + ro + 8192);
  }
  __builtin_amdgcn_s_setprio(1);
  #pragma unroll
  for (int m = 0; m < 4; ++m)
    #pragma unroll
    for (int n = 0; n < 4; ++n) {
      acc[m][n] = __builtin_amdgcn_mfma_f32_16x16x32_bf16(fal[m], fbh[n], acc[m][n], 0, 0, 0);
      acc[m][n] = __builtin_amdgcn_mfma_f32_16x16x32_bf16(fah[m], fbl[n], acc[m][n], 0, 0, 0);
      acc[m][n] = __builtin_amdgcn_mfma_f32_16x16x32_bf16(fah[m], fbh[n], acc[m][n], 0, 0, 0);
    }
  __builtin_amdgcn_s_setprio(0);
  asm volatile("s_waitcnt vmcnt(0)" ::: "memory");
  __builtin_amdgcn_s_barrier();
}

__global__ void __launch_bounds__(256, 2)
gemm3_bt(const bf16* __restrict__ Ah, const bf16* __restrict__ Al,
         long a_rs, long a_oo, long a_oi,
         const bf16* __restrict__ Bth, const bf16* __restrict__ Btl,
         long b_rs, long b_oo, long b_oi,
         float* __restrict__ Cf, bf16* __restrict__ Ch, bf16* __restrict__ Cl,
         long c_rs, long c_oo, long c_oi,
         int M, int N, int K, int nlim, int zdiv)
{
  __shared__ __attribute__((aligned(128))) char ldsc[65536];
  const int tid = threadIdx.x;
  const int wid = tid >> 6;
  const int lid = tid & 63;
  const int z = blockIdx.z;
  const int zo = z / zdiv, zi = z - zo*zdiv;
  const long aoff = (long)zo*a_oo + (long)zi*a_oi;
  const long boff = (long)zo*b_oo + (long)zi*b_oi;
  const long cbase = (long)zo*c_oo + (long)zi*c_oi;
  const int brow = blockIdx.y * 128;
  const int bcol = blockIdx.x * 128;

  const int ch0 = tid;
  int ra0 = brow + (ch0 >> 2);       if (ra0 > M-1) ra0 = M-1;
  int ra1 = brow + 64 + (ch0 >> 2);  if (ra1 > M-1) ra1 = M-1;
  int rb0 = bcol + (ch0 >> 2);       if (rb0 > N-1) rb0 = N-1;
  int rb1 = bcol + 64 + (ch0 >> 2);  if (rb1 > N-1) rb1 = N-1;
  const int sw = ((ch0 ^ (ch0 >> 3)) & 3) * 8;   // f(row)=(row>>1)&3, row=ch>>2
  const char* qh0 = (const char*)(Ah + aoff + (long)ra0*a_rs + sw);
  const char* qh1 = (const char*)(Ah + aoff + (long)ra1*a_rs + sw);
  const char* ql0 = (const char*)(Al + aoff + (long)ra0*a_rs + sw);
  const char* ql1 = (const char*)(Al + aoff + (long)ra1*a_rs + sw);
  const char* rh0 = (const char*)(Bth + boff + (long)rb0*b_rs + sw);
  const char* rh1 = (const char*)(Bth + boff + (long)rb1*b_rs + sw);
  const char* rl0 = (const char*)(Btl + boff + (long)rb0*b_rs + sw);
  const char* rl1 = (const char*)(Btl + boff + (long)rb1*b_rs + sw);
  char* ldsw = ldsc + wid * 1024;

  f32x4 acc[4][4] = {};
  const int wm = wid >> 1, wn = wid & 1;
  const int fr = lid & 15, g8 = (lid >> 4) * 8;
  const int cx = (g8*2) ^ (((fr >> 1) & 3) << 4);   // read-side, byte units

  const int NT = K >> 5;
  // prologue: stage T0 -> buf0
  gld_lds16c(qh0, ldsw);
  gld_lds16c(qh1, ldsw + 4096);
  gld_lds16c(ql0, ldsw + 8192);
  gld_lds16c(ql1, ldsw + 12288);
  gld_lds16c(rh0, ldsw + 16384);
  gld_lds16c(rh1, ldsw + 20480);
  gld_lds16c(rl0, ldsw + 24576);
  gld_lds16c(rl1, ldsw + 28672);
  qh0 += 64; qh1 += 64; ql0 += 64; ql1 += 64;
  rh0 += 64; rh1 += 64; rl0 += 64; rl1 += 64;
  asm volatile("s_waitcnt vmcnt(0)" ::: "memory");
  __builtin_amdgcn_s_barrier();

  for (int tp = 0; tp < NT; tp += 2) {
    g3_step<0>(ldsc, ldsw, wm, wn, cx, fr,
               qh0, qh1, ql0, ql1, rh0, rh1, rl0, rl1, (tp + 1) < NT, acc);
    if (tp + 1 < NT)
      g3_step<32768>(ldsc, ldsw, wm, wn, cx, fr,
                     qh0, qh1, ql0, ql1, rh0, rh1, rl0, rl1, (tp + 2) < NT, acc);
  }

  const int rg = (lid >> 4) * 4;
  #pragma unroll
  for (int m = 0; m < 4; ++m) {
    #pragma unroll
    for (int n = 0; n < 4; ++n) {
      const int col = bcol + wn*64 + n*16 + fr;
      if (col < nlim) {
        #pragma unroll
        for (int j = 0; j < 4; ++j) {
          const int row = brow + wm*64 + m*16 + rg + j;
          if (row < M) {
            long off = cbase + (long)row*c_rs + col;
            float v = acc[m][n][j];
            if (Cl) {
              bf16 h = __float2bfloat16(v);
              Ch[off] = h;
              Cl[off] = __float2bfloat16(v - __bfloat162float(h));
            } else if (Ch) {
              Ch[off] = __float2bfloat16(v);
            } else {
              Cf[off] = v;
            }
          }
        }
      }
    }
  }
}

// ---------------- weight transpose fp32 -> bf16 (opt. 16-row interleave) ----------------
__global__ void wtrans(const float* __restrict__ in, bf16* __restrict__ out,
                       int R, int Cc, long in_rs, long out_rs, long in_bs, long out_bs,
                       int ilv, int radd)
{
  __shared__ float tile[32][33];
  in  += (long)blockIdx.z * in_bs;
  out += (long)blockIdx.z * out_bs;
  int r0 = blockIdx.y*32, c0 = blockIdx.x*32;
  int tx = threadIdx.x, ty = threadIdx.y;
  #pragma unroll
  for (int i = 0; i < 32; i += 8) {
    int r = r0 + ty + i, c = c0 + tx;
    if (r < R && c < Cc) tile[ty+i][tx] = in[(long)r*in_rs + c];
  }
  __syncthreads();
  #pragma unroll
  for (int i = 0; i < 32; i += 8) {
    int ro = c0 + ty + i, co = r0 + tx;
    if (ro < Cc && co < R) {
      int rr = ilv ? (((ro >> 4) << 5) + (ro & 15) + radd) : ro;
      out[(long)rr*out_rs + co] = __float2bfloat16(tile[tx][ty+i]);
    }
  }
}

// ---------------- weight transpose fp32 -> bf16 hi/lo pair ----------------
__global__ void wtrans3(const float* __restrict__ in, bf16* __restrict__ oh, bf16* __restrict__ ol,
                        int R, int Cc, long in_rs, long out_rs)
{
  __shared__ float tile[32][33];
  int r0 = blockIdx.y*32, c0 = blockIdx.x*32;
  int tx = threadIdx.x, ty = threadIdx.y;
  #pragma unroll
  for (int i = 0; i < 32; i += 8) {
    int r = r0 + ty + i, c = c0 + tx;
    if (r < R && c < Cc) tile[ty+i][tx] = in[(long)r*in_rs + c];
  }
  __syncthreads();
  #pragma unroll
  for (int i = 0; i < 32; i += 8) {
    int ro = c0 + ty + i, co = r0 + tx;
    if (ro < Cc && co < R) {
      float v = tile[tx][ty+i];
      bf16 h = __float2bfloat16(v);
      long o = (long)ro*out_rs + co;
      oh[o] = h;
      ol[o] = __float2bfloat16(v - __bfloat162float(h));
    }
  }
}

// ---------------- LayerNorm ----------------
__global__ void ln_partial(const float* __restrict__ x, float* __restrict__ part) {
  int b = blockIdx.y, blk = blockIdx.x;
  const float* xb = x + (long)b*NPB;
  int start = blk * 4374;
  float s = 0.f, ss = 0.f;
  for (int i = start + threadIdx.x; i < start + 4374; i += 256) {
    float v = xb[i]; s += v; ss += v*v;
  }
  #pragma unroll
  for (int o = 32; o; o >>= 1) { s += __shfl_down(s, o); ss += __shfl_down(ss, o); }
  __shared__ float red[2][4];
  int wid = threadIdx.x >> 6, lid = threadIdx.x & 63;
  if (lid == 0) { red[0][wid] = s; red[1][wid] = ss; }
  __syncthreads();
  if (threadIdx.x == 0) {
    float S = 0.f, SS = 0.f;
    for (int w = 0; w < 4; ++w) { S += red[0][w]; SS += red[1][w]; }
    part[(b*128 + blk)*2] = S; part[(b*128 + blk)*2 + 1] = SS;
  }
}

__global__ void ln_final(const float* __restrict__ part, float* __restrict__ stats) {
  int b = blockIdx.x, lid = threadIdx.x;
  float s = 0.f, ss = 0.f;
  for (int i = lid; i < 128; i += 64) { s += part[(b*128+i)*2]; ss += part[(b*128+i)*2+1]; }
  #pragma unroll
  for (int o = 32; o; o >>= 1) { s += __shfl_down(s, o); ss += __shfl_down(ss, o); }
  if (lid == 0) {
    float mean = s / (float)NPB;
    float var = ss / (float)NPB - mean*mean;
    stats[b*2] = mean; stats[b*2+1] = rsqrtf(var + 1e-5f);
  }
}

__global__ void ln_apply3(const float* __restrict__ x, const float* __restrict__ lnw,
                          const float* __restrict__ lnb, const float* __restrict__ stats,
                          bf16* __restrict__ th, bf16* __restrict__ tl, long ts)
{
  __shared__ float tile[32][33];
  int b = blockIdx.z;
  int s0 = blockIdx.x*32, c0 = blockIdx.y*32;
  float mean = stats[b*2], rstd = stats[b*2+1];
  int tx = threadIdx.x, ty = threadIdx.y;
  #pragma unroll
  for (int i = 0; i < 32; i += 8) {
    int c = c0 + ty + i, s = s0 + tx;
    if (s < S_) {
      long o = (long)c*S_ + s;
      tile[ty+i][tx] = (x[(long)b*NPB + o] - mean)*rstd*lnw[o] + lnb[o];
    }
  }
  __syncthreads();
  #pragma unroll
  for (int i = 0; i < 32; i += 8) {
    int s = s0 + ty + i, c = c0 + tx;
    if (s < S_) {
      float v = tile[tx][ty+i];
      bf16 h = __float2bfloat16(v);
      long o = ((long)b*S_ + s)*ts + c;
      th[o] = h;
      tl[o] = __float2bfloat16(v - __bfloat162float(h));
    }
  }
}

// ------- V transpose (bf16), hi (z<64) and lo (z>=64), zero pad t in [S_, SPAD) -------
__global__ void vtrans2(const bf16* __restrict__ qkvh, const bf16* __restrict__ qkvl,
                        bf16* __restrict__ VTh, bf16* __restrict__ VTl)
{
  __shared__ float tile[32][33];
  int z = blockIdx.z;
  const bf16* qkv = (z < 64) ? qkvh : qkvl;
  bf16* VT = (z < 64) ? VTh : VTl;
  int zz = z & 63;
  int bb = zz >> 3, h = zz & 7;
  const bf16* v = qkv + (long)bb*S_*C3 + 1536 + h*DH_;
  bf16* o = VT + (long)zz*DH_*SPAD;
  int t0 = blockIdx.y*32, d0 = blockIdx.x*32;
  int tx = threadIdx.x, ty = threadIdx.y;
  #pragma unroll
  for (int i = 0; i < 32; i += 8) {
    int t = t0 + ty + i, d = d0 + tx;
    float val = 0.f;
    if (t < S_ && d < DH_) val = __bfloat162float(v[(long)t*C3 + d]);
    tile[ty+i][tx] = val;
  }
  __syncthreads();
  #pragma unroll
  for (int i = 0; i < 32; i += 8) {
    int d = d0 + ty + i, t = t0 + tx;
    if (d < DH_ && t < SPAD) o[(long)d*SPAD + t] = __float2bfloat16(tile[tx][ty+i]);
  }
}

// -------- softmax over bf16 hi/lo score rows, IN PLACE (row stride 2*SPAD) --------
__global__ void softmax3p(bf16* __restrict__ scores, int nrows) {
  int row = blockIdx.x*4 + (threadIdx.x >> 6);
  if (row >= nrows) return;
  int lid = threadIdx.x & 63;
  bf16* ph = scores + (long)row*2*SPAD;
  bf16* pl = ph + SPAD;
  float vals[12];
  float mx = -1e30f;
  #pragma unroll
  for (int i = 0; i < 12; ++i) {
    int t = i*64 + lid;
    float v = -1e30f;
    if (t < S_) v = __bfloat162float(ph[t]) + __bfloat162float(pl[t]);
    vals[i] = v; mx = fmaxf(mx, v);
  }
  #pragma unroll
  for (int o = 32; o; o >>= 1) mx = fmaxf(mx, __shfl_xor(mx, o));
  float sum = 0.f;
  #pragma unroll
  for (int i = 0; i < 12; ++i) { float e = __expf(vals[i] - mx); vals[i] = e; sum += e; }
  #pragma unroll
  for (int o = 32; o; o >>= 1) sum += __shfl_xor(sum, o);
  float inv = 1.f / sum;
  #pragma unroll
  for (int i = 0; i < 12; ++i) {
    int t = i*64 + lid;
    if (t < SPAD) {
      float p = (t < S_) ? vals[i]*inv : 0.f;
      bf16 h = __float2bfloat16(p);
      ph[t] = h;
      pl[t] = __float2bfloat16(p - __bfloat162float(h));
    }
  }
}

// ---------------- residual transpose-add 1 ----------------
__global__ void tadd1(const float* __restrict__ x, const float* __restrict__ oproj,
                      float* __restrict__ xattn, bf16* __restrict__ tok2,
                      float* __restrict__ tok2f)
{
  __shared__ float t_o[32][33];
  __shared__ float t_x[32][33];
  int b = blockIdx.z;
  int s0 = blockIdx.x*32, c0 = blockIdx.y*32;
  int tx = threadIdx.x, ty = threadIdx.y;
  #pragma unroll
  for (int i = 0; i < 32; i += 8) {
    int s = s0 + ty + i;
    if (s < S_) t_o[ty+i][tx] = oproj[((long)b*S_ + s)*C_ + c0 + tx];
    int s2 = s0 + tx;
    if (s2 < S_) t_x[ty+i][tx] = x[(long)b*NPB + (long)(c0+ty+i)*S_ + s2];
  }
  __syncthreads();
  #pragma unroll
  for (int i = 0; i < 32; i += 8) {
    int s = s0 + tx, c = c0 + ty + i;
    if (s < S_) xattn[(long)b*NPB + (long)c*S_ + s] = t_x[ty+i][tx] + t_o[tx][ty+i];
    int s2 = s0 + ty + i, c2 = c0 + tx;
    if (s2 < S_) {
      float v = t_x[tx][ty+i] + t_o[ty+i][tx];
      long o = ((long)b*S_ + s2)*C_ + c2;
      tok2[o] = __float2bfloat16(v);
      tok2f[o] = v;
    }
  }
}

// ---- residual transpose-add 2 (final output), sums 8 bf16 down-partials ----
__global__ void tadd2(const float* __restrict__ xattn, const bf16* __restrict__ prt,
                      float* __restrict__ out)
{
  __shared__ float t_m[32][33];
  __shared__ float t_x[32][33];
  int b = blockIdx.z;
  int s0 = blockIdx.x*32, c0 = blockIdx.y*32;
  int tx = threadIdx.x, ty = threadIdx.y;
  #pragma unroll
  for (int i = 0; i < 32; i += 8) {
    int s = s0 + ty + i;
    if (s < S_) {
      const bf16* p = prt + ((long)b*S_ + s)*768 + c0 + tx;
      float acc = 0.f;
      #pragma unroll
      for (int z = 0; z < 8; ++z) acc += __bfloat162float(p[(long)z*MTOK*768]);
      t_m[ty+i][tx] = acc;
    }
    int s2 = s0 + tx;
    if (s2 < S_) t_x[ty+i][tx] = xattn[(long)b*NPB + (long)(c0+ty+i)*S_ + s2];
  }
  __syncthreads();
  #pragma unroll
  for (int i = 0; i < 32; i += 8) {
    int s = s0 + tx, c = c0 + ty + i;
    if (s < S_) out[(long)b*NPB + (long)c*S_ + s] = t_x[ty+i][tx] + t_m[tx][ty+i];
  }
}

// ---------------- router: top-2 of 3 from fp32 tok2, normalized weights ----------------
__global__ void router_k(const float* __restrict__ tok2f, const float* __restrict__ rw,
                         float* __restrict__ wfull)
{
  int t = blockIdx.x*4 + (threadIdx.x >> 6);
  if (t >= MTOK) return;
  int lid = threadIdx.x & 63;
  const float* tk = tok2f + (long)t*C_;
  float a0 = 0.f, a1 = 0.f, a2 = 0.f;
  for (int i = lid; i < C_; i += 64) {
    float v = tk[i];
    a0 += v*rw[i*3+0]; a1 += v*rw[i*3+1]; a2 += v*rw[i*3+2];
  }
  #pragma unroll
  for (int o = 32; o; o >>= 1) {
    a0 += __shfl_xor(a0, o); a1 += __shfl_xor(a1, o); a2 += __shfl_xor(a2, o);
  }
  if (lid == 0) {
    float m = fmaxf(a0, fmaxf(a1, a2));
    float e0 = __expf(a0-m), e1 = __expf(a1-m), e2 = __expf(a2-m);
    int emin = 0; float pm = e0;
    if (e1 <= pm) { pm = e1; emin = 1; }
    if (e2 <= pm) { pm = e2; emin = 2; }
    float rest = e0 + e1 + e2 - pm;
    wfull[t*3+0] = (emin == 0) ? 0.f : e0/rest;
    wfull[t*3+1] = (emin == 1) ? 0.f : e1/rest;
    wfull[t*3+2] = (emin == 2) ? 0.f : e2/rest;
  }
}

// =============================== host ===============================
static inline void launch_gemm3(hipStream_t st,
    const bf16* Ah, const bf16* Al, long a_rs, long a_oo, long a_oi,
    const bf16* Bh, const bf16* Bl, long b_rs, long b_oo, long b_oi,
    float* Cf, bf16* Ch, bf16* Cl, long c_rs, long c_oo, long c_oi,
    int M, int N, int K, int nlim, int zdiv, int nz)
{
  dim3 g((N + 127)/128, (M + 127)/128, nz);
  gemm3_bt<<<g, 256, 0, st>>>(Ah, Al, a_rs, a_oo, a_oi, Bh, Bl, b_rs, b_oo, b_oi,
                              Cf, Ch, Cl, c_rs, c_oo, c_oi, M, N, K, nlim, zdiv);
}

extern "C" void kernel_launch(void* const* d_in, const int* in_sizes, int n_in,
                              void* d_out, int out_size, void* d_ws, size_t ws_size,
                              hipStream_t stream)
{
  const float* x      = (const float*)d_in[0];
  const float* ln_w   = (const float*)d_in[1];
  const float* ln_b   = (const float*)d_in[2];
  const float* qkv_w  = (const float*)d_in[3];
  const float* proj_w = (const float*)d_in[4];
  const float* rout_w = (const float*)d_in[5];
  const float* gate_w = (const float*)d_in[6];
  const float* up_w   = (const float*)d_in[7];
  const float* down_w = (const float*)d_in[8];
  float* out = (float*)d_out;

  char* ws = (char*)d_ws;
  size_t off = 0;
  auto alloc = [&](size_t bytes) { size_t r = off; off += (bytes + 255) & ~(size_t)255; return r; };

  // persistent (~82.6 MB)
  size_t o_stats = alloc(8*2*4);
  size_t o_part  = alloc(8*128*2*4);
  size_t o_wfull = alloc((size_t)MTOK*3*4);
  size_t o_qkvTh = alloc((size_t)C3*C_*2);
  size_t o_qkvTl = alloc((size_t)C3*C_*2);
  size_t o_prjTh = alloc((size_t)C_*C_*2);
  size_t o_prjTl = alloc((size_t)C_*C_*2);
  size_t o_guT   = alloc((size_t)GUN*C_*2);      // gate/up 16-row interleaved
  size_t o_downT = alloc((size_t)C_*DK*2);
  size_t o_xattn = alloc((size_t)B_*NPB*4);
  size_t o_tok2  = alloc((size_t)MTOK*C_*2);
  size_t o_tok2f = alloc((size_t)MTOK*C_*4);
  size_t big0 = off;
  // phase A (attention): fixed buffers + union region (tok | scores | oproj)
  size_t o_qkvh  = alloc((size_t)MTOK*C3*2);
  size_t o_qkvl  = alloc((size_t)MTOK*C3*2);
  size_t o_VTh   = alloc((size_t)64*DH_*SPAD*2);
  size_t o_VTl   = alloc((size_t)64*DH_*SPAD*2);
  size_t o_aoh   = alloc((size_t)MTOK*C_*2);
  size_t o_aol   = alloc((size_t)MTOK*C_*2);
  size_t o_union = alloc((size_t)32*S_*SPAD*4);  // 68.7 MB
  size_t endA = off;
  // phase B (MoE): hidden + 8 bf16 partials
  off = big0;
  size_t o_hid = alloc((size_t)MTOK*DK*2);
  size_t o_prt = alloc((size_t)8*MTOK*768*2);
  size_t endB = off;
  size_t needed = endA > endB ? endA : endB;
  if (ws_size < needed) return;  // insufficient workspace: visible failure

  float* stats  = (float*)(ws + o_stats);
  float* part   = (float*)(ws + o_part);
  float* wfull  = (float*)(ws + o_wfull);
  bf16*  qkvTh  = (bf16*)(ws + o_qkvTh);
  bf16*  qkvTl  = (bf16*)(ws + o_qkvTl);
  bf16*  prjTh  = (bf16*)(ws + o_prjTh);
  bf16*  prjTl  = (bf16*)(ws + o_prjTl);
  bf16*  guT    = (bf16*)(ws + o_guT);
  bf16*  downT  = (bf16*)(ws + o_downT);
  float* xattn  = (float*)(ws + o_xattn);
  bf16*  tok2   = (bf16*)(ws + o_tok2);
  float* tok2f  = (float*)(ws + o_tok2f);
  bf16*  qkvh   = (bf16*)(ws + o_qkvh);
  bf16*  qkvl   = (bf16*)(ws + o_qkvl);
  bf16*  VTh    = (bf16*)(ws + o_VTh);
  bf16*  VTl    = (bf16*)(ws + o_VTl);
  bf16*  aoh    = (bf16*)(ws + o_aoh);
  bf16*  aol    = (bf16*)(ws + o_aol);
  // union region occupants (live ranges disjoint in stream order):
  bf16*  tokh   = (bf16*)(ws + o_union);
  bf16*  tokl   = (bf16*)(ws + o_union + (size_t)MTOK*C_*2);
  bf16*  Pbase  = (bf16*)(ws + o_union);
  float* oproj  = (float*)(ws + o_union);
  bf16*  hidden = (bf16*)(ws + o_hid);
  bf16*  prt    = (bf16*)(ws + o_prt);

  dim3 b32(32, 8);

  // weight conversions (gate/up 16-row interleaved per 32-row block of guT)
  wtrans3<<<dim3(72,24,1), b32, 0, stream>>>(qkv_w,  qkvTh, qkvTl, 768, 2304, 2304, 768);
  wtrans3<<<dim3(24,24,1), b32, 0, stream>>>(proj_w, prjTh, prjTl, 768, 768,  768,  768);
  wtrans<<<dim3(64,24,3), b32, 0, stream>>>(gate_w, guT, 768, 2048, 2048, 768,
                                            (long)768*2048, (long)4096*768, 1, 0);
  wtrans<<<dim3(64,24,3), b32, 0, stream>>>(up_w, guT, 768, 2048, 2048, 768,
                                            (long)768*2048, (long)4096*768, 1, 16);
  wtrans<<<dim3(24,64,3), b32, 0, stream>>>(down_w, downT, 2048, 768, 768, 6144,
                                            (long)2048*768, 2048, 0, 0);

  // LayerNorm -> tok hi/lo (b,s,c)
  ln_partial<<<dim3(128,8), 256, 0, stream>>>(x, part);
  ln_final<<<8, 64, 0, stream>>>(part, stats);
  ln_apply3<<<dim3(23,24,8), b32, 0, stream>>>(x, ln_w, ln_b, stats, tokh, tokl, C_);

  // qkv = tok @ qkv_w (bf16x3, hi/lo out); tok region dead afterwards
  launch_gemm3(stream, tokh, tokl, C_, 0, 0, qkvTh, qkvTl, C_, 0, 0,
               nullptr, qkvh, qkvl, C3, 0, 0, MTOK, C3, C_, C3, 1, 1);

  // V^T per (b,h), hi+lo in one dispatch, zero-padded to SPAD
  vtrans2<<<dim3(3,23,128), b32, 0, stream>>>(qkvh, qkvl, VTh, VTl);

  // attention in 2 chunks of 32 (b,h)-pairs (4 batches each)
  for (int c = 0; c < 2; ++c) {
    const long qoff = (long)(4*c)*S_*C3;
    launch_gemm3(stream,
        qkvh + qoff, qkvl + qoff, C3, (long)S_*C3, DH_,
        qkvh + qoff + 768, qkvl + qoff + 768, C3, (long)S_*C3, DH_,
        nullptr, Pbase, Pbase + SPAD, 2*SPAD, (long)8*S_*2*SPAD, (long)S_*2*SPAD,
        S_, S_, DH_, SPAD, 8, 32);
    softmax3p<<<5832, 256, 0, stream>>>(Pbase, 32*S_);
    launch_gemm3(stream,
        Pbase, Pbase + SPAD, 2*SPAD, (long)8*S_*2*SPAD, (long)S_*2*SPAD,
        VTh + (size_t)c*32*DH_*SPAD, VTl + (size_t)c*32*DH_*SPAD, SPAD,
        (long)8*DH_*SPAD, (long)DH_*SPAD,
        nullptr, aoh + (size_t)(4*c)*S_*C_, aol + (size_t)(4*c)*S_*C_,
        C_, (long)S_*C_, DH_,
        S_, DH_, SPAD, DH_, 8, 32);
  }

  // oproj = attnout @ proj_w (fp32 out, into union region — P dead now)
  launch_gemm3(stream, aoh, aol, C_, 0, 0, prjTh, prjTl, C_, 0, 0,
               oproj, nullptr, nullptr, C_, 0, 0, MTOK, C_, C_, C_, 1, 1);

  // residual + layouts
  tadd1<<<dim3(23,24,8), b32, 0, stream>>>(x, oproj, xattn, tok2, tok2f);

  // router weights (fp32 path) — must precede fused GU epilogue
  router_k<<<1458, 256, 0, stream>>>(tok2f, rout_w, wfull);

  // GU gemm with fused silu*up*w epilogue -> hidden [MTOK][6144]  (128^2 high-occ kernel)
  gemm97<<<dim3(GUN/128, 46, 1), 256, 0, stream>>>(
      tok2, C_, guT, C_, nullptr, hidden, DK, 0, MTOK, GUN, C_, wfull, 3);

  // down GEMM (K=6144) nz=8 K-split, bf16 partials
  gemm97<<<dim3(C_/128, 46, 8), 256, 0, stream>>>(
      hidden, DK, downT, DK, nullptr, prt, 768, (long)MTOK*768, MTOK, C_, DK/8,
      nullptr, 0);

  // final residual transpose-add (sums 8 partials) into output
  tadd2<<<dim3(23,24,8), b32, 0, stream>>>(xattn, prt, out);
}

// Round 18
// 693.080 us; speedup vs baseline: 1.1404x; 1.0115x over previous
//
#include <hip/hip_runtime.h>
#include <hip/hip_bf16.h>

#define C_    768
#define NH_   8
#define DH_   96
#define S_    729
#define B_    8
#define MTOK  5832
#define C3    2304
#define GUN   12288
#define DK    6144
#define SPAD  736
#define NPB   559872   // C_*S_

typedef __attribute__((ext_vector_type(8))) short short8;
typedef __attribute__((ext_vector_type(4))) float f32x4;
typedef __attribute__((ext_vector_type(4))) unsigned int uint4v;
typedef __hip_bfloat16 bf16;

__device__ __forceinline__ void gld_lds16c(const char* g, char* l) {
  __builtin_amdgcn_global_load_lds((const __attribute__((address_space(1))) void*)g,
                                   (__attribute__((address_space(3))) void*)l, 16, 0, 0);
}

// ========== 128x128 4-wave BK=32 double-buffered GEMM (m97-style, high occupancy) ==========
// Swizzle f(row) = (row>>1)&3 -> 2-way LDS access (free). Verified r16: conflicts = 0.
template<int DBO>
__device__ __forceinline__ void g97_step(
    char* ldsc, char* ldsw, const int rA, const int rB, const int cx,
    const char*& pA0, const char*& pA1, const char*& pB0, const char*& pB1,
    const bool stage, f32x4 (&acc)[4][4])
{
  const int NBO = 16384 - DBO;
  if (stage) {
    gld_lds16c(pA0, ldsw + NBO);
    gld_lds16c(pA1, ldsw + NBO + 4096);
    gld_lds16c(pB0, ldsw + NBO + 8192);
    gld_lds16c(pB1, ldsw + NBO + 12288);
    pA0 += 64; pA1 += 64; pB0 += 64; pB1 += 64;
  }
  short8 a4[4], b4[4];
  #pragma unroll
  for (int mf = 0; mf < 4; ++mf)
    a4[mf] = *(const short8*)(ldsc + DBO + rA + mf*1024 + cx);
  #pragma unroll
  for (int nf = 0; nf < 4; ++nf)
    b4[nf] = *(const short8*)(ldsc + DBO + rB + nf*1024 + cx);
  __builtin_amdgcn_s_setprio(1);
  #pragma unroll
  for (int mf = 0; mf < 4; ++mf)
    #pragma unroll
    for (int nf = 0; nf < 4; ++nf)
      acc[mf][nf] = __builtin_amdgcn_mfma_f32_16x16x32_bf16(a4[mf], b4[nf], acc[mf][nf], 0, 0, 0);
  __builtin_amdgcn_s_setprio(0);
  asm volatile("s_waitcnt vmcnt(0)" ::: "memory");
  __builtin_amdgcn_s_barrier();
}

// modes: 0 = bf16 out (Cb, +z*c_zoff). 1 = fp32 out (Cf, +z*c_zoff).
// 3 = fused MoE: gate/up interleaved at 16-col granularity; writes
// silu(g)*u*wfull[row*3+e] bf16 to Cb[row*c_rs + h].
__global__ void __launch_bounds__(256, 4)
gemm97(const bf16* __restrict__ A, long a_rs,
       const bf16* __restrict__ Bt, long b_rs,
       float* __restrict__ Cf, bf16* __restrict__ Cb,
       long c_rs, long c_zoff, int M, int N, int Ksub,
       const float* __restrict__ wfull, int mode)
{
  __shared__ __attribute__((aligned(128))) char ldsc[32768];
  const int tid = threadIdx.x;
  const int wid = tid >> 6, lid = tid & 63;
  const int wm = wid >> 1, wn = wid & 1;           // 2 x 2 wave grid (64x64 each)
  const int fr = lid & 15, g8 = (lid >> 4) * 8;
  const int brow = blockIdx.y * 128, bcol = blockIdx.x * 128;
  const long k0b = (long)blockIdx.z * Ksub * 2;
  const long a_rsb = a_rs * 2, b_rsb = b_rs * 2;
  const int srow = tid >> 2;                        // 0..63
  const int scol = ((tid & 3) ^ ((tid >> 3) & 3)) << 4;  // f(row)=(row>>1)&3
  const int NT = Ksub >> 5;
  char* ldsw = ldsc + wid * 1024;                   // wave staging base (+lid*16)

  int ra0_ = brow + srow;       if (ra0_ > M-1) ra0_ = M-1;
  int ra1_ = brow + 64 + srow;  if (ra1_ > M-1) ra1_ = M-1;
  int rb0_ = bcol + srow;       if (rb0_ > N-1) rb0_ = N-1;
  int rb1_ = bcol + 64 + srow;  if (rb1_ > N-1) rb1_ = N-1;
  const char* pA0 = (const char*)A + (long)ra0_*a_rsb + k0b + scol;
  const char* pA1 = (const char*)A + (long)ra1_*a_rsb + k0b + scol;
  const char* pB0 = (const char*)Bt + (long)rb0_*b_rsb + k0b + scol;
  const char* pB1 = (const char*)Bt + (long)rb1_*b_rsb + k0b + scol;

  const int cx = (g8*2) ^ (((fr >> 1) & 3) << 4);   // read-side: f = (fr>>1)&3
  const int rA = (wm*64 + fr)*64;
  const int rB = 8192 + (wn*64 + fr)*64;

  f32x4 acc[4][4] = {};

  // prologue: stage T0 -> buf0
  gld_lds16c(pA0, ldsw);
  gld_lds16c(pA1, ldsw + 4096);
  gld_lds16c(pB0, ldsw + 8192);
  gld_lds16c(pB1, ldsw + 12288);
  pA0 += 64; pA1 += 64; pB0 += 64; pB1 += 64;
  asm volatile("s_waitcnt vmcnt(0)" ::: "memory");
  __builtin_amdgcn_s_barrier();

  for (int tp = 0; tp < NT; tp += 2) {
    g97_step<0>(ldsc, ldsw, rA, rB, cx, pA0, pA1, pB0, pB1, true, acc);
    g97_step<16384>(ldsc, ldsw, rA, rB, cx, pA0, pA1, pB0, pB1, (tp + 2) < NT, acc);
  }

  const int rg = (lid >> 4) * 4;
  if (mode == 3) {
    // fused silu(gate)*up*w; gate = acc[*][even nf], up = acc[*][odd nf]
    #pragma unroll
    for (int mf = 0; mf < 4; ++mf) {
      #pragma unroll
      for (int np = 0; np < 2; ++np) {
        const int hb = (bcol + wn*64 + np*32) >> 5;
        const int h = hb*16 + fr;
        const int e = h >> 11;
        #pragma unroll
        for (int j = 0; j < 4; ++j) {
          const int row = brow + wm*64 + mf*16 + rg + j;
          if (row < M) {
            float g = acc[mf][2*np][j];
            float u = acc[mf][2*np+1][j];
            float w = wfull[row*3 + e];
            float sg = g / (1.f + __expf(-g));
            Cb[(long)row*c_rs + h] = __float2bfloat16(sg * u * w);
          }
        }
      }
    }
  } else {
    #pragma unroll
    for (int mf = 0; mf < 4; ++mf) {
      #pragma unroll
      for (int nf = 0; nf < 4; ++nf) {
        const int col = bcol + wn*64 + nf*16 + fr;
        if (col < N) {
          #pragma unroll
          for (int j = 0; j < 4; ++j) {
            const int row = brow + wm*64 + mf*16 + rg + j;
            if (row < M) {
              long off = (long)blockIdx.z*c_zoff + (long)row*c_rs + col;
              if (mode == 0) Cb[off] = __float2bfloat16(acc[mf][nf][j]);
              else           Cf[off] = acc[mf][nf][j];
            }
          }
        }
      }
    }
  }
}

// ------- bf16x3 split GEMM, DOUBLE-BUFFERED, 128x128 tile (A=(Ah+Al), B=(Bh+Bl)) -------
template<int DBO>
__device__ __forceinline__ void g3_step(
    char* ldsc, char* ldsw, const int wm, const int wn, const int cx, const int fr,
    const char*& qh0, const char*& qh1, const char*& ql0, const char*& ql1,
    const char*& rh0, const char*& rh1, const char*& rl0, const char*& rl1,
    const bool stage, f32x4 (&acc)[4][4])
{
  const int NBO = 32768 - DBO;
  if (stage) {
    gld_lds16c(qh0, ldsw + NBO);
    gld_lds16c(qh1, ldsw + NBO + 4096);
    gld_lds16c(ql0, ldsw + NBO + 8192);
    gld_lds16c(ql1, ldsw + NBO + 12288);
    gld_lds16c(rh0, ldsw + NBO + 16384);
    gld_lds16c(rh1, ldsw + NBO + 20480);
    gld_lds16c(rl0, ldsw + NBO + 24576);
    gld_lds16c(rl1, ldsw + NBO + 28672);
    qh0 += 64; qh1 += 64; ql0 += 64; ql1 += 64;
    rh0 += 64; rh1 += 64; rl0 += 64; rl1 += 64;
  }
  short8 fah[4], fal[4], fbh[4], fbl[4];
  #pragma unroll
  for (int m = 0; m < 4; ++m) {
    const int ro = DBO + (wm*64 + m*16 + fr)*64 + cx;
    fah[m] = *(const short8*)(ldsc + ro);
    fal[m] = *(const short8*)(ldsc + ro + 8192);
  }
  #pragma unroll
  for (int n = 0; n < 4; ++n) {
    const int ro = DBO + 16384 + (wn*64 + n*16 + fr)*64 + cx;
    fbh[n] = *(const short8*)(ldsc + ro);
    fbl[n] = *(const short8*)(ldsc + ro + 8192);
  }
  __builtin_amdgcn_s_setprio(1);
  #pragma unroll
  for (int m = 0; m < 4; ++m)
    #pragma unroll
    for (int n = 0; n < 4; ++n) {
      acc[m][n] = __builtin_amdgcn_mfma_f32_16x16x32_bf16(fal[m], fbh[n], acc[m][n], 0, 0, 0);
      acc[m][n] = __builtin_amdgcn_mfma_f32_16x16x32_bf16(fah[m], fbl[n], acc[m][n], 0, 0, 0);
      acc[m][n] = __builtin_amdgcn_mfma_f32_16x16x32_bf16(fah[m], fbh[n], acc[m][n], 0, 0, 0);
    }
  __builtin_amdgcn_s_setprio(0);
  asm volatile("s_waitcnt vmcnt(0)" ::: "memory");
  __builtin_amdgcn_s_barrier();
}

__global__ void __launch_bounds__(256, 2)
gemm3_bt(const bf16* __restrict__ Ah, const bf16* __restrict__ Al,
         long a_rs, long a_oo, long a_oi,
         const bf16* __restrict__ Bth, const bf16* __restrict__ Btl,
         long b_rs, long b_oo, long b_oi,
         float* __restrict__ Cf, bf16* __restrict__ Ch, bf16* __restrict__ Cl,
         long c_rs, long c_oo, long c_oi,
         int M, int N, int K, int nlim, int zdiv)
{
  __shared__ __attribute__((aligned(128))) char ldsc[65536];
  const int tid = threadIdx.x;
  const int wid = tid >> 6;
  const int lid = tid & 63;
  const int z = blockIdx.z;
  const int zo = z / zdiv, zi = z - zo*zdiv;
  const long aoff = (long)zo*a_oo + (long)zi*a_oi;
  const long boff = (long)zo*b_oo + (long)zi*b_oi;
  const long cbase = (long)zo*c_oo + (long)zi*c_oi;
  const int brow = blockIdx.y * 128;
  const int bcol = blockIdx.x * 128;

  const int ch0 = tid;
  int ra0 = brow + (ch0 >> 2);       if (ra0 > M-1) ra0 = M-1;
  int ra1 = brow + 64 + (ch0 >> 2);  if (ra1 > M-1) ra1 = M-1;
  int rb0 = bcol + (ch0 >> 2);       if (rb0 > N-1) rb0 = N-1;
  int rb1 = bcol + 64 + (ch0 >> 2);  if (rb1 > N-1) rb1 = N-1;
  const int sw = ((ch0 ^ (ch0 >> 3)) & 3) * 8;   // f(row)=(row>>1)&3, row=ch>>2
  const char* qh0 = (const char*)(Ah + aoff + (long)ra0*a_rs + sw);
  const char* qh1 = (const char*)(Ah + aoff + (long)ra1*a_rs + sw);
  const char* ql0 = (const char*)(Al + aoff + (long)ra0*a_rs + sw);
  const char* ql1 = (const char*)(Al + aoff + (long)ra1*a_rs + sw);
  const char* rh0 = (const char*)(Bth + boff + (long)rb0*b_rs + sw);
  const char* rh1 = (const char*)(Bth + boff + (long)rb1*b_rs + sw);
  const char* rl0 = (const char*)(Btl + boff + (long)rb0*b_rs + sw);
  const char* rl1 = (const char*)(Btl + boff + (long)rb1*b_rs + sw);
  char* ldsw = ldsc + wid * 1024;

  f32x4 acc[4][4] = {};
  const int wm = wid >> 1, wn = wid & 1;
  const int fr = lid & 15, g8 = (lid >> 4) * 8;
  const int cx = (g8*2) ^ (((fr >> 1) & 3) << 4);   // read-side, byte units

  const int NT = K >> 5;
  gld_lds16c(qh0, ldsw);
  gld_lds16c(qh1, ldsw + 4096);
  gld_lds16c(ql0, ldsw + 8192);
  gld_lds16c(ql1, ldsw + 12288);
  gld_lds16c(rh0, ldsw + 16384);
  gld_lds16c(rh1, ldsw + 20480);
  gld_lds16c(rl0, ldsw + 24576);
  gld_lds16c(rl1, ldsw + 28672);
  qh0 += 64; qh1 += 64; ql0 += 64; ql1 += 64;
  rh0 += 64; rh1 += 64; rl0 += 64; rl1 += 64;
  asm volatile("s_waitcnt vmcnt(0)" ::: "memory");
  __builtin_amdgcn_s_barrier();

  for (int tp = 0; tp < NT; tp += 2) {
    g3_step<0>(ldsc, ldsw, wm, wn, cx, fr,
               qh0, qh1, ql0, ql1, rh0, rh1, rl0, rl1, (tp + 1) < NT, acc);
    if (tp + 1 < NT)
      g3_step<32768>(ldsc, ldsw, wm, wn, cx, fr,
                     qh0, qh1, ql0, ql1, rh0, rh1, rl0, rl1, (tp + 2) < NT, acc);
  }

  const int rg = (lid >> 4) * 4;
  #pragma unroll
  for (int m = 0; m < 4; ++m) {
    #pragma unroll
    for (int n = 0; n < 4; ++n) {
      const int col = bcol + wn*64 + n*16 + fr;
      if (col < nlim) {
        #pragma unroll
        for (int j = 0; j < 4; ++j) {
          const int row = brow + wm*64 + m*16 + rg + j;
          if (row < M) {
            long off = cbase + (long)row*c_rs + col;
            float v = acc[m][n][j];
            if (Cl) {
              bf16 h = __float2bfloat16(v);
              Ch[off] = h;
              Cl[off] = __float2bfloat16(v - __bfloat162float(h));
            } else if (Ch) {
              Ch[off] = __float2bfloat16(v);
            } else {
              Cf[off] = v;
            }
          }
        }
      }
    }
  }
}

// ------- bf16x3 split GEMM, DOUBLE-BUFFERED, 64x128 tile (3 blocks/CU, fill-bound shapes) -------
// LDS buffer 24KB = {Ah 4K | Al 4K | Bh 8K | Bl 8K}, x2 = 48KB. Waves 2x2: 32 rows x 64 cols.
template<int DBO>
__device__ __forceinline__ void g3h_step(
    char* ldsc, char* ldsw, const int wm, const int wn, const int cx, const int fr,
    const char*& qh0, const char*& ql0,
    const char*& rh0, const char*& rh1, const char*& rl0, const char*& rl1,
    const bool stage, f32x4 (&acc)[2][4])
{
  const int NBO = 24576 - DBO;
  if (stage) {
    gld_lds16c(qh0, ldsw + NBO);
    gld_lds16c(ql0, ldsw + NBO + 4096);
    gld_lds16c(rh0, ldsw + NBO + 8192);
    gld_lds16c(rh1, ldsw + NBO + 12288);
    gld_lds16c(rl0, ldsw + NBO + 16384);
    gld_lds16c(rl1, ldsw + NBO + 20480);
    qh0 += 64; ql0 += 64;
    rh0 += 64; rh1 += 64; rl0 += 64; rl1 += 64;
  }
  short8 fah[2], fal[2], fbh[4], fbl[4];
  #pragma unroll
  for (int m = 0; m < 2; ++m) {
    const int ro = DBO + (wm*32 + m*16 + fr)*64 + cx;
    fah[m] = *(const short8*)(ldsc + ro);
    fal[m] = *(const short8*)(ldsc + ro + 4096);
  }
  #pragma unroll
  for (int n = 0; n < 4; ++n) {
    const int ro = DBO + 8192 + (wn*64 + n*16 + fr)*64 + cx;
    fbh[n] = *(const short8*)(ldsc + ro);
    fbl[n] = *(const short8*)(ldsc + ro + 8192);
  }
  __builtin_amdgcn_s_setprio(1);
  #pragma unroll
  for (int m = 0; m < 2; ++m)
    #pragma unroll
    for (int n = 0; n < 4; ++n) {
      acc[m][n] = __builtin_amdgcn_mfma_f32_16x16x32_bf16(fal[m], fbh[n], acc[m][n], 0, 0, 0);
      acc[m][n] = __builtin_amdgcn_mfma_f32_16x16x32_bf16(fah[m], fbl[n], acc[m][n], 0, 0, 0);
      acc[m][n] = __builtin_amdgcn_mfma_f32_16x16x32_bf16(fah[m], fbh[n], acc[m][n], 0, 0, 0);
    }
  __builtin_amdgcn_s_setprio(0);
  asm volatile("s_waitcnt vmcnt(0)" ::: "memory");
  __builtin_amdgcn_s_barrier();
}

__global__ void __launch_bounds__(256, 3)
gemm3h_bt(const bf16* __restrict__ Ah, const bf16* __restrict__ Al,
          long a_rs, long a_oo, long a_oi,
          const bf16* __restrict__ Bth, const bf16* __restrict__ Btl,
          long b_rs, long b_oo, long b_oi,
          float* __restrict__ Cf, bf16* __restrict__ Ch, bf16* __restrict__ Cl,
          long c_rs, long c_oo, long c_oi,
          int M, int N, int K, int nlim, int zdiv)
{
  __shared__ __attribute__((aligned(128))) char ldsc[49152];
  const int tid = threadIdx.x;
  const int wid = tid >> 6;
  const int lid = tid & 63;
  const int z = blockIdx.z;
  const int zo = z / zdiv, zi = z - zo*zdiv;
  const long aoff = (long)zo*a_oo + (long)zi*a_oi;
  const long boff = (long)zo*b_oo + (long)zi*b_oi;
  const long cbase = (long)zo*c_oo + (long)zi*c_oi;
  const int brow = blockIdx.y * 64;
  const int bcol = blockIdx.x * 128;

  const int ch0 = tid;
  int ra0 = brow + (ch0 >> 2);       if (ra0 > M-1) ra0 = M-1;
  int rb0 = bcol + (ch0 >> 2);       if (rb0 > N-1) rb0 = N-1;
  int rb1 = bcol + 64 + (ch0 >> 2);  if (rb1 > N-1) rb1 = N-1;
  const int sw = ((ch0 ^ (ch0 >> 3)) & 3) * 8;   // f(row)=(row>>1)&3
  const char* qh0 = (const char*)(Ah + aoff + (long)ra0*a_rs + sw);
  const char* ql0 = (const char*)(Al + aoff + (long)ra0*a_rs + sw);
  const char* rh0 = (const char*)(Bth + boff + (long)rb0*b_rs + sw);
  const char* rh1 = (const char*)(Bth + boff + (long)rb1*b_rs + sw);
  const char* rl0 = (const char*)(Btl + boff + (long)rb0*b_rs + sw);
  const char* rl1 = (const char*)(Btl + boff + (long)rb1*b_rs + sw);
  char* ldsw = ldsc + wid * 1024;

  f32x4 acc[2][4] = {};
  const int wm = wid >> 1, wn = wid & 1;
  const int fr = lid & 15, g8 = (lid >> 4) * 8;
  const int cx = (g8*2) ^ (((fr >> 1) & 3) << 4);

  const int NT = K >> 5;
  gld_lds16c(qh0, ldsw);
  gld_lds16c(ql0, ldsw + 4096);
  gld_lds16c(rh0, ldsw + 8192);
  gld_lds16c(rh1, ldsw + 12288);
  gld_lds16c(rl0, ldsw + 16384);
  gld_lds16c(rl1, ldsw + 20480);
  qh0 += 64; ql0 += 64;
  rh0 += 64; rh1 += 64; rl0 += 64; rl1 += 64;
  asm volatile("s_waitcnt vmcnt(0)" ::: "memory");
  __builtin_amdgcn_s_barrier();

  for (int tp = 0; tp < NT; tp += 2) {
    g3h_step<0>(ldsc, ldsw, wm, wn, cx, fr,
                qh0, ql0, rh0, rh1, rl0, rl1, (tp + 1) < NT, acc);
    if (tp + 1 < NT)
      g3h_step<24576>(ldsc, ldsw, wm, wn, cx, fr,
                      qh0, ql0, rh0, rh1, rl0, rl1, (tp + 2) < NT, acc);
  }

  const int rg = (lid >> 4) * 4;
  #pragma unroll
  for (int m = 0; m < 2; ++m) {
    #pragma unroll
    for (int n = 0; n < 4; ++n) {
      const int col = bcol + wn*64 + n*16 + fr;
      if (col < nlim) {
        #pragma unroll
        for (int j = 0; j < 4; ++j) {
          const int row = brow + wm*32 + m*16 + rg + j;
          if (row < M) {
            long off = cbase + (long)row*c_rs + col;
            float v = acc[m][n][j];
            if (Cl) {
              bf16 h = __float2bfloat16(v);
              Ch[off] = h;
              Cl[off] = __float2bfloat16(v - __bfloat162float(h));
            } else if (Ch) {
              Ch[off] = __float2bfloat16(v);
            } else {
              Cf[off] = v;
            }
          }
        }
      }
    }
  }
}

// ---------------- weight transpose fp32 -> bf16 (opt. 16-row interleave) ----------------
__global__ void wtrans(const float* __restrict__ in, bf16* __restrict__ out,
                       int R, int Cc, long in_rs, long out_rs, long in_bs, long out_bs,
                       int ilv, int radd)
{
  __shared__ float tile[32][33];
  in  += (long)blockIdx.z * in_bs;
  out += (long)blockIdx.z * out_bs;
  int r0 = blockIdx.y*32, c0 = blockIdx.x*32;
  int tx = threadIdx.x, ty = threadIdx.y;
  #pragma unroll
  for (int i = 0; i < 32; i += 8) {
    int r = r0 + ty + i, c = c0 + tx;
    if (r < R && c < Cc) tile[ty+i][tx] = in[(long)r*in_rs + c];
  }
  __syncthreads();
  #pragma unroll
  for (int i = 0; i < 32; i += 8) {
    int ro = c0 + ty + i, co = r0 + tx;
    if (ro < Cc && co < R) {
      int rr = ilv ? (((ro >> 4) << 5) + (ro & 15) + radd) : ro;
      out[(long)rr*out_rs + co] = __float2bfloat16(tile[tx][ty+i]);
    }
  }
}

// ---------------- weight transpose fp32 -> bf16 hi/lo pair ----------------
__global__ void wtrans3(const float* __restrict__ in, bf16* __restrict__ oh, bf16* __restrict__ ol,
                        int R, int Cc, long in_rs, long out_rs)
{
  __shared__ float tile[32][33];
  int r0 = blockIdx.y*32, c0 = blockIdx.x*32;
  int tx = threadIdx.x, ty = threadIdx.y;
  #pragma unroll
  for (int i = 0; i < 32; i += 8) {
    int r = r0 + ty + i, c = c0 + tx;
    if (r < R && c < Cc) tile[ty+i][tx] = in[(long)r*in_rs + c];
  }
  __syncthreads();
  #pragma unroll
  for (int i = 0; i < 32; i += 8) {
    int ro = c0 + ty + i, co = r0 + tx;
    if (ro < Cc && co < R) {
      float v = tile[tx][ty+i];
      bf16 h = __float2bfloat16(v);
      long o = (long)ro*out_rs + co;
      oh[o] = h;
      ol[o] = __float2bfloat16(v - __bfloat162float(h));
    }
  }
}

// ---------------- LayerNorm ----------------
__global__ void ln_partial(const float* __restrict__ x, float* __restrict__ part) {
  int b = blockIdx.y, blk = blockIdx.x;
  const float* xb = x + (long)b*NPB;
  int start = blk * 4374;
  float s = 0.f, ss = 0.f;
  for (int i = start + threadIdx.x; i < start + 4374; i += 256) {
    float v = xb[i]; s += v; ss += v*v;
  }
  #pragma unroll
  for (int o = 32; o; o >>= 1) { s += __shfl_down(s, o); ss += __shfl_down(ss, o); }
  __shared__ float red[2][4];
  int wid = threadIdx.x >> 6, lid = threadIdx.x & 63;
  if (lid == 0) { red[0][wid] = s; red[1][wid] = ss; }
  __syncthreads();
  if (threadIdx.x == 0) {
    float S = 0.f, SS = 0.f;
    for (int w = 0; w < 4; ++w) { S += red[0][w]; SS += red[1][w]; }
    part[(b*128 + blk)*2] = S; part[(b*128 + blk)*2 + 1] = SS;
  }
}

__global__ void ln_final(const float* __restrict__ part, float* __restrict__ stats) {
  int b = blockIdx.x, lid = threadIdx.x;
  float s = 0.f, ss = 0.f;
  for (int i = lid; i < 128; i += 64) { s += part[(b*128+i)*2]; ss += part[(b*128+i)*2+1]; }
  #pragma unroll
  for (int o = 32; o; o >>= 1) { s += __shfl_down(s, o); ss += __shfl_down(ss, o); }
  if (lid == 0) {
    float mean = s / (float)NPB;
    float var = ss / (float)NPB - mean*mean;
    stats[b*2] = mean; stats[b*2+1] = rsqrtf(var + 1e-5f);
  }
}

__global__ void ln_apply3(const float* __restrict__ x, const float* __restrict__ lnw,
                          const float* __restrict__ lnb, const float* __restrict__ stats,
                          bf16* __restrict__ th, bf16* __restrict__ tl, long ts)
{
  __shared__ float tile[32][33];
  int b = blockIdx.z;
  int s0 = blockIdx.x*32, c0 = blockIdx.y*32;
  float mean = stats[b*2], rstd = stats[b*2+1];
  int tx = threadIdx.x, ty = threadIdx.y;
  #pragma unroll
  for (int i = 0; i < 32; i += 8) {
    int c = c0 + ty + i, s = s0 + tx;
    if (s < S_) {
      long o = (long)c*S_ + s;
      tile[ty+i][tx] = (x[(long)b*NPB + o] - mean)*rstd*lnw[o] + lnb[o];
    }
  }
  __syncthreads();
  #pragma unroll
  for (int i = 0; i < 32; i += 8) {
    int s = s0 + ty + i, c = c0 + tx;
    if (s < S_) {
      float v = tile[tx][ty+i];
      bf16 h = __float2bfloat16(v);
      long o = ((long)b*S_ + s)*ts + c;
      th[o] = h;
      tl[o] = __float2bfloat16(v - __bfloat162float(h));
    }
  }
}

// ------- V transpose (bf16), hi (z<64) and lo (z>=64), zero pad t in [S_, SPAD) -------
__global__ void vtrans2(const bf16* __restrict__ qkvh, const bf16* __restrict__ qkvl,
                        bf16* __restrict__ VTh, bf16* __restrict__ VTl)
{
  __shared__ float tile[32][33];
  int z = blockIdx.z;
  const bf16* qkv = (z < 64) ? qkvh : qkvl;
  bf16* VT = (z < 64) ? VTh : VTl;
  int zz = z & 63;
  int bb = zz >> 3, h = zz & 7;
  const bf16* v = qkv + (long)bb*S_*C3 + 1536 + h*DH_;
  bf16* o = VT + (long)zz*DH_*SPAD;
  int t0 = blockIdx.y*32, d0 = blockIdx.x*32;
  int tx = threadIdx.x, ty = threadIdx.y;
  #pragma unroll
  for (int i = 0; i < 32; i += 8) {
    int t = t0 + ty + i, d = d0 + tx;
    float val = 0.f;
    if (t < S_ && d < DH_) val = __bfloat162float(v[(long)t*C3 + d]);
    tile[ty+i][tx] = val;
  }
  __syncthreads();
  #pragma unroll
  for (int i = 0; i < 32; i += 8) {
    int d = d0 + ty + i, t = t0 + tx;
    if (d < DH_ && t < SPAD) o[(long)d*SPAD + t] = __float2bfloat16(tile[tx][ty+i]);
  }
}

// -------- softmax over bf16 hi/lo score rows, IN PLACE (row stride 2*SPAD) --------
__global__ void softmax3p(bf16* __restrict__ scores, int nrows) {
  int row = blockIdx.x*4 + (threadIdx.x >> 6);
  if (row >= nrows) return;
  int lid = threadIdx.x & 63;
  bf16* ph = scores + (long)row*2*SPAD;
  bf16* pl = ph + SPAD;
  float vals[12];
  float mx = -1e30f;
  #pragma unroll
  for (int i = 0; i < 12; ++i) {
    int t = i*64 + lid;
    float v = -1e30f;
    if (t < S_) v = __bfloat162float(ph[t]) + __bfloat162float(pl[t]);
    vals[i] = v; mx = fmaxf(mx, v);
  }
  #pragma unroll
  for (int o = 32; o; o >>= 1) mx = fmaxf(mx, __shfl_xor(mx, o));
  float sum = 0.f;
  #pragma unroll
  for (int i = 0; i < 12; ++i) { float e = __expf(vals[i] - mx); vals[i] = e; sum += e; }
  #pragma unroll
  for (int o = 32; o; o >>= 1) sum += __shfl_xor(sum, o);
  float inv = 1.f / sum;
  #pragma unroll
  for (int i = 0; i < 12; ++i) {
    int t = i*64 + lid;
    if (t < SPAD) {
      float p = (t < S_) ? vals[i]*inv : 0.f;
      bf16 h = __float2bfloat16(p);
      ph[t] = h;
      pl[t] = __float2bfloat16(p - __bfloat162float(h));
    }
  }
}

// ---------------- residual transpose-add 1 ----------------
__global__ void tadd1(const float* __restrict__ x, const float* __restrict__ oproj,
                      float* __restrict__ xattn, bf16* __restrict__ tok2,
                      float* __restrict__ tok2f)
{
  __shared__ float t_o[32][33];
  __shared__ float t_x[32][33];
  int b = blockIdx.z;
  int s0 = blockIdx.x*32, c0 = blockIdx.y*32;
  int tx = threadIdx.x, ty = threadIdx.y;
  #pragma unroll
  for (int i = 0; i < 32; i += 8) {
    int s = s0 + ty + i;
    if (s < S_) t_o[ty+i][tx] = oproj[((long)b*S_ + s)*C_ + c0 + tx];
    int s2 = s0 + tx;
    if (s2 < S_) t_x[ty+i][tx] = x[(long)b*NPB + (long)(c0+ty+i)*S_ + s2];
  }
  __syncthreads();
  #pragma unroll
  for (int i = 0; i < 32; i += 8) {
    int s = s0 + tx, c = c0 + ty + i;
    if (s < S_) xattn[(long)b*NPB + (long)c*S_ + s] = t_x[ty+i][tx] + t_o[tx][ty+i];
    int s2 = s0 + ty + i, c2 = c0 + tx;
    if (s2 < S_) {
      float v = t_x[tx][ty+i] + t_o[ty+i][tx];
      long o = ((long)b*S_ + s2)*C_ + c2;
      tok2[o] = __float2bfloat16(v);
      tok2f[o] = v;
    }
  }
}

// ---- residual transpose-add 2 (final output), sums 8 bf16 down-partials ----
__global__ void tadd2(const float* __restrict__ xattn, const bf16* __restrict__ prt,
                      float* __restrict__ out)
{
  __shared__ float t_m[32][33];
  __shared__ float t_x[32][33];
  int b = blockIdx.z;
  int s0 = blockIdx.x*32, c0 = blockIdx.y*32;
  int tx = threadIdx.x, ty = threadIdx.y;
  #pragma unroll
  for (int i = 0; i < 32; i += 8) {
    int s = s0 + ty + i;
    if (s < S_) {
      const bf16* p = prt + ((long)b*S_ + s)*768 + c0 + tx;
      float acc = 0.f;
      #pragma unroll
      for (int z = 0; z < 8; ++z) acc += __bfloat162float(p[(long)z*MTOK*768]);
      t_m[ty+i][tx] = acc;
    }
    int s2 = s0 + tx;
    if (s2 < S_) t_x[ty+i][tx] = xattn[(long)b*NPB + (long)(c0+ty+i)*S_ + s2];
  }
  __syncthreads();
  #pragma unroll
  for (int i = 0; i < 32; i += 8) {
    int s = s0 + tx, c = c0 + ty + i;
    if (s < S_) out[(long)b*NPB + (long)c*S_ + s] = t_x[ty+i][tx] + t_m[tx][ty+i];
  }
}

// ---------------- router: top-2 of 3 from fp32 tok2, normalized weights ----------------
__global__ void router_k(const float* __restrict__ tok2f, const float* __restrict__ rw,
                         float* __restrict__ wfull)
{
  int t = blockIdx.x*4 + (threadIdx.x >> 6);
  if (t >= MTOK) return;
  int lid = threadIdx.x & 63;
  const float* tk = tok2f + (long)t*C_;
  float a0 = 0.f, a1 = 0.f, a2 = 0.f;
  for (int i = lid; i < C_; i += 64) {
    float v = tk[i];
    a0 += v*rw[i*3+0]; a1 += v*rw[i*3+1]; a2 += v*rw[i*3+2];
  }
  #pragma unroll
  for (int o = 32; o; o >>= 1) {
    a0 += __shfl_xor(a0, o); a1 += __shfl_xor(a1, o); a2 += __shfl_xor(a2, o);
  }
  if (lid == 0) {
    float m = fmaxf(a0, fmaxf(a1, a2));
    float e0 = __expf(a0-m), e1 = __expf(a1-m), e2 = __expf(a2-m);
    int emin = 0; float pm = e0;
    if (e1 <= pm) { pm = e1; emin = 1; }
    if (e2 <= pm) { pm = e2; emin = 2; }
    float rest = e0 + e1 + e2 - pm;
    wfull[t*3+0] = (emin == 0) ? 0.f : e0/rest;
    wfull[t*3+1] = (emin == 1) ? 0.f : e1/rest;
    wfull[t*3+2] = (emin == 2) ? 0.f : e2/rest;
  }
}

// =============================== host ===============================
static inline void launch_gemm3(hipStream_t st,
    const bf16* Ah, const bf16* Al, long a_rs, long a_oo, long a_oi,
    const bf16* Bh, const bf16* Bl, long b_rs, long b_oo, long b_oi,
    float* Cf, bf16* Ch, bf16* Cl, long c_rs, long c_oo, long c_oi,
    int M, int N, int K, int nlim, int zdiv, int nz)
{
  dim3 g((N + 127)/128, (M + 127)/128, nz);
  gemm3_bt<<<g, 256, 0, st>>>(Ah, Al, a_rs, a_oo, a_oi, Bh, Bl, b_rs, b_oo, b_oi,
                              Cf, Ch, Cl, c_rs, c_oo, c_oi, M, N, K, nlim, zdiv);
}

static inline void launch_gemm3h(hipStream_t st,
    const bf16* Ah, const bf16* Al, long a_rs, long a_oo, long a_oi,
    const bf16* Bh, const bf16* Bl, long b_rs, long b_oo, long b_oi,
    float* Cf, bf16* Ch, bf16* Cl, long c_rs, long c_oo, long c_oi,
    int M, int N, int K, int nlim, int zdiv, int nz)
{
  dim3 g((N + 127)/128, (M + 63)/64, nz);
  gemm3h_bt<<<g, 256, 0, st>>>(Ah, Al, a_rs, a_oo, a_oi, Bh, Bl, b_rs, b_oo, b_oi,
                               Cf, Ch, Cl, c_rs, c_oo, c_oi, M, N, K, nlim, zdiv);
}

extern "C" void kernel_launch(void* const* d_in, const int* in_sizes, int n_in,
                              void* d_out, int out_size, void* d_ws, size_t ws_size,
                              hipStream_t stream)
{
  const float* x      = (const float*)d_in[0];
  const float* ln_w   = (const float*)d_in[1];
  const float* ln_b   = (const float*)d_in[2];
  const float* qkv_w  = (const float*)d_in[3];
  const float* proj_w = (const float*)d_in[4];
  const float* rout_w = (const float*)d_in[5];
  const float* gate_w = (const float*)d_in[6];
  const float* up_w   = (const float*)d_in[7];
  const float* down_w = (const float*)d_in[8];
  float* out = (float*)d_out;

  char* ws = (char*)d_ws;
  size_t off = 0;
  auto alloc = [&](size_t bytes) { size_t r = off; off += (bytes + 255) & ~(size_t)255; return r; };

  // persistent (~82.6 MB)
  size_t o_stats = alloc(8*2*4);
  size_t o_part  = alloc(8*128*2*4);
  size_t o_wfull = alloc((size_t)MTOK*3*4);
  size_t o_qkvTh = alloc((size_t)C3*C_*2);
  size_t o_qkvTl = alloc((size_t)C3*C_*2);
  size_t o_prjTh = alloc((size_t)C_*C_*2);
  size_t o_prjTl = alloc((size_t)C_*C_*2);
  size_t o_guT   = alloc((size_t)GUN*C_*2);      // gate/up 16-row interleaved
  size_t o_downT = alloc((size_t)C_*DK*2);
  size_t o_xattn = alloc((size_t)B_*NPB*4);
  size_t o_tok2  = alloc((size_t)MTOK*C_*2);
  size_t o_tok2f = alloc((size_t)MTOK*C_*4);
  size_t big0 = off;
  // phase A (attention): fixed buffers + union region (tok | scores | oproj)
  size_t o_qkvh  = alloc((size_t)MTOK*C3*2);
  size_t o_qkvl  = alloc((size_t)MTOK*C3*2);
  size_t o_VTh   = alloc((size_t)64*DH_*SPAD*2);
  size_t o_VTl   = alloc((size_t)64*DH_*SPAD*2);
  size_t o_aoh   = alloc((size_t)MTOK*C_*2);
  size_t o_aol   = alloc((size_t)MTOK*C_*2);
  size_t o_union = alloc((size_t)32*S_*SPAD*4);  // 68.7 MB
  size_t endA = off;
  // phase B (MoE): hidden + 8 bf16 partials
  off = big0;
  size_t o_hid = alloc((size_t)MTOK*DK*2);
  size_t o_prt = alloc((size_t)8*MTOK*768*2);
  size_t endB = off;
  size_t needed = endA > endB ? endA : endB;
  if (ws_size < needed) return;  // insufficient workspace: visible failure

  float* stats  = (float*)(ws + o_stats);
  float* part   = (float*)(ws + o_part);
  float* wfull  = (float*)(ws + o_wfull);
  bf16*  qkvTh  = (bf16*)(ws + o_qkvTh);
  bf16*  qkvTl  = (bf16*)(ws + o_qkvTl);
  bf16*  prjTh  = (bf16*)(ws + o_prjTh);
  bf16*  prjTl  = (bf16*)(ws + o_prjTl);
  bf16*  guT    = (bf16*)(ws + o_guT);
  bf16*  downT  = (bf16*)(ws + o_downT);
  float* xattn  = (float*)(ws + o_xattn);
  bf16*  tok2   = (bf16*)(ws + o_tok2);
  float* tok2f  = (float*)(ws + o_tok2f);
  bf16*  qkvh   = (bf16*)(ws + o_qkvh);
  bf16*  qkvl   = (bf16*)(ws + o_qkvl);
  bf16*  VTh    = (bf16*)(ws + o_VTh);
  bf16*  VTl    = (bf16*)(ws + o_VTl);
  bf16*  aoh    = (bf16*)(ws + o_aoh);
  bf16*  aol    = (bf16*)(ws + o_aol);
  // union region occupants (live ranges disjoint in stream order):
  bf16*  tokh   = (bf16*)(ws + o_union);
  bf16*  tokl   = (bf16*)(ws + o_union + (size_t)MTOK*C_*2);
  bf16*  Pbase  = (bf16*)(ws + o_union);
  float* oproj  = (float*)(ws + o_union);
  bf16*  hidden = (bf16*)(ws + o_hid);
  bf16*  prt    = (bf16*)(ws + o_prt);

  dim3 b32(32, 8);

  // weight conversions (gate/up 16-row interleaved per 32-row block of guT)
  wtrans3<<<dim3(72,24,1), b32, 0, stream>>>(qkv_w,  qkvTh, qkvTl, 768, 2304, 2304, 768);
  wtrans3<<<dim3(24,24,1), b32, 0, stream>>>(proj_w, prjTh, prjTl, 768, 768,  768,  768);
  wtrans<<<dim3(64,24,3), b32, 0, stream>>>(gate_w, guT, 768, 2048, 2048, 768,
                                            (long)768*2048, (long)4096*768, 1, 0);
  wtrans<<<dim3(64,24,3), b32, 0, stream>>>(up_w, guT, 768, 2048, 2048, 768,
                                            (long)768*2048, (long)4096*768, 1, 16);
  wtrans<<<dim3(24,64,3), b32, 0, stream>>>(down_w, downT, 2048, 768, 768, 6144,
                                            (long)2048*768, 2048, 0, 0);

  // LayerNorm -> tok hi/lo (b,s,c)
  ln_partial<<<dim3(128,8), 256, 0, stream>>>(x, part);
  ln_final<<<8, 64, 0, stream>>>(part, stats);
  ln_apply3<<<dim3(23,24,8), b32, 0, stream>>>(x, ln_w, ln_b, stats, tokh, tokl, C_);

  // qkv = tok @ qkv_w (bf16x3, hi/lo out); tok region dead afterwards
  launch_gemm3(stream, tokh, tokl, C_, 0, 0, qkvTh, qkvTl, C_, 0, 0,
               nullptr, qkvh, qkvl, C3, 0, 0, MTOK, C3, C_, C3, 1, 1);

  // V^T per (b,h), hi+lo in one dispatch, zero-padded to SPAD
  vtrans2<<<dim3(3,23,128), b32, 0, stream>>>(qkvh, qkvl, VTh, VTl);

  // attention in 2 chunks of 32 (b,h)-pairs (4 batches each)
  for (int c = 0; c < 2; ++c) {
    const long qoff = (long)(4*c)*S_*C3;
    launch_gemm3(stream,
        qkvh + qoff, qkvl + qoff, C3, (long)S_*C3, DH_,
        qkvh + qoff + 768, qkvl + qoff + 768, C3, (long)S_*C3, DH_,
        nullptr, Pbase, Pbase + SPAD, 2*SPAD, (long)8*S_*2*SPAD, (long)S_*2*SPAD,
        S_, S_, DH_, SPAD, 8, 32);
    softmax3p<<<5832, 256, 0, stream>>>(Pbase, 32*S_);
    // PV via M64 kernel (384 blocks @ 3 blocks/CU)
    launch_gemm3h(stream,
        Pbase, Pbase + SPAD, 2*SPAD, (long)8*S_*2*SPAD, (long)S_*2*SPAD,
        VTh + (size_t)c*32*DH_*SPAD, VTl + (size_t)c*32*DH_*SPAD, SPAD,
        (long)8*DH_*SPAD, (long)DH_*SPAD,
        nullptr, aoh + (size_t)(4*c)*S_*C_, aol + (size_t)(4*c)*S_*C_,
        C_, (long)S_*C_, DH_,
        S_, DH_, SPAD, DH_, 8, 32);
  }

  // oproj = attnout @ proj_w (fp32 out, into union region) via M64 kernel (552 blocks)
  launch_gemm3h(stream, aoh, aol, C_, 0, 0, prjTh, prjTl, C_, 0, 0,
                oproj, nullptr, nullptr, C_, 0, 0, MTOK, C_, C_, C_, 1, 1);

  // residual + layouts
  tadd1<<<dim3(23,24,8), b32, 0, stream>>>(x, oproj, xattn, tok2, tok2f);

  // router weights (fp32 path) — must precede fused GU epilogue
  router_k<<<1458, 256, 0, stream>>>(tok2f, rout_w, wfull);

  // GU gemm with fused silu*up*w epilogue -> hidden [MTOK][6144]
  gemm97<<<dim3(GUN/128, 46, 1), 256, 0, stream>>>(
      tok2, C_, guT, C_, nullptr, hidden, DK, 0, MTOK, GUN, C_, wfull, 3);

  // down GEMM (K=6144) nz=8 K-split, bf16 partials
  gemm97<<<dim3(C_/128, 46, 8), 256, 0, stream>>>(
      hidden, DK, downT, DK, nullptr, prt, 768, (long)MTOK*768, MTOK, C_, DK/8,
      nullptr, 0);

  // final residual transpose-add (sums 8 partials) into output
  tadd2<<<dim3(23,24,8), b32, 0, stream>>>(xattn, prt, out);
}